// Round 6
// baseline (1019.987 us; speedup 1.0000x reference)
//
#include <hip/hip_runtime.h>
#include <math.h>

// Problem constants
#define NB   64
#define NN   400
#define DD   256
#define NHH  4
#define HDD  64
#define MR   25600            // NB*NN

typedef __attribute__((ext_vector_type(8))) short bf16x8;
typedef __attribute__((ext_vector_type(4))) float f32x4;

__device__ __forceinline__ short f2bf(float x) {
    union { float f; unsigned u; } v; v.f = x;
    return (short)((v.u + 0x7FFFu + ((v.u >> 16) & 1u)) >> 16);
}
__device__ __forceinline__ float bf2f(short s) {
    union { unsigned u; float f; } v; v.u = ((unsigned)(unsigned short)s) << 16;
    return v.f;
}
// async global->LDS, 16 B/lane; src = per-lane addr, LDS dest = wave-uniform base
__device__ __forceinline__ void gl_lds16(const void* g, void* l) {
    __builtin_amdgcn_global_load_lds(
        (const __attribute__((address_space(1))) unsigned*)g,
        (__attribute__((address_space(3))) unsigned*)l, 16, 0, 0);
}
// counted vmcnt wait (T4): never drain to 0 in a main loop. "memory" clobber
// orders LDS reads after the wait at IR level.
__device__ __forceinline__ void wait_vmcnt(int n) {
    switch (n) {
    case 0: asm volatile("s_waitcnt vmcnt(0)" ::: "memory"); break;
    case 1: asm volatile("s_waitcnt vmcnt(1)" ::: "memory"); break;
    case 2: asm volatile("s_waitcnt vmcnt(2)" ::: "memory"); break;
    case 3: asm volatile("s_waitcnt vmcnt(3)" ::: "memory"); break;
    case 4: asm volatile("s_waitcnt vmcnt(4)" ::: "memory"); break;
    default: asm volatile("s_waitcnt vmcnt(5)" ::: "memory"); break;
    }
}
__device__ __forceinline__ void barrier_raw() {
    __builtin_amdgcn_sched_barrier(0);
    __builtin_amdgcn_s_barrier();
    __builtin_amdgcn_sched_barrier(0);
}

// ---------------------------------------------------------------------------
// P8 layout: element (row, k) lives at ((k>>3)*rows + row)*8 + (k&7) (bf16).
// = the 16x16x32 MFMA fragment layout; staging is contiguous 1 KiB bursts.
// ---------------------------------------------------------------------------

// bf16 GEMM, 128x128 tile, BK=32 — ALL-GLOBAL K-loop: A/B fragments are read
// straight from global into registers (16 lanes x 16B contiguous per quad =
// coalesced; B is a small L2-resident weight, A re-reads are L3-served).
// 1-deep NAMED register double-buffer (a0/b0 vs a1/b1, loop unrolled by 2 —
// KT is always even here), ZERO barriers in the K-loop. LDS = epilogue only.
__global__ __launch_bounds__(256) void gemm_p8(
    const short* __restrict__ A, int arows, long long sA,
    const short* __restrict__ B, int brows, long long sB,
    const float* __restrict__ bias,
    short* __restrict__ C, int crows, int crz, long long sCe,
    int M, int N, int Npad, int K, int relu)
{
    __shared__ short lds[17408];   // epilogue tile [128][136]
    const int tid = threadIdx.x;
    const int z = blockIdx.z;
    const int m0 = blockIdx.x * 128, n0 = blockIdx.y * 128;
    const short* Ab = A + (size_t)z * sA;
    const short* Bb = B + (size_t)z * sB;

    const int w = tid >> 6, lane = tid & 63;
    const int quad = lane >> 4, l15 = lane & 15;
    const int wm = w & 1, wn = w >> 1;

    // fragment base: plane quad (advances 4 planes per K-step)
    const short* Abase = Ab + (((size_t)quad * arows) + m0 + wm * 64 + l15) * 8;
    const short* Bbase = Bb + (((size_t)quad * brows) + n0 + wn * 64 + l15) * 8;
    const size_t stepA = (size_t)4 * arows * 8;   // shorts per K-step
    const size_t stepB = (size_t)4 * brows * 8;

    f32x4 acc[4][4] = {};
    const int KT = K >> 5;          // steps of 32 k (4 planes); KT even (8 or 14)

    bf16x8 a0[4], b0[4], a1[4], b1[4];

#define LOADA(d, kt) { const short* _p = Abase + (size_t)(kt) * stepA; \
    _Pragma("unroll") for (int mi = 0; mi < 4; ++mi) \
        d[mi] = *reinterpret_cast<const bf16x8*>(_p + mi * 128); }
#define LOADB(d, kt) { const short* _p = Bbase + (size_t)(kt) * stepB; \
    _Pragma("unroll") for (int ni = 0; ni < 4; ++ni) \
        d[ni] = *reinterpret_cast<const bf16x8*>(_p + ni * 128); }
#define MFMA16(af, bfr) { \
    _Pragma("unroll") for (int mi = 0; mi < 4; ++mi) \
    _Pragma("unroll") for (int ni = 0; ni < 4; ++ni) \
        acc[mi][ni] = __builtin_amdgcn_mfma_f32_16x16x32_bf16(af[mi], bfr[ni], acc[mi][ni], 0, 0, 0); }

    LOADA(a0, 0); LOADB(b0, 0);
    for (int kt = 0; kt < KT; kt += 2) {
        LOADA(a1, kt + 1); LOADB(b1, kt + 1);   // kt+1 < KT always (KT even)
        MFMA16(a0, b0);
        if (kt + 2 < KT) { LOADA(a0, kt + 2); LOADB(b0, kt + 2); }
        MFMA16(a1, b1);
    }
#undef LOADA
#undef LOADB
#undef MFMA16

    // epilogue: acc -> bf16 row-major LDS tile, then 16 B coalesced stores
#pragma unroll
    for (int mi = 0; mi < 4; ++mi) {
#pragma unroll
        for (int r = 0; r < 4; ++r) {
            int row = wm * 64 + mi * 16 + quad * 4 + r;
#pragma unroll
            for (int ni = 0; ni < 4; ++ni) {
                int col = wn * 64 + ni * 16 + l15;
                int gcol = n0 + col;
                float v = 0.0f;
                if (gcol < N) {
                    v = acc[mi][ni][r];
                    if (bias) v += bias[gcol];
                    if (relu) v = fmaxf(v, 0.0f);
                }
                lds[row * 136 + col] = f2bf(v);
            }
        }
    }
    __syncthreads();
    short* Cbz = C + (size_t)z * sCe;
    const long long zr = (long long)z * crz;
#pragma unroll
    for (int t = 0; t < 8; ++t) {
        int c = t * 256 + tid;
        int row = c & 127, p16 = c >> 7;
        int grow = m0 + row;
        int gcol0 = n0 + p16 * 8;
        if (grow < M && gcol0 < Npad) {
            bf16x8 v = *reinterpret_cast<const bf16x8*>(&lds[row * 136 + p16 * 8]);
            *reinterpret_cast<bf16x8*>(
                &Cbz[((size_t)(gcol0 >> 3) * crows + zr + grow) * 8]) = v;
        }
    }
}

// ---------------------------------------------------------------------------
// Fused GEMM (N=256) + residual + LayerNorm. Tile 64m x 256n; BK=32, 3
// staging buffers, 2-deep counted-vmcnt pipeline (same scheme as gemm_p8).
// out[row] = LN(resid[row] + bf16(A·B^T + bias)) * g + b.  K % 64 == 0.
// ---------------------------------------------------------------------------
__global__ __launch_bounds__(256) void gemm_ln(
    const short* __restrict__ A,
    const short* __restrict__ B, int brows,
    const float* __restrict__ bias,
    const short* __restrict__ resid,
    const float* __restrict__ g, const float* __restrict__ bb,
    short* __restrict__ out, int K)
{
    __shared__ short lds[30720];        // 3 bufs of 10240: A [0,2048) B [2048,10240); epilogue rowt[64][264]
    __shared__ float gs[256], bs[256], bi_s[256];
    __shared__ float red[2][4][64];
    const int tid = threadIdx.x;
    const int m0 = blockIdx.x * 64;
    const int w = tid >> 6, lane = tid & 63;
    const int quad = lane >> 4, l15 = lane & 15;
    gs[tid] = g[tid]; bs[tid] = bb[tid]; bi_s[tid] = bias[tid];

    f32x4 acc[16] = {};
    const int KT = K >> 5;

    auto STAGE = [&](int buf, int kt) {
        const int gp0 = kt << 2;
        short* Al = lds + buf * 10240;
        short* Bl = Al + 2048;
        // 20 chunks (4 A + 16 B), 5 per wave
#pragma unroll
        for (int i = 0; i < 5; ++i) {
            int c = i * 4 + w;
            if (c < 4) {
                gl_lds16(A + ((size_t)(gp0 + c) * MR + m0 + lane) * 8, &Al[(c * 64) * 8]);
            } else {
                int cb = c - 4, p = cb >> 2, cq = cb & 3;
                gl_lds16(B + ((size_t)(gp0 + p) * brows + cq * 64 + lane) * 8,
                         &Bl[(p * 256 + cq * 64) * 8]);
            }
        }
    };

    STAGE(0, 0);
    STAGE(1, 1);
    for (int kt = 0; kt < KT; ++kt) {
        wait_vmcnt(kt + 1 < KT ? 5 : 0);
        barrier_raw();
        if (kt + 2 < KT) STAGE((kt + 2) % 3, kt + 2);
        const short* Al = lds + (kt % 3) * 10240;
        const short* Bl = Al + 2048;
        bf16x8 af = *reinterpret_cast<const bf16x8*>(
            &Al[(quad * 64 + w * 16 + l15) * 8]);
#pragma unroll
        for (int ni = 0; ni < 16; ++ni) {
            bf16x8 bfr = *reinterpret_cast<const bf16x8*>(
                &Bl[(quad * 256 + ni * 16 + l15) * 8]);
            acc[ni] = __builtin_amdgcn_mfma_f32_16x16x32_bf16(af, bfr, acc[ni], 0, 0, 0);
        }
    }
    __syncthreads();   // staging reads complete before rowt overwrite

    // epilogue 1: bias add, round to bf16 (matches old GEMM->global->LN path),
    // into row-tile rowt[64][4 groups][66] (66-stride breaks bank alignment)
    short* rowt = lds;
#pragma unroll
    for (int ni = 0; ni < 16; ++ni) {
        int col = ni * 16 + l15;
        int part = col >> 6, idx = col & 63;
#pragma unroll
        for (int r = 0; r < 4; ++r) {
            int row = w * 16 + quad * 4 + r;
            rowt[row * 264 + part * 66 + idx] = f2bf(acc[ni][r] + bi_s[col]);
        }
    }
    __syncthreads();

    // epilogue 2: thread = (row, quarter): add residual, reduce, normalize
    const int row = tid >> 2, part = tid & 3;
    const int grow = m0 + row;
    float vv[8][8];
    float sum = 0.0f, sq = 0.0f;
#pragma unroll
    for (int i = 0; i < 8; ++i) {
        int plane = part * 8 + i;
        bf16x8 rv = *reinterpret_cast<const bf16x8*>(resid + ((size_t)plane * MR + grow) * 8);
        bf16x8 tv = *reinterpret_cast<const bf16x8*>(&rowt[row * 264 + part * 66 + i * 8]);
#pragma unroll
        for (int e = 0; e < 8; ++e) {
            float v = bf2f(tv[e]) + bf2f(rv[e]);
            vv[i][e] = v; sum += v; sq += v * v;
        }
    }
    red[0][part][row] = sum; red[1][part][row] = sq;
    __syncthreads();
    sum = red[0][0][row] + red[0][1][row] + red[0][2][row] + red[0][3][row];
    sq  = red[1][0][row] + red[1][1][row] + red[1][2][row] + red[1][3][row];
    float mu = sum * (1.0f / 256.0f);
    float var = sq * (1.0f / 256.0f) - mu * mu;
    float rstd = 1.0f / sqrtf(fmaxf(var, 0.0f) + 1e-5f);
#pragma unroll
    for (int i = 0; i < 8; ++i) {
        int plane = part * 8 + i;
        bf16x8 o;
#pragma unroll
        for (int e = 0; e < 8; ++e)
            o[e] = f2bf((vv[i][e] - mu) * rstd * gs[plane * 8 + e] + bs[plane * 8 + e]);
        *reinterpret_cast<bf16x8*>(out + ((size_t)plane * MR + grow) * 8) = o;
    }
}

// ---------------------------------------------------------------------------
// V transpose: per (b,h), vT[(bh*56 + kp)*64 + d]*8 + (key&7) = V[key][d],
// keys >= 400 zeroed. XCD-swizzled 1D grid (1792 = 8*224): all chunks of a
// (b,h) run on XCD bh%8 -> vT lands in the L2 that attn_p8 will read it from.
// ---------------------------------------------------------------------------
__global__ __launch_bounds__(256) void vtrans(
    const short* __restrict__ qkv, short* __restrict__ vT)
{
    __shared__ short tile[64][66];
    const int id = blockIdx.x;
    const int xcd = id & 7, rem = id >> 3;
    const int bh_hi = rem / 7, c = rem - bh_hi * 7;
    const int bh_i = bh_hi * 8 + xcd;
    const int h = bh_i & 3, b = bh_i >> 2;
    const int tid = threadIdx.x;
    const size_t bh = (size_t)bh_i;
    for (int t = tid; t < 512; t += 256) {
        int pp = t >> 6, l = t & 63;
        int j = c * 64 + l;
        bf16x8 v;
        if (j < NN)
            v = *reinterpret_cast<const bf16x8*>(
                qkv + (((size_t)(64 + 8 * h + pp)) * MR + (size_t)b * NN + j) * 8);
        else { for (int e = 0; e < 8; ++e) v[e] = 0; }
#pragma unroll
        for (int e = 0; e < 8; ++e) tile[l][pp * 8 + e] = v[e];
    }
    __syncthreads();
    for (int t = tid; t < 512; t += 256) {
        int kq = t >> 6, d = t & 63;
        int kp = c * 8 + kq;
        bf16x8 o;
#pragma unroll
        for (int e = 0; e < 8; ++e) o[e] = tile[kq * 8 + e][d];
        *reinterpret_cast<bf16x8*>(vT + ((bh * 56 + kp) * 64 + d) * 8) = o;
    }
}

// ---------------------------------------------------------------------------
// Attention, LDS-minimal: K and V fragments are read STRAIGHT FROM GLOBAL
// (both are L2-resident on this block's XCD thanks to the swizzle, and both
// access patterns are 16 lanes x 16B contiguous per quad = fully coalesced).
// LDS holds only the P tile (and transiently Q) -> 52 KB -> 3 blocks/CU.
// Barriers per block: 3 (vs 17 with staged K/V). PV loop is barrier-free.
// ---------------------------------------------------------------------------
__global__ __launch_bounds__(256, 3) void attn_p8(
    const short* __restrict__ qkv, const short* __restrict__ vT,
    short* __restrict__ Out)
{
    __shared__ short PS[26624];   // P: 52 planes x 64 rows x 8 (53248 B); [0..4096) doubles as Q staging
    const int id = blockIdx.x;
    const int xcd = id & 7, rem = id >> 3;
    const int bh_hi = rem / 7, qt = rem - bh_hi * 7;
    const int bh_i = bh_hi * 8 + xcd;
    const int h = bh_i & 3, b = bh_i >> 2;
    const int tid = threadIdx.x;
    const int w = tid >> 6, lane = tid & 63;
    const int quad = lane >> 4, l15 = lane & 15;
    const size_t rowb = (size_t)b * NN;

    // stage Q (8 planes x 64 rows) into PS[0..4096)
    for (int j = w; j < 8; j += 4)
        gl_lds16(qkv + (((size_t)(8 * h + j)) * MR + rowb + qt * 64 + lane) * 8, &PS[j * 512]);
    __syncthreads();

    bf16x8 aq0 = *reinterpret_cast<const bf16x8*>(&PS[(quad * 64 + w * 16 + l15) * 8]);
    bf16x8 aq1 = *reinterpret_cast<const bf16x8*>(&PS[((4 + quad) * 64 + w * 16 + l15) * 8]);

    // QK^T: K fragment for (nt, quad) = 16B at plane (32+8h+quad), key nt*16+l15
    const short* Kb0 = qkv + ((size_t)(32 + 8 * h + quad) * MR + rowb + l15) * 8;
    const short* Kb1 = qkv + ((size_t)(36 + 8 * h + quad) * MR + rowb + l15) * 8;

    f32x4 sacc[25];
#pragma unroll
    for (int nt = 0; nt < 25; ++nt) { sacc[nt][0] = 0; sacc[nt][1] = 0; sacc[nt][2] = 0; sacc[nt][3] = 0; }
#pragma unroll
    for (int nt = 0; nt < 25; ++nt) {
        bf16x8 b0 = *reinterpret_cast<const bf16x8*>(Kb0 + nt * 128);
        bf16x8 b1 = *reinterpret_cast<const bf16x8*>(Kb1 + nt * 128);
        sacc[nt] = __builtin_amdgcn_mfma_f32_16x16x32_bf16(aq0, b0, sacc[nt], 0, 0, 0);
        sacc[nt] = __builtin_amdgcn_mfma_f32_16x16x32_bf16(aq1, b1, sacc[nt], 0, 0, 0);
    }

    float mx[4] = {-3e38f, -3e38f, -3e38f, -3e38f}, sm[4] = {0, 0, 0, 0};
#pragma unroll
    for (int nt = 0; nt < 25; ++nt)
#pragma unroll
        for (int r = 0; r < 4; ++r) mx[r] = fmaxf(mx[r], sacc[nt][r]);
#pragma unroll
    for (int r = 0; r < 4; ++r) {
        mx[r] = fmaxf(mx[r], __shfl_xor(mx[r], 1));
        mx[r] = fmaxf(mx[r], __shfl_xor(mx[r], 2));
        mx[r] = fmaxf(mx[r], __shfl_xor(mx[r], 4));
        mx[r] = fmaxf(mx[r], __shfl_xor(mx[r], 8));
    }
#pragma unroll
    for (int nt = 0; nt < 25; ++nt)
#pragma unroll
        for (int r = 0; r < 4; ++r) {
            float e = __expf((sacc[nt][r] - mx[r]) * 0.125f);
            sacc[nt][r] = e;
            sm[r] += e;
        }
#pragma unroll
    for (int r = 0; r < 4; ++r) {
        sm[r] += __shfl_xor(sm[r], 1);
        sm[r] += __shfl_xor(sm[r], 2);
        sm[r] += __shfl_xor(sm[r], 4);
        sm[r] += __shfl_xor(sm[r], 8);
    }
    __syncthreads();   // Q LDS reads complete -> P may overwrite PS

    // P transpose into PS (C-layout -> A-fragment layout), keys>=400 zeroed
#pragma unroll
    for (int nt = 0; nt < 25; ++nt)
#pragma unroll
        for (int r = 0; r < 4; ++r) {
            int colk = nt * 16 + l15;
            PS[((colk >> 3) * 64 + w * 16 + quad * 4 + r) * 8 + (colk & 7)] = f2bf(sacc[nt][r]);
        }
    for (int idx = tid; idx < 1024; idx += 256) PS[25600 + idx] = 0;

    f32x4 oacc[4];
#pragma unroll
    for (int dt = 0; dt < 4; ++dt) { oacc[dt][0] = 0; oacc[dt][1] = 0; oacc[dt][2] = 0; oacc[dt][3] = 0; }
    __syncthreads();   // P visible to all waves

    // PV, barrier-free: V fragment for (kt, quad, dt) = 16B at vT plane
    // bh*56 + kt*4 + quad, d = dt*16 + l15 (L2-resident, coalesced).
    const short* Vb = vT + (((size_t)bh_i * 56 + quad) * 64 + l15) * 8;
#pragma unroll
    for (int kt = 0; kt < 13; ++kt) {
        bf16x8 pa = *reinterpret_cast<const bf16x8*>(
            &PS[((kt * 4 + quad) * 64 + w * 16 + l15) * 8]);
#pragma unroll
        for (int dt = 0; dt < 4; ++dt) {
            bf16x8 vb = *reinterpret_cast<const bf16x8*>(Vb + kt * 2048 + dt * 128);
            oacc[dt] = __builtin_amdgcn_mfma_f32_16x16x32_bf16(pa, vb, oacc[dt], 0, 0, 0);
        }
    }
#pragma unroll
    for (int r = 0; r < 4; ++r) {
        int row = qt * 64 + w * 16 + quad * 4 + r;
        if (row >= NN) continue;
        float inv = 1.0f / sm[r];
#pragma unroll
        for (int dt = 0; dt < 4; ++dt) {
            int col = dt * 16 + l15;
            Out[(((size_t)(8 * h + (col >> 3))) * MR + rowb + row) * 8 + (col & 7)] =
                f2bf(oacc[dt][r] * inv);
        }
    }
}

// ---------------------------------------------------------------------------
// vectorized f32 -> P8 conversion: one thread per (row, 8-col group);
// float4 x2 reads, one bf16x8 store.
// ---------------------------------------------------------------------------
__global__ void conv_p8(const float* __restrict__ src, short* __restrict__ dst,
                        int R, int K, int Kp, int PR)
{
    const int G = Kp >> 3;
    int idx = blockIdx.x * 256 + threadIdx.x;
    if (idx >= R * G) return;
    int r = idx / G, g = idx - r * G;
    int k0 = g << 3;
    bf16x8 o;
    if (k0 + 8 <= K) {
        const float4 v0 = *reinterpret_cast<const float4*>(src + (size_t)r * K + k0);
        const float4 v1 = *reinterpret_cast<const float4*>(src + (size_t)r * K + k0 + 4);
        o[0] = f2bf(v0.x); o[1] = f2bf(v0.y); o[2] = f2bf(v0.z); o[3] = f2bf(v0.w);
        o[4] = f2bf(v1.x); o[5] = f2bf(v1.y); o[6] = f2bf(v1.z); o[7] = f2bf(v1.w);
    } else {
#pragma unroll
        for (int e = 0; e < 8; ++e) {
            int k = k0 + e;
            o[e] = (k < K) ? f2bf(src[(size_t)r * K + k]) : (short)0;
        }
    }
    *reinterpret_cast<bf16x8*>(dst + ((size_t)g * PR + r) * 8) = o;
}

// ---------------------------------------------------------------------------
__global__ __launch_bounds__(256) void w1_p8(
    const float* __restrict__ W1, short* __restrict__ Wp)
{
    __shared__ float tile[128][129];
    const int k0 = blockIdx.x * 128;
    const int tid = threadIdx.x;
    for (int t = 0; t < 16; ++t) {
        int idx = t * 256 + tid;
        int r = idx >> 5, k4 = idx & 31;
        float4 v = *(const float4*)(W1 + (size_t)r * 102400 + k0 + k4 * 4);
        tile[r][k4 * 4 + 0] = v.x; tile[r][k4 * 4 + 1] = v.y;
        tile[r][k4 * 4 + 2] = v.z; tile[r][k4 * 4 + 3] = v.w;
    }
    __syncthreads();
    for (int t = 0; t < 8; ++t) {
        int idx = t * 256 + tid;
        int pidx = idx >> 7, r = idx & 127;
        bf16x8 o;
#pragma unroll
        for (int e = 0; e < 8; ++e) o[e] = f2bf(tile[r][pidx * 8 + e]);
        *reinterpret_cast<bf16x8*>(Wp + (((size_t)(k0 >> 3) + pidx) * 128 + r) * 8) = o;
    }
}

// ---------------------------------------------------------------------------
__global__ void colsum_dinv(const float* __restrict__ sc, float* __restrict__ dinv)
{
    int b = blockIdx.y;
    int j = blockIdx.x * 256 + threadIdx.x;
    if (j >= NN) return;
    const float* p = sc + (size_t)b * NN * NN + j;
    float s = 0.0f;
    for (int i = 0; i < NN; ++i) s += p[(size_t)i * NN];
    dinv[b * NN + j] = (s > 0.0f) ? 1.0f / sqrtf(s) : 0.0f;
}

// ---------------------------------------------------------------------------
__global__ __launch_bounds__(256) void sc_prep(
    const float* __restrict__ sc, const float* __restrict__ dinv,
    short* __restrict__ scb, short* __restrict__ anT)
{
    __shared__ float tile[64][65];
    const int b = blockIdx.z;
    const int i0 = blockIdx.y * 64, j0 = blockIdx.x * 64;
    const int tid = threadIdx.x;
    const float* sb = sc + (size_t)b * NN * NN;
    short* scbb = scb + (size_t)b * 56 * 512 * 8;
    short* anTb = anT + (size_t)b * 56 * 512 * 8;
    for (int e = tid; e < 4096; e += 256) {
        int r = e >> 6, c = e & 63;
        int i = i0 + r, j = j0 + c;
        tile[r][c] = (i < NN && j < NN) ? sb[(size_t)i * NN + j] : 0.0f;
    }
    __syncthreads();
    for (int e = tid; e < 4096; e += 256) {
        int r = e >> 6, c = e & 63;
        int i = i0 + r, j = j0 + c;
        scbb[((size_t)(j >> 3) * 512 + i) * 8 + (j & 7)] = f2bf(tile[r][c]);
        float v = 0.0f;
        if (i < NN && j < NN) v = tile[r][c] * dinv[b * NN + i] * dinv[b * NN + j];
        anTb[((size_t)(i >> 3) * 512 + j) * 8 + (i & 7)] = f2bf(v);
    }
}

// ---------------------------------------------------------------------------
__global__ __launch_bounds__(256) void cls_gemm(
    const short* __restrict__ C1, const short* __restrict__ C2,
    const short* __restrict__ Wp, float* __restrict__ partial)
{
    __shared__ short Al[32 * 64 * 8];
    __shared__ short Wl[8 * 128 * 8];
    const int j = blockIdx.x;
    const int tid = threadIdx.x;
    const int w = tid >> 6, lane = tid & 63;
    const int quad = lane >> 4, l15 = lane & 15;

    for (int s = 0; s < 8; ++s) {
        int idx = s * 256 + tid;
        int p = idx >> 6, b = idx & 63;
        size_t ad = ((size_t)p * MR + (size_t)b * NN + j) * 8;
        bf16x8 a = *reinterpret_cast<const bf16x8*>(C1 + ad);
        bf16x8 c = *reinterpret_cast<const bf16x8*>(C2 + ad);
        bf16x8 o;
#pragma unroll
        for (int e = 0; e < 8; ++e) o[e] = f2bf(0.5f * (bf2f(a[e]) + bf2f(c[e])));
        *reinterpret_cast<bf16x8*>(&Al[(p * 64 + b) * 8]) = o;
    }

    f32x4 acc[4][2] = {};
    const size_t wp0 = (size_t)j * 32;
    for (int s = 0; s < 4; ++s) {
#pragma unroll
        for (int pp = 0; pp < 2; ++pp) {
            int p = w + pp * 4;
            gl_lds16(Wp + ((wp0 + s * 8 + p) * 128 + lane) * 8,      &Wl[(p * 128) * 8]);
            gl_lds16(Wp + ((wp0 + s * 8 + p) * 128 + 64 + lane) * 8, &Wl[(p * 128 + 64) * 8]);
        }
        __syncthreads();
#pragma unroll
        for (int kb = 0; kb < 2; ++kb) {
            bf16x8 af[4], bfr[2];
#pragma unroll
            for (int mi = 0; mi < 4; ++mi)
                af[mi] = *reinterpret_cast<const bf16x8*>(
                    &Al[((s * 8 + kb * 4 + quad) * 64 + mi * 16 + l15) * 8]);
#pragma unroll
            for (int ni = 0; ni < 2; ++ni)
                bfr[ni] = *reinterpret_cast<const bf16x8*>(
                    &Wl[((kb * 4 + quad) * 128 + w * 32 + ni * 16 + l15) * 8]);
#pragma unroll
            for (int mi = 0; mi < 4; ++mi)
#pragma unroll
                for (int ni = 0; ni < 2; ++ni)
                    acc[mi][ni] = __builtin_amdgcn_mfma_f32_16x16x32_bf16(af[mi], bfr[ni], acc[mi][ni], 0, 0, 0);
        }
        __syncthreads();
    }
    float* pj = partial + (size_t)j * 8192;
#pragma unroll
    for (int mi = 0; mi < 4; ++mi)
#pragma unroll
        for (int r = 0; r < 4; ++r) {
            int row = mi * 16 + quad * 4 + r;
#pragma unroll
            for (int ni = 0; ni < 2; ++ni)
                pj[row * 128 + w * 32 + ni * 16 + l15] = acc[mi][ni][r];
        }
}

__global__ void cls_reduce(const float* __restrict__ partial, float* __restrict__ clsh)
{
    int o = blockIdx.x * 256 + threadIdx.x;
    float s = 0.0f;
    for (int kb = 0; kb < 400; ++kb) s += partial[(size_t)kb * 8192 + o];
    clsh[o] = s;
}

__global__ void logits_final(
    const float* __restrict__ clsh, const float* __restrict__ b1,
    const float* __restrict__ w2, const float* __restrict__ b2,
    float* __restrict__ out)
{
    __shared__ float t[128];
    int b = blockIdx.x;
    int tid = threadIdx.x;
    t[tid] = fmaxf(clsh[b * 128 + tid] + b1[tid], 0.0f);
    __syncthreads();
    if (tid < 2) {
        float s = b2[tid];
        for (int o = 0; o < 128; ++o) s += t[o] * w2[tid * 128 + o];
        out[b * 2 + tid] = s;
    }
}

// ---------------------------------------------------------------------------
extern "C" void kernel_launch(void* const* d_in, const int* in_sizes, int n_in,
                              void* d_out, int out_size, void* d_ws, size_t ws_size,
                              hipStream_t stream)
{
    const float* fc        = (const float*)d_in[0];
    const float* sc        = (const float*)d_in[1];
    const float* proj_w    = (const float*)d_in[2];
    const float* proj_b    = (const float*)d_in[3];
    const float* enc_qkv_w = (const float*)d_in[4];
    const float* enc_qkv_b = (const float*)d_in[5];
    const float* enc_out_w = (const float*)d_in[6];
    const float* enc_out_b = (const float*)d_in[7];
    const float* enc_l1_w  = (const float*)d_in[8];
    const float* enc_l1_b  = (const float*)d_in[9];
    const float* enc_l2_w  = (const float*)d_in[10];
    const float* enc_l2_b  = (const float*)d_in[11];
    const float* enc_n1_g  = (const float*)d_in[12];
    const float* enc_n1_b  = (const float*)d_in[13];
    const float* enc_n2_g  = (const float*)d_in[14];
    const float* enc_n2_b  = (const float*)d_in[15];
    const float* gcn_w1    = (const float*)d_in[16];
    const float* gcn_b1    = (const float*)d_in[17];
    const float* gcn_w2    = (const float*)d_in[18];
    const float* gcn_b2    = (const float*)d_in[19];
    const float* ca1_qkv_w = (const float*)d_in[20];
    const float* ca1_qkv_b = (const float*)d_in[21];
    const float* ca1_out_w = (const float*)d_in[22];
    const float* ca1_out_b = (const float*)d_in[23];
    const float* ca1_n_g   = (const float*)d_in[24];
    const float* ca1_n_b   = (const float*)d_in[25];
    const float* ca2_qkv_w = (const float*)d_in[26];
    const float* ca2_qkv_b = (const float*)d_in[27];
    const float* ca2_out_w = (const float*)d_in[28];
    const float* ca2_out_b = (const float*)d_in[29];
    const float* ca2_n_g   = (const float*)d_in[30];
    const float* ca2_n_b   = (const float*)d_in[31];
    const float* cls_w1    = (const float*)d_in[32];
    const float* cls_b1    = (const float*)d_in[33];
    const float* cls_w2    = (const float*)d_in[34];
    const float* cls_b2    = (const float*)d_in[35];

    char* wsb = (char*)d_ws;
    size_t off = 0;
    auto alloc = [&](size_t bytes) { char* r = wsb + off; off += (bytes + 255) & ~(size_t)255; return r; };
    short* bufBig = (short*)alloc((size_t)MR * 1024 * 2);
    short* fcb    = (short*)alloc((size_t)56 * MR * 8 * 2);
    short* anT    = (short*)alloc((size_t)NB * 56 * 512 * 8 * 2);
    short* bufH   = (short*)alloc((size_t)32 * MR * 8 * 2);
    short* bufA   = (short*)alloc((size_t)32 * MR * 8 * 2);
    short* bufC   = (short*)alloc((size_t)32 * MR * 8 * 2);
    short* bufZS  = (short*)alloc((size_t)32 * MR * 8 * 2);
    short* vT     = (short*)alloc((size_t)NB * NHH * 56 * 64 * 8 * 2);
    short* w1b    = (short*)alloc((size_t)12800 * 128 * 8 * 2);
    short* projwb = (short*)alloc((size_t)56 * 256 * 8 * 2);
    short* qkvwb  = (short*)alloc((size_t)32 * 1536 * 8 * 2);
    short* outwb  = (short*)alloc((size_t)32 * 512 * 8 * 2);
    short* l1wb   = (short*)alloc((size_t)32 * 2048 * 8 * 2);
    short* l2wb   = (short*)alloc((size_t)128 * 512 * 8 * 2);
    short* gw1b   = (short*)alloc((size_t)56 * 256 * 8 * 2);
    short* gw2b   = (short*)alloc((size_t)32 * 256 * 8 * 2);
    short* c1qb   = (short*)alloc((size_t)32 * 768 * 8 * 2);
    short* c1ob   = (short*)alloc((size_t)32 * 256 * 8 * 2);
    short* c2qb   = (short*)alloc((size_t)32 * 768 * 8 * 2);
    short* c2ob   = (short*)alloc((size_t)32 * 256 * 8 * 2);
    float* dinv   = (float*)alloc((size_t)MR * 4);
    float* clsh   = (float*)alloc((size_t)NB * 128 * 4);
    short* scb = bufBig;
    short* XT1 = bufBig + (size_t)64 * 56 * 512 * 8;
    short* h1  = bufBig;
    short* XT2 = XT1;
    float* partial = (float*)fcb;

    dim3 blk(256);
    auto cgrid = [](long long n) { return dim3((unsigned)((n + 255) / 256)); };

    // ---- conversions to P8 (1 thread per 8-elem group) ----
    conv_p8<<<cgrid((long long)MR * 56), blk, 0, stream>>>(fc, fcb, MR, 400, 448, MR);
    conv_p8<<<cgrid(256 * 56), blk, 0, stream>>>(proj_w, projwb, 256, 400, 448, 256);
    conv_p8<<<cgrid(1536 * 32), blk, 0, stream>>>(enc_qkv_w, qkvwb, 1536, 256, 256, 1536);
    conv_p8<<<cgrid(512 * 32), blk, 0, stream>>>(enc_out_w, outwb, 512, 256, 256, 512);
    conv_p8<<<cgrid(2048 * 32), blk, 0, stream>>>(enc_l1_w, l1wb, 2048, 256, 256, 2048);
    conv_p8<<<cgrid(512 * 128), blk, 0, stream>>>(enc_l2_w, l2wb, 512, 1024, 1024, 512);
    conv_p8<<<cgrid(256 * 56), blk, 0, stream>>>(gcn_w1, gw1b, 256, 400, 448, 256);
    conv_p8<<<cgrid(256 * 32), blk, 0, stream>>>(gcn_w2, gw2b, 256, 256, 256, 256);
    conv_p8<<<cgrid(768 * 32), blk, 0, stream>>>(ca1_qkv_w, c1qb, 768, 256, 256, 768);
    conv_p8<<<cgrid(256 * 32), blk, 0, stream>>>(ca1_out_w, c1ob, 256, 256, 256, 256);
    conv_p8<<<cgrid(768 * 32), blk, 0, stream>>>(ca2_qkv_w, c2qb, 768, 256, 256, 768);
    conv_p8<<<cgrid(256 * 32), blk, 0, stream>>>(ca2_out_w, c2ob, 256, 256, 256, 256);
    w1_p8<<<800, blk, 0, stream>>>(cls_w1, w1b);

    // ---- FC branch ----
    gemm_p8<<<dim3(200, 2, 1), blk, 0, stream>>>(
        fcb, MR, 0, projwb, 256, 0, proj_b, bufH, MR, 0, 0, MR, 256, 256, 448, 0);
    for (int l = 0; l < 2; ++l) {
        gemm_p8<<<dim3(200, 6, 1), blk, 0, stream>>>(
            bufH, MR, 0, qkvwb + (size_t)l * 768 * 8, 1536, 0, enc_qkv_b + l * 768,
            bufBig, MR, 0, 0, MR, 768, 768, 256, 0);
        vtrans<<<dim3(1792), blk, 0, stream>>>(bufBig, vT);
        attn_p8<<<dim3(1792), blk, 0, stream>>>(bufBig, vT, bufA);
        // attn-out GEMM + residual + LN (in-place on bufH)
        gemm_ln<<<400, blk, 0, stream>>>(
            bufA, outwb + (size_t)l * 256 * 8, 512, enc_out_b + l * 256,
            bufH, enc_n1_g + l * DD, enc_n1_b + l * DD, bufH, 256);
        gemm_p8<<<dim3(200, 8, 1), blk, 0, stream>>>(
            bufH, MR, 0, l1wb + (size_t)l * 1024 * 8, 2048, 0, enc_l1_b + l * 1024,
            bufBig, MR, 0, 0, MR, 1024, 1024, 256, 1);
        // FF2 GEMM + residual + LN (in-place on bufH)
        gemm_ln<<<400, blk, 0, stream>>>(
            bufBig, l2wb + (size_t)l * 256 * 8, 512, enc_l2_b + l * 256,
            bufH, enc_n2_g + l * DD, enc_n2_b + l * DD, bufH, 1024);
    }

    // ---- GCN branch ----
    colsum_dinv<<<dim3(2, NB), blk, 0, stream>>>(sc, dinv);
    sc_prep<<<dim3(7, 7, NB), blk, 0, stream>>>(sc, dinv, scb, anT);
    gemm_p8<<<dim3(2, 4, NB), blk, 0, stream>>>(
        gw1b, 256, 0, scb, 512, 56LL * 512 * 8, nullptr,
        XT1, 256, 0, 56LL * 256 * 8, 256, 400, 448, 448, 0);
    gemm_p8<<<dim3(4, 2, NB), blk, 0, stream>>>(
        anT, 512, 56LL * 512 * 8, XT1, 256, 56LL * 256 * 8, gcn_b1,
        h1, 512, 0, 32LL * 512 * 8, 400, 256, 256, 448, 1);
    gemm_p8<<<dim3(2, 4, NB), blk, 0, stream>>>(
        gw2b, 256, 0, h1, 512, 32LL * 512 * 8, nullptr,
        XT2, 256, 0, 56LL * 256 * 8, 256, 400, 448, 256, 0);
    gemm_p8<<<dim3(4, 2, NB), blk, 0, stream>>>(
        anT, 512, 56LL * 512 * 8, XT2, 256, 56LL * 256 * 8, gcn_b2,
        bufZS, MR, 400, 0, 400, 256, 256, 448, 0);

    // ---- Cross attention 1: Q = Z_F, KV = Z_S ----
    gemm_p8<<<dim3(200, 2, 1), blk, 0, stream>>>(
        bufH, MR, 0, c1qb, 768, 0, ca1_qkv_b, bufBig, MR, 0, 0, MR, 256, 256, 256, 0);
    gemm_p8<<<dim3(200, 4, 1), blk, 0, stream>>>(
        bufZS, MR, 0, c1qb + 256 * 8, 768, 0, ca1_qkv_b + 256,
        bufBig + (size_t)32 * MR * 8, MR, 0, 0, MR, 512, 512, 256, 0);
    vtrans<<<dim3(1792), blk, 0, stream>>>(bufBig, vT);
    attn_p8<<<dim3(1792), blk, 0, stream>>>(bufBig, vT, bufA);
    gemm_ln<<<400, blk, 0, stream>>>(
        bufA, c1ob, 256, ca1_out_b, bufH, ca1_n_g, ca1_n_b, bufC, 256);

    // ---- Cross attention 2: Q = Z_S, KV = Z_F ----
    gemm_p8<<<dim3(200, 2, 1), blk, 0, stream>>>(
        bufZS, MR, 0, c2qb, 768, 0, ca2_qkv_b, bufBig, MR, 0, 0, MR, 256, 256, 256, 0);
    gemm_p8<<<dim3(200, 4, 1), blk, 0, stream>>>(
        bufH, MR, 0, c2qb + 256 * 8, 768, 0, ca2_qkv_b + 256,
        bufBig + (size_t)32 * MR * 8, MR, 0, 0, MR, 512, 512, 256, 0);
    vtrans<<<dim3(1792), blk, 0, stream>>>(bufBig, vT);
    attn_p8<<<dim3(1792), blk, 0, stream>>>(bufBig, vT, bufA);
    gemm_ln<<<400, blk, 0, stream>>>(
        bufA, c2ob, 256, ca2_out_b, bufZS, ca2_n_g, ca2_n_b, bufZS, 256);

    // ---- Classifier ----
    cls_gemm<<<400, blk, 0, stream>>>(bufC, bufZS, w1b, partial);
    cls_reduce<<<32, blk, 0, stream>>>(partial, clsh);
    logits_final<<<NB, 128, 0, stream>>>(clsh, cls_b1, cls_w2, cls_b2, (float*)d_out);
}

// Round 8
// 970.305 us; speedup vs baseline: 1.0512x; 1.0512x over previous
//
#include <hip/hip_runtime.h>
#include <math.h>

// Problem constants
#define NB   64
#define NN   400
#define DD   256
#define NHH  4
#define HDD  64
#define MR   25600            // NB*NN

typedef __attribute__((ext_vector_type(8))) short bf16x8;
typedef __attribute__((ext_vector_type(4))) float f32x4;

__device__ __forceinline__ short f2bf(float x) {
    union { float f; unsigned u; } v; v.f = x;
    return (short)((v.u + 0x7FFFu + ((v.u >> 16) & 1u)) >> 16);
}
__device__ __forceinline__ float bf2f(short s) {
    union { unsigned u; float f; } v; v.u = ((unsigned)(unsigned short)s) << 16;
    return v.f;
}
// async global->LDS, 16 B/lane; src = per-lane addr, LDS dest = wave-uniform base
__device__ __forceinline__ void gl_lds16(const void* g, void* l) {
    __builtin_amdgcn_global_load_lds(
        (const __attribute__((address_space(1))) unsigned*)g,
        (__attribute__((address_space(3))) unsigned*)l, 16, 0, 0);
}
// counted vmcnt wait (T4): never drain to 0 in a main loop. "memory" clobber
// orders LDS reads after the wait at IR level.
__device__ __forceinline__ void wait_vmcnt(int n) {
    switch (n) {
    case 0: asm volatile("s_waitcnt vmcnt(0)" ::: "memory"); break;
    case 1: asm volatile("s_waitcnt vmcnt(1)" ::: "memory"); break;
    case 2: asm volatile("s_waitcnt vmcnt(2)" ::: "memory"); break;
    case 3: asm volatile("s_waitcnt vmcnt(3)" ::: "memory"); break;
    case 4: asm volatile("s_waitcnt vmcnt(4)" ::: "memory"); break;
    default: asm volatile("s_waitcnt vmcnt(5)" ::: "memory"); break;
    }
}
__device__ __forceinline__ void barrier_raw() {
    __builtin_amdgcn_sched_barrier(0);
    __builtin_amdgcn_s_barrier();
    __builtin_amdgcn_sched_barrier(0);
}

// ---------------------------------------------------------------------------
// P8 layout: element (row, k) lives at ((k>>3)*rows + row)*8 + (k&7) (bf16).
// = the 16x16x32 MFMA fragment layout; staging is contiguous 1 KiB bursts.
// ---------------------------------------------------------------------------

// bf16 GEMM, 128x128 tile, BK=32, 3 staging buffers, 2-deep counted-vmcnt
// pipeline (REVERTED to the measured-best Round-2 form: all-global K-loop
// regressed 46->55 us — register DB cost + lost LDS sharing).
__global__ __launch_bounds__(256) void gemm_p8(
    const short* __restrict__ A, int arows, long long sA,
    const short* __restrict__ B, int brows, long long sB,
    const float* __restrict__ bias,
    short* __restrict__ C, int crows, int crz, long long sCe,
    int M, int N, int Npad, int K, int relu)
{
    __shared__ short lds[24576];   // 3 bufs of 8192 (A 4096 + B 4096); epilogue reuses [0..17407]
    const int tid = threadIdx.x;
    const int z = blockIdx.z;
    const int m0 = blockIdx.x * 128, n0 = blockIdx.y * 128;
    const short* Ab = A + (size_t)z * sA;
    const short* Bb = B + (size_t)z * sB;

    const int w = tid >> 6, lane = tid & 63;
    const int quad = lane >> 4, l15 = lane & 15;
    const int wm = w & 1, wn = w >> 1;

    f32x4 acc[4][4] = {};

    const int KT = K >> 5;          // steps of 32 k (4 planes)

    auto STAGE = [&](int buf, int kt) {
        const int gp0 = kt << 2;
        short* Al = lds + buf * 8192;
        short* Bl = Al + 4096;
        // 16 chunks (8 A + 8 B), 4 per wave; p = plane(0..3), h = row-half
#pragma unroll
        for (int i = 0; i < 4; ++i) {
            int c = i * 4 + w;
            int p = (c >> 1) & 3, hh = c & 1;
            if (c < 8)
                gl_lds16(Ab + ((size_t)(gp0 + p) * arows + m0 + hh * 64 + lane) * 8,
                         &Al[(p * 128 + hh * 64) * 8]);
            else
                gl_lds16(Bb + ((size_t)(gp0 + p) * brows + n0 + hh * 64 + lane) * 8,
                         &Bl[(p * 128 + hh * 64) * 8]);
        }
    };

    STAGE(0, 0);
    STAGE(1, 1);
    for (int kt = 0; kt < KT; ++kt) {
        wait_vmcnt(kt + 1 < KT ? 4 : 0);   // chunk kt complete; kt+1 stays in flight
        barrier_raw();
        if (kt + 2 < KT) STAGE((kt + 2) % 3, kt + 2);
        const short* Al = lds + (kt % 3) * 8192;
        const short* Bl = Al + 4096;
        bf16x8 af[4], bfr[4];
#pragma unroll
        for (int mi = 0; mi < 4; ++mi)
            af[mi] = *reinterpret_cast<const bf16x8*>(
                &Al[(quad * 128 + wm * 64 + mi * 16 + l15) * 8]);
#pragma unroll
        for (int ni = 0; ni < 4; ++ni)
            bfr[ni] = *reinterpret_cast<const bf16x8*>(
                &Bl[(quad * 128 + wn * 64 + ni * 16 + l15) * 8]);
#pragma unroll
        for (int mi = 0; mi < 4; ++mi)
#pragma unroll
            for (int ni = 0; ni < 4; ++ni)
                acc[mi][ni] = __builtin_amdgcn_mfma_f32_16x16x32_bf16(af[mi], bfr[ni], acc[mi][ni], 0, 0, 0);
    }
    __syncthreads();   // all waves done reading staging before epilogue overwrite

    // epilogue: acc -> bf16 row-major LDS tile, then 16 B coalesced stores
#pragma unroll
    for (int mi = 0; mi < 4; ++mi) {
#pragma unroll
        for (int r = 0; r < 4; ++r) {
            int row = wm * 64 + mi * 16 + quad * 4 + r;
#pragma unroll
            for (int ni = 0; ni < 4; ++ni) {
                int col = wn * 64 + ni * 16 + l15;
                int gcol = n0 + col;
                float v = 0.0f;
                if (gcol < N) {
                    v = acc[mi][ni][r];
                    if (bias) v += bias[gcol];
                    if (relu) v = fmaxf(v, 0.0f);
                }
                lds[row * 136 + col] = f2bf(v);
            }
        }
    }
    __syncthreads();
    short* Cbz = C + (size_t)z * sCe;
    const long long zr = (long long)z * crz;
#pragma unroll
    for (int t = 0; t < 8; ++t) {
        int c = t * 256 + tid;
        int row = c & 127, p16 = c >> 7;
        int grow = m0 + row;
        int gcol0 = n0 + p16 * 8;
        if (grow < M && gcol0 < Npad) {
            bf16x8 v = *reinterpret_cast<const bf16x8*>(&lds[row * 136 + p16 * 8]);
            *reinterpret_cast<bf16x8*>(
                &Cbz[((size_t)(gcol0 >> 3) * crows + zr + grow) * 8]) = v;
        }
    }
}

// ---------------------------------------------------------------------------
// Fused GEMM (N=256) + residual + LayerNorm. Tile 64m x 256n; BK=32, 3
// staging buffers, 2-deep counted-vmcnt pipeline. NEW wave decomposition:
// wave w owns COLS w*64..w*64+64 (4 m-frags x 4 n-frags) -> 8 ds_read_b128
// per step instead of 17 (old 16-rows-per-wave redundantly read all 16
// B-frags in every wave). Same MFMA count, same acc registers.
// out[row] = LN(resid[row] + bf16(A·B^T + bias)) * g + b.  K % 64 == 0.
// ---------------------------------------------------------------------------
__global__ __launch_bounds__(256) void gemm_ln(
    const short* __restrict__ A,
    const short* __restrict__ B, int brows,
    const float* __restrict__ bias,
    const short* __restrict__ resid,
    const float* __restrict__ g, const float* __restrict__ bb,
    short* __restrict__ out, int K)
{
    __shared__ short lds[30720];        // 3 bufs of 10240: A [0,2048) B [2048,10240); epilogue rowt[64][264]
    __shared__ float gs[256], bs[256], bi_s[256];
    __shared__ float red[2][4][64];
    const int tid = threadIdx.x;
    const int m0 = blockIdx.x * 64;
    const int w = tid >> 6, lane = tid & 63;
    const int quad = lane >> 4, l15 = lane & 15;
    gs[tid] = g[tid]; bs[tid] = bb[tid]; bi_s[tid] = bias[tid];

    f32x4 acc[4][4] = {};
    const int KT = K >> 5;

    auto STAGE = [&](int buf, int kt) {
        const int gp0 = kt << 2;
        short* Al = lds + buf * 10240;
        short* Bl = Al + 2048;
        // 20 chunks (4 A + 16 B), 5 per wave
#pragma unroll
        for (int i = 0; i < 5; ++i) {
            int c = i * 4 + w;
            if (c < 4) {
                gl_lds16(A + ((size_t)(gp0 + c) * MR + m0 + lane) * 8, &Al[(c * 64) * 8]);
            } else {
                int cb = c - 4, p = cb >> 2, cq = cb & 3;
                gl_lds16(B + ((size_t)(gp0 + p) * brows + cq * 64 + lane) * 8,
                         &Bl[(p * 256 + cq * 64) * 8]);
            }
        }
    };

    STAGE(0, 0);
    STAGE(1, 1);
    for (int kt = 0; kt < KT; ++kt) {
        wait_vmcnt(kt + 1 < KT ? 5 : 0);
        barrier_raw();
        if (kt + 2 < KT) STAGE((kt + 2) % 3, kt + 2);
        const short* Al = lds + (kt % 3) * 10240;
        const short* Bl = Al + 2048;
        bf16x8 af[4], bfr[4];
#pragma unroll
        for (int mi = 0; mi < 4; ++mi)
            af[mi] = *reinterpret_cast<const bf16x8*>(
                &Al[(quad * 64 + mi * 16 + l15) * 8]);
#pragma unroll
        for (int ni = 0; ni < 4; ++ni)
            bfr[ni] = *reinterpret_cast<const bf16x8*>(
                &Bl[(quad * 256 + w * 64 + ni * 16 + l15) * 8]);
#pragma unroll
        for (int mi = 0; mi < 4; ++mi)
#pragma unroll
            for (int ni = 0; ni < 4; ++ni)
                acc[mi][ni] = __builtin_amdgcn_mfma_f32_16x16x32_bf16(af[mi], bfr[ni], acc[mi][ni], 0, 0, 0);
    }
    __syncthreads();   // staging reads complete before rowt overwrite

    // epilogue 1: bias add, round to bf16, into row-tile rowt[64][4 groups][66]
    // (66-stride breaks bank alignment). part = w (this wave's col quarter).
    short* rowt = lds;
#pragma unroll
    for (int mi = 0; mi < 4; ++mi)
#pragma unroll
        for (int ni = 0; ni < 4; ++ni) {
            int col = w * 64 + ni * 16 + l15;
#pragma unroll
            for (int r = 0; r < 4; ++r) {
                int row = mi * 16 + quad * 4 + r;
                rowt[row * 264 + w * 66 + ni * 16 + l15] = f2bf(acc[mi][ni][r] + bi_s[col]);
            }
        }
    __syncthreads();

    // epilogue 2: thread = (row, quarter): add residual, reduce, normalize
    const int row = tid >> 2, part = tid & 3;
    const int grow = m0 + row;
    float vv[8][8];
    float sum = 0.0f, sq = 0.0f;
#pragma unroll
    for (int i = 0; i < 8; ++i) {
        int plane = part * 8 + i;
        bf16x8 rv = *reinterpret_cast<const bf16x8*>(resid + ((size_t)plane * MR + grow) * 8);
        bf16x8 tv = *reinterpret_cast<const bf16x8*>(&rowt[row * 264 + part * 66 + i * 8]);
#pragma unroll
        for (int e = 0; e < 8; ++e) {
            float v = bf2f(tv[e]) + bf2f(rv[e]);
            vv[i][e] = v; sum += v; sq += v * v;
        }
    }
    red[0][part][row] = sum; red[1][part][row] = sq;
    __syncthreads();
    sum = red[0][0][row] + red[0][1][row] + red[0][2][row] + red[0][3][row];
    sq  = red[1][0][row] + red[1][1][row] + red[1][2][row] + red[1][3][row];
    float mu = sum * (1.0f / 256.0f);
    float var = sq * (1.0f / 256.0f) - mu * mu;
    float rstd = 1.0f / sqrtf(fmaxf(var, 0.0f) + 1e-5f);
#pragma unroll
    for (int i = 0; i < 8; ++i) {
        int plane = part * 8 + i;
        bf16x8 o;
#pragma unroll
        for (int e = 0; e < 8; ++e)
            o[e] = f2bf((vv[i][e] - mu) * rstd * gs[plane * 8 + e] + bs[plane * 8 + e]);
        *reinterpret_cast<bf16x8*>(out + ((size_t)plane * MR + grow) * 8) = o;
    }
}

// ---------------------------------------------------------------------------
// V transpose: per (b,h), vT[(bh*56 + kp)*64 + d]*8 + (key&7) = V[key][d],
// keys >= 400 zeroed. XCD-swizzled 1D grid (1792 = 8*224): all chunks of a
// (b,h) run on XCD bh%8 -> vT lands in the L2 that attn_p8 will read it from.
// ---------------------------------------------------------------------------
__global__ __launch_bounds__(256) void vtrans(
    const short* __restrict__ qkv, short* __restrict__ vT)
{
    __shared__ short tile[64][66];
    const int id = blockIdx.x;
    const int xcd = id & 7, rem = id >> 3;
    const int bh_hi = rem / 7, c = rem - bh_hi * 7;
    const int bh_i = bh_hi * 8 + xcd;
    const int h = bh_i & 3, b = bh_i >> 2;
    const int tid = threadIdx.x;
    const size_t bh = (size_t)bh_i;
    for (int t = tid; t < 512; t += 256) {
        int pp = t >> 6, l = t & 63;
        int j = c * 64 + l;
        bf16x8 v;
        if (j < NN)
            v = *reinterpret_cast<const bf16x8*>(
                qkv + (((size_t)(64 + 8 * h + pp)) * MR + (size_t)b * NN + j) * 8);
        else { for (int e = 0; e < 8; ++e) v[e] = 0; }
#pragma unroll
        for (int e = 0; e < 8; ++e) tile[l][pp * 8 + e] = v[e];
    }
    __syncthreads();
    for (int t = tid; t < 512; t += 256) {
        int kq = t >> 6, d = t & 63;
        int kp = c * 8 + kq;
        bf16x8 o;
#pragma unroll
        for (int e = 0; e < 8; ++e) o[e] = tile[kq * 8 + e][d];
        *reinterpret_cast<bf16x8*>(vT + ((bh * 56 + kp) * 64 + d) * 8) = o;
    }
}

// ---------------------------------------------------------------------------
// Attention, LDS-minimal: K and V fragments are read STRAIGHT FROM GLOBAL
// (both are L2-resident on this block's XCD thanks to the swizzle, and both
// access patterns are 16 lanes x 16B contiguous per quad = fully coalesced).
// LDS holds only the P tile (and transiently Q) -> 52 KB -> 3 blocks/CU.
// Barriers per block: 3. PV loop is barrier-free.
// ---------------------------------------------------------------------------
__global__ __launch_bounds__(256, 3) void attn_p8(
    const short* __restrict__ qkv, const short* __restrict__ vT,
    short* __restrict__ Out)
{
    __shared__ short PS[26624];   // P: 52 planes x 64 rows x 8 (53248 B); [0..4096) doubles as Q staging
    const int id = blockIdx.x;
    const int xcd = id & 7, rem = id >> 3;
    const int bh_hi = rem / 7, qt = rem - bh_hi * 7;
    const int bh_i = bh_hi * 8 + xcd;
    const int h = bh_i & 3, b = bh_i >> 2;
    const int tid = threadIdx.x;
    const int w = tid >> 6, lane = tid & 63;
    const int quad = lane >> 4, l15 = lane & 15;
    const size_t rowb = (size_t)b * NN;

    // stage Q (8 planes x 64 rows) into PS[0..4096)
    for (int j = w; j < 8; j += 4)
        gl_lds16(qkv + (((size_t)(8 * h + j)) * MR + rowb + qt * 64 + lane) * 8, &PS[j * 512]);
    __syncthreads();

    bf16x8 aq0 = *reinterpret_cast<const bf16x8*>(&PS[(quad * 64 + w * 16 + l15) * 8]);
    bf16x8 aq1 = *reinterpret_cast<const bf16x8*>(&PS[((4 + quad) * 64 + w * 16 + l15) * 8]);

    // QK^T: K fragment for (nt, quad) = 16B at plane (32+8h+quad), key nt*16+l15
    const short* Kb0 = qkv + ((size_t)(32 + 8 * h + quad) * MR + rowb + l15) * 8;
    const short* Kb1 = qkv + ((size_t)(36 + 8 * h + quad) * MR + rowb + l15) * 8;

    f32x4 sacc[25];
#pragma unroll
    for (int nt = 0; nt < 25; ++nt) { sacc[nt][0] = 0; sacc[nt][1] = 0; sacc[nt][2] = 0; sacc[nt][3] = 0; }
#pragma unroll
    for (int nt = 0; nt < 25; ++nt) {
        bf16x8 b0 = *reinterpret_cast<const bf16x8*>(Kb0 + nt * 128);
        bf16x8 b1 = *reinterpret_cast<const bf16x8*>(Kb1 + nt * 128);
        sacc[nt] = __builtin_amdgcn_mfma_f32_16x16x32_bf16(aq0, b0, sacc[nt], 0, 0, 0);
        sacc[nt] = __builtin_amdgcn_mfma_f32_16x16x32_bf16(aq1, b1, sacc[nt], 0, 0, 0);
    }

    float mx[4] = {-3e38f, -3e38f, -3e38f, -3e38f}, sm[4] = {0, 0, 0, 0};
#pragma unroll
    for (int nt = 0; nt < 25; ++nt)
#pragma unroll
        for (int r = 0; r < 4; ++r) mx[r] = fmaxf(mx[r], sacc[nt][r]);
#pragma unroll
    for (int r = 0; r < 4; ++r) {
        mx[r] = fmaxf(mx[r], __shfl_xor(mx[r], 1));
        mx[r] = fmaxf(mx[r], __shfl_xor(mx[r], 2));
        mx[r] = fmaxf(mx[r], __shfl_xor(mx[r], 4));
        mx[r] = fmaxf(mx[r], __shfl_xor(mx[r], 8));
    }
#pragma unroll
    for (int nt = 0; nt < 25; ++nt)
#pragma unroll
        for (int r = 0; r < 4; ++r) {
            float e = __expf((sacc[nt][r] - mx[r]) * 0.125f);
            sacc[nt][r] = e;
            sm[r] += e;
        }
#pragma unroll
    for (int r = 0; r < 4; ++r) {
        sm[r] += __shfl_xor(sm[r], 1);
        sm[r] += __shfl_xor(sm[r], 2);
        sm[r] += __shfl_xor(sm[r], 4);
        sm[r] += __shfl_xor(sm[r], 8);
    }
    __syncthreads();   // Q LDS reads complete -> P may overwrite PS

    // P transpose into PS (C-layout -> A-fragment layout), keys>=400 zeroed
#pragma unroll
    for (int nt = 0; nt < 25; ++nt)
#pragma unroll
        for (int r = 0; r < 4; ++r) {
            int colk = nt * 16 + l15;
            PS[((colk >> 3) * 64 + w * 16 + quad * 4 + r) * 8 + (colk & 7)] = f2bf(sacc[nt][r]);
        }
    for (int idx = tid; idx < 1024; idx += 256) PS[25600 + idx] = 0;

    f32x4 oacc[4];
#pragma unroll
    for (int dt = 0; dt < 4; ++dt) { oacc[dt][0] = 0; oacc[dt][1] = 0; oacc[dt][2] = 0; oacc[dt][3] = 0; }
    __syncthreads();   // P visible to all waves

    // PV, barrier-free: V fragment for (kt, quad, dt) = 16B at vT plane
    // bh*56 + kt*4 + quad, d = dt*16 + l15 (L2-resident, coalesced).
    const short* Vb = vT + (((size_t)bh_i * 56 + quad) * 64 + l15) * 8;
#pragma unroll
    for (int kt = 0; kt < 13; ++kt) {
        bf16x8 pa = *reinterpret_cast<const bf16x8*>(
            &PS[((kt * 4 + quad) * 64 + w * 16 + l15) * 8]);
#pragma unroll
        for (int dt = 0; dt < 4; ++dt) {
            bf16x8 vb = *reinterpret_cast<const bf16x8*>(Vb + kt * 2048 + dt * 128);
            oacc[dt] = __builtin_amdgcn_mfma_f32_16x16x32_bf16(pa, vb, oacc[dt], 0, 0, 0);
        }
    }
#pragma unroll
    for (int r = 0; r < 4; ++r) {
        int row = qt * 64 + w * 16 + quad * 4 + r;
        if (row >= NN) continue;
        float inv = 1.0f / sm[r];
#pragma unroll
        for (int dt = 0; dt < 4; ++dt) {
            int col = dt * 16 + l15;
            Out[(((size_t)(8 * h + (col >> 3))) * MR + rowb + row) * 8 + (col & 7)] =
                f2bf(oacc[dt][r] * inv);
        }
    }
}

// ---------------------------------------------------------------------------
// vectorized f32 -> P8 conversion: one thread per (row, 8-col group);
// float4 x2 reads, one bf16x8 store.
// ---------------------------------------------------------------------------
__global__ void conv_p8(const float* __restrict__ src, short* __restrict__ dst,
                        int R, int K, int Kp, int PR)
{
    const int G = Kp >> 3;
    int idx = blockIdx.x * 256 + threadIdx.x;
    if (idx >= R * G) return;
    int r = idx / G, g = idx - r * G;
    int k0 = g << 3;
    bf16x8 o;
    if (k0 + 8 <= K) {
        const float4 v0 = *reinterpret_cast<const float4*>(src + (size_t)r * K + k0);
        const float4 v1 = *reinterpret_cast<const float4*>(src + (size_t)r * K + k0 + 4);
        o[0] = f2bf(v0.x); o[1] = f2bf(v0.y); o[2] = f2bf(v0.z); o[3] = f2bf(v0.w);
        o[4] = f2bf(v1.x); o[5] = f2bf(v1.y); o[6] = f2bf(v1.z); o[7] = f2bf(v1.w);
    } else {
#pragma unroll
        for (int e = 0; e < 8; ++e) {
            int k = k0 + e;
            o[e] = (k < K) ? f2bf(src[(size_t)r * K + k]) : (short)0;
        }
    }
    *reinterpret_cast<bf16x8*>(dst + ((size_t)g * PR + r) * 8) = o;
}

// ---------------------------------------------------------------------------
__global__ __launch_bounds__(256) void w1_p8(
    const float* __restrict__ W1, short* __restrict__ Wp)
{
    __shared__ float tile[128][129];
    const int k0 = blockIdx.x * 128;
    const int tid = threadIdx.x;
    for (int t = 0; t < 16; ++t) {
        int idx = t * 256 + tid;
        int r = idx >> 5, k4 = idx & 31;
        float4 v = *(const float4*)(W1 + (size_t)r * 102400 + k0 + k4 * 4);
        tile[r][k4 * 4 + 0] = v.x; tile[r][k4 * 4 + 1] = v.y;
        tile[r][k4 * 4 + 2] = v.z; tile[r][k4 * 4 + 3] = v.w;
    }
    __syncthreads();
    for (int t = 0; t < 8; ++t) {
        int idx = t * 256 + tid;
        int pidx = idx >> 7, r = idx & 127;
        bf16x8 o;
#pragma unroll
        for (int e = 0; e < 8; ++e) o[e] = f2bf(tile[r][pidx * 8 + e]);
        *reinterpret_cast<bf16x8*>(Wp + (((size_t)(k0 >> 3) + pidx) * 128 + r) * 8) = o;
    }
}

// ---------------------------------------------------------------------------
__global__ void colsum_dinv(const float* __restrict__ sc, float* __restrict__ dinv)
{
    int b = blockIdx.y;
    int j = blockIdx.x * 256 + threadIdx.x;
    if (j >= NN) return;
    const float* p = sc + (size_t)b * NN * NN + j;
    float s = 0.0f;
    for (int i = 0; i < NN; ++i) s += p[(size_t)i * NN];
    dinv[b * NN + j] = (s > 0.0f) ? 1.0f / sqrtf(s) : 0.0f;
}

// ---------------------------------------------------------------------------
__global__ __launch_bounds__(256) void sc_prep(
    const float* __restrict__ sc, const float* __restrict__ dinv,
    short* __restrict__ scb, short* __restrict__ anT)
{
    __shared__ float tile[64][65];
    const int b = blockIdx.z;
    const int i0 = blockIdx.y * 64, j0 = blockIdx.x * 64;
    const int tid = threadIdx.x;
    const float* sb = sc + (size_t)b * NN * NN;
    short* scbb = scb + (size_t)b * 56 * 512 * 8;
    short* anTb = anT + (size_t)b * 56 * 512 * 8;
    for (int e = tid; e < 4096; e += 256) {
        int r = e >> 6, c = e & 63;
        int i = i0 + r, j = j0 + c;
        tile[r][c] = (i < NN && j < NN) ? sb[(size_t)i * NN + j] : 0.0f;
    }
    __syncthreads();
    for (int e = tid; e < 4096; e += 256) {
        int r = e >> 6, c = e & 63;
        int i = i0 + r, j = j0 + c;
        scbb[((size_t)(j >> 3) * 512 + i) * 8 + (j & 7)] = f2bf(tile[r][c]);
        float v = 0.0f;
        if (i < NN && j < NN) v = tile[r][c] * dinv[b * NN + i] * dinv[b * NN + j];
        anTb[((size_t)(i >> 3) * 512 + j) * 8 + (i & 7)] = f2bf(v);
    }
}

// ---------------------------------------------------------------------------
__global__ __launch_bounds__(256) void cls_gemm(
    const short* __restrict__ C1, const short* __restrict__ C2,
    const short* __restrict__ Wp, float* __restrict__ partial)
{
    __shared__ short Al[32 * 64 * 8];
    __shared__ short Wl[8 * 128 * 8];
    const int j = blockIdx.x;
    const int tid = threadIdx.x;
    const int w = tid >> 6, lane = tid & 63;
    const int quad = lane >> 4, l15 = lane & 15;

    for (int s = 0; s < 8; ++s) {
        int idx = s * 256 + tid;
        int p = idx >> 6, b = idx & 63;
        size_t ad = ((size_t)p * MR + (size_t)b * NN + j) * 8;
        bf16x8 a = *reinterpret_cast<const bf16x8*>(C1 + ad);
        bf16x8 c = *reinterpret_cast<const bf16x8*>(C2 + ad);
        bf16x8 o;
#pragma unroll
        for (int e = 0; e < 8; ++e) o[e] = f2bf(0.5f * (bf2f(a[e]) + bf2f(c[e])));
        *reinterpret_cast<bf16x8*>(&Al[(p * 64 + b) * 8]) = o;
    }

    f32x4 acc[4][2] = {};
    const size_t wp0 = (size_t)j * 32;
    for (int s = 0; s < 4; ++s) {
#pragma unroll
        for (int pp = 0; pp < 2; ++pp) {
            int p = w + pp * 4;
            gl_lds16(Wp + ((wp0 + s * 8 + p) * 128 + lane) * 8,      &Wl[(p * 128) * 8]);
            gl_lds16(Wp + ((wp0 + s * 8 + p) * 128 + 64 + lane) * 8, &Wl[(p * 128 + 64) * 8]);
        }
        __syncthreads();
#pragma unroll
        for (int kb = 0; kb < 2; ++kb) {
            bf16x8 af[4], bfr[2];
#pragma unroll
            for (int mi = 0; mi < 4; ++mi)
                af[mi] = *reinterpret_cast<const bf16x8*>(
                    &Al[((s * 8 + kb * 4 + quad) * 64 + mi * 16 + l15) * 8]);
#pragma unroll
            for (int ni = 0; ni < 2; ++ni)
                bfr[ni] = *reinterpret_cast<const bf16x8*>(
                    &Wl[((kb * 4 + quad) * 128 + w * 32 + ni * 16 + l15) * 8]);
#pragma unroll
            for (int mi = 0; mi < 4; ++mi)
#pragma unroll
                for (int ni = 0; ni < 2; ++ni)
                    acc[mi][ni] = __builtin_amdgcn_mfma_f32_16x16x32_bf16(af[mi], bfr[ni], acc[mi][ni], 0, 0, 0);
        }
        __syncthreads();
    }
    float* pj = partial + (size_t)j * 8192;
#pragma unroll
    for (int mi = 0; mi < 4; ++mi)
#pragma unroll
        for (int r = 0; r < 4; ++r) {
            int row = mi * 16 + quad * 4 + r;
#pragma unroll
            for (int ni = 0; ni < 2; ++ni)
                pj[row * 128 + w * 32 + ni * 16 + l15] = acc[mi][ni][r];
        }
}

__global__ void cls_reduce(const float* __restrict__ partial, float* __restrict__ clsh)
{
    int o = blockIdx.x * 256 + threadIdx.x;
    float s = 0.0f;
    for (int kb = 0; kb < 400; ++kb) s += partial[(size_t)kb * 8192 + o];
    clsh[o] = s;
}

__global__ void logits_final(
    const float* __restrict__ clsh, const float* __restrict__ b1,
    const float* __restrict__ w2, const float* __restrict__ b2,
    float* __restrict__ out)
{
    __shared__ float t[128];
    int b = blockIdx.x;
    int tid = threadIdx.x;
    t[tid] = fmaxf(clsh[b * 128 + tid] + b1[tid], 0.0f);
    __syncthreads();
    if (tid < 2) {
        float s = b2[tid];
        for (int o = 0; o < 128; ++o) s += t[o] * w2[tid * 128 + o];
        out[b * 2 + tid] = s;
    }
}

// ---------------------------------------------------------------------------
extern "C" void kernel_launch(void* const* d_in, const int* in_sizes, int n_in,
                              void* d_out, int out_size, void* d_ws, size_t ws_size,
                              hipStream_t stream)
{
    const float* fc        = (const float*)d_in[0];
    const float* sc        = (const float*)d_in[1];
    const float* proj_w    = (const float*)d_in[2];
    const float* proj_b    = (const float*)d_in[3];
    const float* enc_qkv_w = (const float*)d_in[4];
    const float* enc_qkv_b = (const float*)d_in[5];
    const float* enc_out_w = (const float*)d_in[6];
    const float* enc_out_b = (const float*)d_in[7];
    const float* enc_l1_w  = (const float*)d_in[8];
    const float* enc_l1_b  = (const float*)d_in[9];
    const float* enc_l2_w  = (const float*)d_in[10];
    const float* enc_l2_b  = (const float*)d_in[11];
    const float* enc_n1_g  = (const float*)d_in[12];
    const float* enc_n1_b  = (const float*)d_in[13];
    const float* enc_n2_g  = (const float*)d_in[14];
    const float* enc_n2_b  = (const float*)d_in[15];
    const float* gcn_w1    = (const float*)d_in[16];
    const float* gcn_b1    = (const float*)d_in[17];
    const float* gcn_w2    = (const float*)d_in[18];
    const float* gcn_b2    = (const float*)d_in[19];
    const float* ca1_qkv_w = (const float*)d_in[20];
    const float* ca1_qkv_b = (const float*)d_in[21];
    const float* ca1_out_w = (const float*)d_in[22];
    const float* ca1_out_b = (const float*)d_in[23];
    const float* ca1_n_g   = (const float*)d_in[24];
    const float* ca1_n_b   = (const float*)d_in[25];
    const float* ca2_qkv_w = (const float*)d_in[26];
    const float* ca2_qkv_b = (const float*)d_in[27];
    const float* ca2_out_w = (const float*)d_in[28];
    const float* ca2_out_b = (const float*)d_in[29];
    const float* ca2_n_g   = (const float*)d_in[30];
    const float* ca2_n_b   = (const float*)d_in[31];
    const float* cls_w1    = (const float*)d_in[32];
    const float* cls_b1    = (const float*)d_in[33];
    const float* cls_w2    = (const float*)d_in[34];
    const float* cls_b2    = (const float*)d_in[35];

    char* wsb = (char*)d_ws;
    size_t off = 0;
    auto alloc = [&](size_t bytes) { char* r = wsb + off; off += (bytes + 255) & ~(size_t)255; return r; };
    short* bufBig = (short*)alloc((size_t)MR * 1024 * 2);
    short* fcb    = (short*)alloc((size_t)56 * MR * 8 * 2);
    short* anT    = (short*)alloc((size_t)NB * 56 * 512 * 8 * 2);
    short* bufH   = (short*)alloc((size_t)32 * MR * 8 * 2);
    short* bufA   = (short*)alloc((size_t)32 * MR * 8 * 2);
    short* bufC   = (short*)alloc((size_t)32 * MR * 8 * 2);
    short* bufZS  = (short*)alloc((size_t)32 * MR * 8 * 2);
    short* vT     = (short*)alloc((size_t)NB * NHH * 56 * 64 * 8 * 2);
    short* w1b    = (short*)alloc((size_t)12800 * 128 * 8 * 2);
    short* projwb = (short*)alloc((size_t)56 * 256 * 8 * 2);
    short* qkvwb  = (short*)alloc((size_t)32 * 1536 * 8 * 2);
    short* outwb  = (short*)alloc((size_t)32 * 512 * 8 * 2);
    short* l1wb   = (short*)alloc((size_t)32 * 2048 * 8 * 2);
    short* l2wb   = (short*)alloc((size_t)128 * 512 * 8 * 2);
    short* gw1b   = (short*)alloc((size_t)56 * 256 * 8 * 2);
    short* gw2b   = (short*)alloc((size_t)32 * 256 * 8 * 2);
    short* c1qb   = (short*)alloc((size_t)32 * 768 * 8 * 2);
    short* c1ob   = (short*)alloc((size_t)32 * 256 * 8 * 2);
    short* c2qb   = (short*)alloc((size_t)32 * 768 * 8 * 2);
    short* c2ob   = (short*)alloc((size_t)32 * 256 * 8 * 2);
    float* dinv   = (float*)alloc((size_t)MR * 4);
    float* clsh   = (float*)alloc((size_t)NB * 128 * 4);
    short* scb = bufBig;
    short* XT1 = bufBig + (size_t)64 * 56 * 512 * 8;
    short* h1  = bufBig;
    short* XT2 = XT1;
    float* partial = (float*)fcb;

    dim3 blk(256);
    auto cgrid = [](long long n) { return dim3((unsigned)((n + 255) / 256)); };

    // ---- conversions to P8 (1 thread per 8-elem group) ----
    conv_p8<<<cgrid((long long)MR * 56), blk, 0, stream>>>(fc, fcb, MR, 400, 448, MR);
    conv_p8<<<cgrid(256 * 56), blk, 0, stream>>>(proj_w, projwb, 256, 400, 448, 256);
    conv_p8<<<cgrid(1536 * 32), blk, 0, stream>>>(enc_qkv_w, qkvwb, 1536, 256, 256, 1536);
    conv_p8<<<cgrid(512 * 32), blk, 0, stream>>>(enc_out_w, outwb, 512, 256, 256, 512);
    conv_p8<<<cgrid(2048 * 32), blk, 0, stream>>>(enc_l1_w, l1wb, 2048, 256, 256, 2048);
    conv_p8<<<cgrid(512 * 128), blk, 0, stream>>>(enc_l2_w, l2wb, 512, 1024, 1024, 512);
    conv_p8<<<cgrid(256 * 56), blk, 0, stream>>>(gcn_w1, gw1b, 256, 400, 448, 256);
    conv_p8<<<cgrid(256 * 32), blk, 0, stream>>>(gcn_w2, gw2b, 256, 256, 256, 256);
    conv_p8<<<cgrid(768 * 32), blk, 0, stream>>>(ca1_qkv_w, c1qb, 768, 256, 256, 768);
    conv_p8<<<cgrid(256 * 32), blk, 0, stream>>>(ca1_out_w, c1ob, 256, 256, 256, 256);
    conv_p8<<<cgrid(768 * 32), blk, 0, stream>>>(ca2_qkv_w, c2qb, 768, 256, 256, 768);
    conv_p8<<<cgrid(256 * 32), blk, 0, stream>>>(ca2_out_w, c2ob, 256, 256, 256, 256);
    w1_p8<<<800, blk, 0, stream>>>(cls_w1, w1b);

    // ---- FC branch ----
    gemm_p8<<<dim3(200, 2, 1), blk, 0, stream>>>(
        fcb, MR, 0, projwb, 256, 0, proj_b, bufH, MR, 0, 0, MR, 256, 256, 448, 0);
    for (int l = 0; l < 2; ++l) {
        gemm_p8<<<dim3(200, 6, 1), blk, 0, stream>>>(
            bufH, MR, 0, qkvwb + (size_t)l * 768 * 8, 1536, 0, enc_qkv_b + l * 768,
            bufBig, MR, 0, 0, MR, 768, 768, 256, 0);
        vtrans<<<dim3(1792), blk, 0, stream>>>(bufBig, vT);
        attn_p8<<<dim3(1792), blk, 0, stream>>>(bufBig, vT, bufA);
        // attn-out GEMM + residual + LN (in-place on bufH)
        gemm_ln<<<400, blk, 0, stream>>>(
            bufA, outwb + (size_t)l * 256 * 8, 512, enc_out_b + l * 256,
            bufH, enc_n1_g + l * DD, enc_n1_b + l * DD, bufH, 256);
        gemm_p8<<<dim3(200, 8, 1), blk, 0, stream>>>(
            bufH, MR, 0, l1wb + (size_t)l * 1024 * 8, 2048, 0, enc_l1_b + l * 1024,
            bufBig, MR, 0, 0, MR, 1024, 1024, 256, 1);
        // FF2 GEMM + residual + LN (in-place on bufH)
        gemm_ln<<<400, blk, 0, stream>>>(
            bufBig, l2wb + (size_t)l * 256 * 8, 512, enc_l2_b + l * 256,
            bufH, enc_n2_g + l * DD, enc_n2_b + l * DD, bufH, 1024);
    }

    // ---- GCN branch ----
    colsum_dinv<<<dim3(2, NB), blk, 0, stream>>>(sc, dinv);
    sc_prep<<<dim3(7, 7, NB), blk, 0, stream>>>(sc, dinv, scb, anT);
    gemm_p8<<<dim3(2, 4, NB), blk, 0, stream>>>(
        gw1b, 256, 0, scb, 512, 56LL * 512 * 8, nullptr,
        XT1, 256, 0, 56LL * 256 * 8, 256, 400, 448, 448, 0);
    gemm_p8<<<dim3(4, 2, NB), blk, 0, stream>>>(
        anT, 512, 56LL * 512 * 8, XT1, 256, 56LL * 256 * 8, gcn_b1,
        h1, 512, 0, 32LL * 512 * 8, 400, 256, 256, 448, 1);
    gemm_p8<<<dim3(2, 4, NB), blk, 0, stream>>>(
        gw2b, 256, 0, h1, 512, 32LL * 512 * 8, nullptr,
        XT2, 256, 0, 56LL * 256 * 8, 256, 400, 448, 256, 0);
    gemm_p8<<<dim3(4, 2, NB), blk, 0, stream>>>(
        anT, 512, 56LL * 512 * 8, XT2, 256, 56LL * 256 * 8, gcn_b2,
        bufZS, MR, 400, 0, 400, 256, 256, 448, 0);

    // ---- Cross attention 1: Q = Z_F, KV = Z_S ----
    gemm_p8<<<dim3(200, 2, 1), blk, 0, stream>>>(
        bufH, MR, 0, c1qb, 768, 0, ca1_qkv_b, bufBig, MR, 0, 0, MR, 256, 256, 256, 0);
    gemm_p8<<<dim3(200, 4, 1), blk, 0, stream>>>(
        bufZS, MR, 0, c1qb + 256 * 8, 768, 0, ca1_qkv_b + 256,
        bufBig + (size_t)32 * MR * 8, MR, 0, 0, MR, 512, 512, 256, 0);
    vtrans<<<dim3(1792), blk, 0, stream>>>(bufBig, vT);
    attn_p8<<<dim3(1792), blk, 0, stream>>>(bufBig, vT, bufA);
    gemm_ln<<<400, blk, 0, stream>>>(
        bufA, c1ob, 256, ca1_out_b, bufH, ca1_n_g, ca1_n_b, bufC, 256);

    // ---- Cross attention 2: Q = Z_S, KV = Z_F ----
    gemm_p8<<<dim3(200, 2, 1), blk, 0, stream>>>(
        bufZS, MR, 0, c2qb, 768, 0, ca2_qkv_b, bufBig, MR, 0, 0, MR, 256, 256, 256, 0);
    gemm_p8<<<dim3(200, 4, 1), blk, 0, stream>>>(
        bufH, MR, 0, c2qb + 256 * 8, 768, 0, ca2_qkv_b + 256,
        bufBig + (size_t)32 * MR * 8, MR, 0, 0, MR, 512, 512, 256, 0);
    vtrans<<<dim3(1792), blk, 0, stream>>>(bufBig, vT);
    attn_p8<<<dim3(1792), blk, 0, stream>>>(bufBig, vT, bufA);
    gemm_ln<<<400, blk, 0, stream>>>(
        bufA, c2ob, 256, ca2_out_b, bufZS, ca2_n_g, ca2_n_b, bufZS, 256);

    // ---- Classifier ----
    cls_gemm<<<400, blk, 0, stream>>>(bufC, bufZS, w1b, partial);
    cls_reduce<<<32, blk, 0, stream>>>(partial, clsh);
    logits_final<<<NB, 128, 0, stream>>>(clsh, cls_b1, cls_w2, cls_b2, (float*)d_out);
}

// Round 9
// 940.528 us; speedup vs baseline: 1.0845x; 1.0317x over previous
//
#include <hip/hip_runtime.h>
#include <math.h>

// Problem constants
#define NB   64
#define NN   400
#define DD   256
#define NHH  4
#define HDD  64
#define MR   25600            // NB*NN

typedef __attribute__((ext_vector_type(8))) short bf16x8;
typedef __attribute__((ext_vector_type(4))) float f32x4;

__device__ __forceinline__ short f2bf(float x) {
    union { float f; unsigned u; } v; v.f = x;
    return (short)((v.u + 0x7FFFu + ((v.u >> 16) & 1u)) >> 16);
}
__device__ __forceinline__ float bf2f(short s) {
    union { unsigned u; float f; } v; v.u = ((unsigned)(unsigned short)s) << 16;
    return v.f;
}
// async global->LDS, 16 B/lane; src = per-lane addr, LDS dest = wave-uniform base
__device__ __forceinline__ void gl_lds16(const void* g, void* l) {
    __builtin_amdgcn_global_load_lds(
        (const __attribute__((address_space(1))) unsigned*)g,
        (__attribute__((address_space(3))) unsigned*)l, 16, 0, 0);
}
// counted vmcnt wait (T4): never drain to 0 in a main loop. "memory" clobber
// orders LDS reads after the wait at IR level.
__device__ __forceinline__ void wait_vmcnt(int n) {
    switch (n) {
    case 0: asm volatile("s_waitcnt vmcnt(0)" ::: "memory"); break;
    case 1: asm volatile("s_waitcnt vmcnt(1)" ::: "memory"); break;
    case 2: asm volatile("s_waitcnt vmcnt(2)" ::: "memory"); break;
    case 3: asm volatile("s_waitcnt vmcnt(3)" ::: "memory"); break;
    case 4: asm volatile("s_waitcnt vmcnt(4)" ::: "memory"); break;
    default: asm volatile("s_waitcnt vmcnt(5)" ::: "memory"); break;
    }
}
__device__ __forceinline__ void barrier_raw() {
    __builtin_amdgcn_sched_barrier(0);
    __builtin_amdgcn_s_barrier();
    __builtin_amdgcn_sched_barrier(0);
}

// ---------------------------------------------------------------------------
// P8 layout: element (row, k) lives at ((k>>3)*rows + row)*8 + (k&7) (bf16).
// = the 16x16x32 MFMA fragment layout; staging is contiguous 1 KiB bursts.
// ---------------------------------------------------------------------------

// bf16 GEMM, 256x128 tile, 512 threads (8 waves: 4m x 2n), BK=32, 3 staging
// buffers, 2-deep counted-vmcnt pipeline. Per-wave structure identical to the
// measured-best 128x128 form (8 ds_read + 16 MFMA / step, steady vmcnt(3)),
// but LDS 72KB -> 2 blocks/CU = 16 waves/CU (2x the old 7) and half the
// blocks -> less tail. Occupancy was the measured bottleneck (22%, MfmaUtil 9%).
__global__ __launch_bounds__(512, 4) void gemm_p8(
    const short* __restrict__ A, int arows, long long sA,
    const short* __restrict__ B, int brows, long long sB,
    const float* __restrict__ bias,
    short* __restrict__ C, int crows, int crz, long long sCe,
    int M, int N, int Npad, int K, int relu)
{
    __shared__ short lds[36864];   // 3 bufs of 12288 (A 8192 + B 4096); epilogue [256][136] = 34816 fits
    const int tid = threadIdx.x;
    const int z = blockIdx.z;
    const int m0 = blockIdx.x * 256, n0 = blockIdx.y * 128;
    const short* Ab = A + (size_t)z * sA;
    const short* Bb = B + (size_t)z * sB;

    const int w = tid >> 6, lane = tid & 63;
    const int quad = lane >> 4, l15 = lane & 15;
    const int wm = w & 3, wn = w >> 2;

    f32x4 acc[4][4] = {};

    const int KT = K >> 5;          // steps of 32 k (4 planes)

    auto STAGE = [&](int buf, int kt) {
        const int gp0 = kt << 2;
        short* Al = lds + buf * 12288;
        short* Bl = Al + 8192;
        // 24 chunks (16 A + 8 B), 3 per wave
#pragma unroll
        for (int i = 0; i < 3; ++i) {
            int c = i * 8 + w;
            if (c < 16) {
                int p = c >> 2, hh = c & 3;
                gl_lds16(Ab + ((size_t)(gp0 + p) * arows + m0 + hh * 64 + lane) * 8,
                         &Al[(p * 256 + hh * 64) * 8]);
            } else {
                int cb = c - 16, p = cb >> 1, hh = cb & 1;
                gl_lds16(Bb + ((size_t)(gp0 + p) * brows + n0 + hh * 64 + lane) * 8,
                         &Bl[(p * 128 + hh * 64) * 8]);
            }
        }
    };

    STAGE(0, 0);
    STAGE(1, 1);
    for (int kt = 0; kt < KT; ++kt) {
        wait_vmcnt(kt + 1 < KT ? 3 : 0);   // chunk kt complete; kt+1 (3 loads) stays in flight
        barrier_raw();
        if (kt + 2 < KT) STAGE((kt + 2) % 3, kt + 2);
        const short* Al = lds + (kt % 3) * 12288;
        const short* Bl = Al + 8192;
        bf16x8 af[4], bfr[4];
#pragma unroll
        for (int mi = 0; mi < 4; ++mi)
            af[mi] = *reinterpret_cast<const bf16x8*>(
                &Al[(quad * 256 + wm * 64 + mi * 16 + l15) * 8]);
#pragma unroll
        for (int ni = 0; ni < 4; ++ni)
            bfr[ni] = *reinterpret_cast<const bf16x8*>(
                &Bl[(quad * 128 + wn * 64 + ni * 16 + l15) * 8]);
#pragma unroll
        for (int mi = 0; mi < 4; ++mi)
#pragma unroll
            for (int ni = 0; ni < 4; ++ni)
                acc[mi][ni] = __builtin_amdgcn_mfma_f32_16x16x32_bf16(af[mi], bfr[ni], acc[mi][ni], 0, 0, 0);
    }
    __syncthreads();   // all waves done reading staging before epilogue overwrite

    // epilogue: acc -> bf16 row-major LDS tile [256][136], then 16B coalesced stores
#pragma unroll
    for (int mi = 0; mi < 4; ++mi) {
#pragma unroll
        for (int r = 0; r < 4; ++r) {
            int row = wm * 64 + mi * 16 + quad * 4 + r;
#pragma unroll
            for (int ni = 0; ni < 4; ++ni) {
                int col = wn * 64 + ni * 16 + l15;
                int gcol = n0 + col;
                float v = 0.0f;
                if (gcol < N) {
                    v = acc[mi][ni][r];
                    if (bias) v += bias[gcol];
                    if (relu) v = fmaxf(v, 0.0f);
                }
                lds[row * 136 + col] = f2bf(v);
            }
        }
    }
    __syncthreads();
    short* Cbz = C + (size_t)z * sCe;
    const long long zr = (long long)z * crz;
#pragma unroll
    for (int t = 0; t < 8; ++t) {
        int c = t * 512 + tid;
        int row = c & 255, p16 = c >> 8;
        int grow = m0 + row;
        int gcol0 = n0 + p16 * 8;
        if (grow < M && gcol0 < Npad) {
            bf16x8 v = *reinterpret_cast<const bf16x8*>(&lds[row * 136 + p16 * 8]);
            *reinterpret_cast<bf16x8*>(
                &Cbz[((size_t)(gcol0 >> 3) * crows + zr + grow) * 8]) = v;
        }
    }
}

// ---------------------------------------------------------------------------
// Fused GEMM (N=256) + residual + LayerNorm. Tile 64m x 256n; BK=32, 3
// staging buffers, 2-deep counted-vmcnt pipeline. Wave w owns COLS
// w*64..w*64+64 (4 m-frags x 4 n-frags) -> 8 ds_read_b128 per step.
// out[row] = LN(resid[row] + bf16(A·B^T + bias)) * g + b.  K % 64 == 0.
// ---------------------------------------------------------------------------
__global__ __launch_bounds__(256) void gemm_ln(
    const short* __restrict__ A,
    const short* __restrict__ B, int brows,
    const float* __restrict__ bias,
    const short* __restrict__ resid,
    const float* __restrict__ g, const float* __restrict__ bb,
    short* __restrict__ out, int K)
{
    __shared__ short lds[30720];        // 3 bufs of 10240: A [0,2048) B [2048,10240); epilogue rowt[64][264]
    __shared__ float gs[256], bs[256], bi_s[256];
    __shared__ float red[2][4][64];
    const int tid = threadIdx.x;
    const int m0 = blockIdx.x * 64;
    const int w = tid >> 6, lane = tid & 63;
    const int quad = lane >> 4, l15 = lane & 15;
    gs[tid] = g[tid]; bs[tid] = bb[tid]; bi_s[tid] = bias[tid];

    f32x4 acc[4][4] = {};
    const int KT = K >> 5;

    auto STAGE = [&](int buf, int kt) {
        const int gp0 = kt << 2;
        short* Al = lds + buf * 10240;
        short* Bl = Al + 2048;
        // 20 chunks (4 A + 16 B), 5 per wave
#pragma unroll
        for (int i = 0; i < 5; ++i) {
            int c = i * 4 + w;
            if (c < 4) {
                gl_lds16(A + ((size_t)(gp0 + c) * MR + m0 + lane) * 8, &Al[(c * 64) * 8]);
            } else {
                int cb = c - 4, p = cb >> 2, cq = cb & 3;
                gl_lds16(B + ((size_t)(gp0 + p) * brows + cq * 64 + lane) * 8,
                         &Bl[(p * 256 + cq * 64) * 8]);
            }
        }
    };

    STAGE(0, 0);
    STAGE(1, 1);
    for (int kt = 0; kt < KT; ++kt) {
        wait_vmcnt(kt + 1 < KT ? 5 : 0);
        barrier_raw();
        if (kt + 2 < KT) STAGE((kt + 2) % 3, kt + 2);
        const short* Al = lds + (kt % 3) * 10240;
        const short* Bl = Al + 2048;
        bf16x8 af[4], bfr[4];
#pragma unroll
        for (int mi = 0; mi < 4; ++mi)
            af[mi] = *reinterpret_cast<const bf16x8*>(
                &Al[(quad * 64 + mi * 16 + l15) * 8]);
#pragma unroll
        for (int ni = 0; ni < 4; ++ni)
            bfr[ni] = *reinterpret_cast<const bf16x8*>(
                &Bl[(quad * 256 + w * 64 + ni * 16 + l15) * 8]);
#pragma unroll
        for (int mi = 0; mi < 4; ++mi)
#pragma unroll
            for (int ni = 0; ni < 4; ++ni)
                acc[mi][ni] = __builtin_amdgcn_mfma_f32_16x16x32_bf16(af[mi], bfr[ni], acc[mi][ni], 0, 0, 0);
    }
    __syncthreads();   // staging reads complete before rowt overwrite

    // epilogue 1: bias add, round to bf16, into row-tile rowt[64][4 groups][66]
    // (66-stride breaks bank alignment). part = w (this wave's col quarter).
    short* rowt = lds;
#pragma unroll
    for (int mi = 0; mi < 4; ++mi)
#pragma unroll
        for (int ni = 0; ni < 4; ++ni) {
            int col = w * 64 + ni * 16 + l15;
#pragma unroll
            for (int r = 0; r < 4; ++r) {
                int row = mi * 16 + quad * 4 + r;
                rowt[row * 264 + w * 66 + ni * 16 + l15] = f2bf(acc[mi][ni][r] + bi_s[col]);
            }
        }
    __syncthreads();

    // epilogue 2: thread = (row, quarter): add residual, reduce, normalize
    const int row = tid >> 2, part = tid & 3;
    const int grow = m0 + row;
    float vv[8][8];
    float sum = 0.0f, sq = 0.0f;
#pragma unroll
    for (int i = 0; i < 8; ++i) {
        int plane = part * 8 + i;
        bf16x8 rv = *reinterpret_cast<const bf16x8*>(resid + ((size_t)plane * MR + grow) * 8);
        bf16x8 tv = *reinterpret_cast<const bf16x8*>(&rowt[row * 264 + part * 66 + i * 8]);
#pragma unroll
        for (int e = 0; e < 8; ++e) {
            float v = bf2f(tv[e]) + bf2f(rv[e]);
            vv[i][e] = v; sum += v; sq += v * v;
        }
    }
    red[0][part][row] = sum; red[1][part][row] = sq;
    __syncthreads();
    sum = red[0][0][row] + red[0][1][row] + red[0][2][row] + red[0][3][row];
    sq  = red[1][0][row] + red[1][1][row] + red[1][2][row] + red[1][3][row];
    float mu = sum * (1.0f / 256.0f);
    float var = sq * (1.0f / 256.0f) - mu * mu;
    float rstd = 1.0f / sqrtf(fmaxf(var, 0.0f) + 1e-5f);
#pragma unroll
    for (int i = 0; i < 8; ++i) {
        int plane = part * 8 + i;
        bf16x8 o;
#pragma unroll
        for (int e = 0; e < 8; ++e)
            o[e] = f2bf((vv[i][e] - mu) * rstd * gs[plane * 8 + e] + bs[plane * 8 + e]);
        *reinterpret_cast<bf16x8*>(out + ((size_t)plane * MR + grow) * 8) = o;
    }
}

// ---------------------------------------------------------------------------
// V transpose: per (b,h), vT[(bh*56 + kp)*64 + d]*8 + (key&7) = V[key][d],
// keys >= 400 zeroed. XCD-swizzled 1D grid (1792 = 8*224): all chunks of a
// (b,h) run on XCD bh%8 -> vT lands in the L2 that attn_p8 will read it from.
// ---------------------------------------------------------------------------
__global__ __launch_bounds__(256) void vtrans(
    const short* __restrict__ qkv, short* __restrict__ vT)
{
    __shared__ short tile[64][66];
    const int id = blockIdx.x;
    const int xcd = id & 7, rem = id >> 3;
    const int bh_hi = rem / 7, c = rem - bh_hi * 7;
    const int bh_i = bh_hi * 8 + xcd;
    const int h = bh_i & 3, b = bh_i >> 2;
    const int tid = threadIdx.x;
    const size_t bh = (size_t)bh_i;
    for (int t = tid; t < 512; t += 256) {
        int pp = t >> 6, l = t & 63;
        int j = c * 64 + l;
        bf16x8 v;
        if (j < NN)
            v = *reinterpret_cast<const bf16x8*>(
                qkv + (((size_t)(64 + 8 * h + pp)) * MR + (size_t)b * NN + j) * 8);
        else { for (int e = 0; e < 8; ++e) v[e] = 0; }
#pragma unroll
        for (int e = 0; e < 8; ++e) tile[l][pp * 8 + e] = v[e];
    }
    __syncthreads();
    for (int t = tid; t < 512; t += 256) {
        int kq = t >> 6, d = t & 63;
        int kp = c * 8 + kq;
        bf16x8 o;
#pragma unroll
        for (int e = 0; e < 8; ++e) o[e] = tile[kq * 8 + e][d];
        *reinterpret_cast<bf16x8*>(vT + ((bh * 56 + kp) * 64 + d) * 8) = o;
    }
}

// ---------------------------------------------------------------------------
// Attention, LDS-minimal: K and V fragments are read STRAIGHT FROM GLOBAL
// (both are L2-resident on this block's XCD thanks to the swizzle, and both
// access patterns are 16 lanes x 16B contiguous per quad = fully coalesced).
// LDS holds only the P tile (and transiently Q) -> 52 KB -> 3 blocks/CU.
// Barriers per block: 3. PV loop is barrier-free.
// ---------------------------------------------------------------------------
__global__ __launch_bounds__(256, 3) void attn_p8(
    const short* __restrict__ qkv, const short* __restrict__ vT,
    short* __restrict__ Out)
{
    __shared__ short PS[26624];   // P: 52 planes x 64 rows x 8 (53248 B); [0..4096) doubles as Q staging
    const int id = blockIdx.x;
    const int xcd = id & 7, rem = id >> 3;
    const int bh_hi = rem / 7, qt = rem - bh_hi * 7;
    const int bh_i = bh_hi * 8 + xcd;
    const int h = bh_i & 3, b = bh_i >> 2;
    const int tid = threadIdx.x;
    const int w = tid >> 6, lane = tid & 63;
    const int quad = lane >> 4, l15 = lane & 15;
    const size_t rowb = (size_t)b * NN;

    // stage Q (8 planes x 64 rows) into PS[0..4096)
    for (int j = w; j < 8; j += 4)
        gl_lds16(qkv + (((size_t)(8 * h + j)) * MR + rowb + qt * 64 + lane) * 8, &PS[j * 512]);
    __syncthreads();

    bf16x8 aq0 = *reinterpret_cast<const bf16x8*>(&PS[(quad * 64 + w * 16 + l15) * 8]);
    bf16x8 aq1 = *reinterpret_cast<const bf16x8*>(&PS[((4 + quad) * 64 + w * 16 + l15) * 8]);

    // QK^T: K fragment for (nt, quad) = 16B at plane (32+8h+quad), key nt*16+l15
    const short* Kb0 = qkv + ((size_t)(32 + 8 * h + quad) * MR + rowb + l15) * 8;
    const short* Kb1 = qkv + ((size_t)(36 + 8 * h + quad) * MR + rowb + l15) * 8;

    f32x4 sacc[25];
#pragma unroll
    for (int nt = 0; nt < 25; ++nt) { sacc[nt][0] = 0; sacc[nt][1] = 0; sacc[nt][2] = 0; sacc[nt][3] = 0; }
#pragma unroll
    for (int nt = 0; nt < 25; ++nt) {
        bf16x8 b0 = *reinterpret_cast<const bf16x8*>(Kb0 + nt * 128);
        bf16x8 b1 = *reinterpret_cast<const bf16x8*>(Kb1 + nt * 128);
        sacc[nt] = __builtin_amdgcn_mfma_f32_16x16x32_bf16(aq0, b0, sacc[nt], 0, 0, 0);
        sacc[nt] = __builtin_amdgcn_mfma_f32_16x16x32_bf16(aq1, b1, sacc[nt], 0, 0, 0);
    }

    float mx[4] = {-3e38f, -3e38f, -3e38f, -3e38f}, sm[4] = {0, 0, 0, 0};
#pragma unroll
    for (int nt = 0; nt < 25; ++nt)
#pragma unroll
        for (int r = 0; r < 4; ++r) mx[r] = fmaxf(mx[r], sacc[nt][r]);
#pragma unroll
    for (int r = 0; r < 4; ++r) {
        mx[r] = fmaxf(mx[r], __shfl_xor(mx[r], 1));
        mx[r] = fmaxf(mx[r], __shfl_xor(mx[r], 2));
        mx[r] = fmaxf(mx[r], __shfl_xor(mx[r], 4));
        mx[r] = fmaxf(mx[r], __shfl_xor(mx[r], 8));
    }
#pragma unroll
    for (int nt = 0; nt < 25; ++nt)
#pragma unroll
        for (int r = 0; r < 4; ++r) {
            float e = __expf((sacc[nt][r] - mx[r]) * 0.125f);
            sacc[nt][r] = e;
            sm[r] += e;
        }
#pragma unroll
    for (int r = 0; r < 4; ++r) {
        sm[r] += __shfl_xor(sm[r], 1);
        sm[r] += __shfl_xor(sm[r], 2);
        sm[r] += __shfl_xor(sm[r], 4);
        sm[r] += __shfl_xor(sm[r], 8);
    }
    __syncthreads();   // Q LDS reads complete -> P may overwrite PS

    // P transpose into PS (C-layout -> A-fragment layout), keys>=400 zeroed
#pragma unroll
    for (int nt = 0; nt < 25; ++nt)
#pragma unroll
        for (int r = 0; r < 4; ++r) {
            int colk = nt * 16 + l15;
            PS[((colk >> 3) * 64 + w * 16 + quad * 4 + r) * 8 + (colk & 7)] = f2bf(sacc[nt][r]);
        }
    for (int idx = tid; idx < 1024; idx += 256) PS[25600 + idx] = 0;

    f32x4 oacc[4];
#pragma unroll
    for (int dt = 0; dt < 4; ++dt) { oacc[dt][0] = 0; oacc[dt][1] = 0; oacc[dt][2] = 0; oacc[dt][3] = 0; }
    __syncthreads();   // P visible to all waves

    // PV, barrier-free: V fragment for (kt, quad, dt) = 16B at vT plane
    // bh*56 + kt*4 + quad, d = dt*16 + l15 (L2-resident, coalesced).
    const short* Vb = vT + (((size_t)bh_i * 56 + quad) * 64 + l15) * 8;
#pragma unroll
    for (int kt = 0; kt < 13; ++kt) {
        bf16x8 pa = *reinterpret_cast<const bf16x8*>(
            &PS[((kt * 4 + quad) * 64 + w * 16 + l15) * 8]);
#pragma unroll
        for (int dt = 0; dt < 4; ++dt) {
            bf16x8 vb = *reinterpret_cast<const bf16x8*>(Vb + kt * 2048 + dt * 128);
            oacc[dt] = __builtin_amdgcn_mfma_f32_16x16x32_bf16(pa, vb, oacc[dt], 0, 0, 0);
        }
    }
#pragma unroll
    for (int r = 0; r < 4; ++r) {
        int row = qt * 64 + w * 16 + quad * 4 + r;
        if (row >= NN) continue;
        float inv = 1.0f / sm[r];
#pragma unroll
        for (int dt = 0; dt < 4; ++dt) {
            int col = dt * 16 + l15;
            Out[(((size_t)(8 * h + (col >> 3))) * MR + rowb + row) * 8 + (col & 7)] =
                f2bf(oacc[dt][r] * inv);
        }
    }
}

// ---------------------------------------------------------------------------
// vectorized f32 -> P8 conversion: one thread per (row, 8-col group);
// float4 x2 reads, one bf16x8 store.
// ---------------------------------------------------------------------------
__global__ void conv_p8(const float* __restrict__ src, short* __restrict__ dst,
                        int R, int K, int Kp, int PR)
{
    const int G = Kp >> 3;
    int idx = blockIdx.x * 256 + threadIdx.x;
    if (idx >= R * G) return;
    int r = idx / G, g = idx - r * G;
    int k0 = g << 3;
    bf16x8 o;
    if (k0 + 8 <= K) {
        const float4 v0 = *reinterpret_cast<const float4*>(src + (size_t)r * K + k0);
        const float4 v1 = *reinterpret_cast<const float4*>(src + (size_t)r * K + k0 + 4);
        o[0] = f2bf(v0.x); o[1] = f2bf(v0.y); o[2] = f2bf(v0.z); o[3] = f2bf(v0.w);
        o[4] = f2bf(v1.x); o[5] = f2bf(v1.y); o[6] = f2bf(v1.z); o[7] = f2bf(v1.w);
    } else {
#pragma unroll
        for (int e = 0; e < 8; ++e) {
            int k = k0 + e;
            o[e] = (k < K) ? f2bf(src[(size_t)r * K + k]) : (short)0;
        }
    }
    *reinterpret_cast<bf16x8*>(dst + ((size_t)g * PR + r) * 8) = o;
}

// ---------------------------------------------------------------------------
// batched f32 -> P8 conversion for the 11 small weight matrices: one launch
// instead of 11 (saves ~10 launch slots). Segment table passed by value.
// ---------------------------------------------------------------------------
struct ConvSeg { const float* src; short* dst; int R, K, Kp, start; };
struct ConvPack { ConvSeg s[11]; int total; };

__global__ void conv_multi(ConvPack p)
{
    int idx = blockIdx.x * 256 + threadIdx.x;
    if (idx >= p.total) return;
    int si = 0;
#pragma unroll
    for (int t = 1; t < 11; ++t) if (idx >= p.s[t].start) si = t;
    const ConvSeg sg = p.s[si];
    int local = idx - sg.start;
    const int G = sg.Kp >> 3;
    int r = local / G, g = local - r * G;
    int k0 = g << 3;
    bf16x8 o;
    if (k0 + 8 <= sg.K) {
        const float4 v0 = *reinterpret_cast<const float4*>(sg.src + (size_t)r * sg.K + k0);
        const float4 v1 = *reinterpret_cast<const float4*>(sg.src + (size_t)r * sg.K + k0 + 4);
        o[0] = f2bf(v0.x); o[1] = f2bf(v0.y); o[2] = f2bf(v0.z); o[3] = f2bf(v0.w);
        o[4] = f2bf(v1.x); o[5] = f2bf(v1.y); o[6] = f2bf(v1.z); o[7] = f2bf(v1.w);
    } else {
#pragma unroll
        for (int e = 0; e < 8; ++e) {
            int k = k0 + e;
            o[e] = (k < sg.K) ? f2bf(sg.src[(size_t)r * sg.K + k]) : (short)0;
        }
    }
    *reinterpret_cast<bf16x8*>(sg.dst + ((size_t)g * sg.R + r) * 8) = o;
}

// ---------------------------------------------------------------------------
__global__ __launch_bounds__(256) void w1_p8(
    const float* __restrict__ W1, short* __restrict__ Wp)
{
    __shared__ float tile[128][129];
    const int k0 = blockIdx.x * 128;
    const int tid = threadIdx.x;
    for (int t = 0; t < 16; ++t) {
        int idx = t * 256 + tid;
        int r = idx >> 5, k4 = idx & 31;
        float4 v = *(const float4*)(W1 + (size_t)r * 102400 + k0 + k4 * 4);
        tile[r][k4 * 4 + 0] = v.x; tile[r][k4 * 4 + 1] = v.y;
        tile[r][k4 * 4 + 2] = v.z; tile[r][k4 * 4 + 3] = v.w;
    }
    __syncthreads();
    for (int t = 0; t < 8; ++t) {
        int idx = t * 256 + tid;
        int pidx = idx >> 7, r = idx & 127;
        bf16x8 o;
#pragma unroll
        for (int e = 0; e < 8; ++e) o[e] = f2bf(tile[r][pidx * 8 + e]);
        *reinterpret_cast<bf16x8*>(Wp + (((size_t)(k0 >> 3) + pidx) * 128 + r) * 8) = o;
    }
}

// ---------------------------------------------------------------------------
__global__ void colsum_dinv(const float* __restrict__ sc, float* __restrict__ dinv)
{
    int b = blockIdx.y;
    int j = blockIdx.x * 256 + threadIdx.x;
    if (j >= NN) return;
    const float* p = sc + (size_t)b * NN * NN + j;
    float s = 0.0f;
    for (int i = 0; i < NN; ++i) s += p[(size_t)i * NN];
    dinv[b * NN + j] = (s > 0.0f) ? 1.0f / sqrtf(s) : 0.0f;
}

// ---------------------------------------------------------------------------
__global__ __launch_bounds__(256) void sc_prep(
    const float* __restrict__ sc, const float* __restrict__ dinv,
    short* __restrict__ scb, short* __restrict__ anT)
{
    __shared__ float tile[64][65];
    const int b = blockIdx.z;
    const int i0 = blockIdx.y * 64, j0 = blockIdx.x * 64;
    const int tid = threadIdx.x;
    const float* sb = sc + (size_t)b * NN * NN;
    short* scbb = scb + (size_t)b * 56 * 512 * 8;
    short* anTb = anT + (size_t)b * 56 * 512 * 8;
    for (int e = tid; e < 4096; e += 256) {
        int r = e >> 6, c = e & 63;
        int i = i0 + r, j = j0 + c;
        tile[r][c] = (i < NN && j < NN) ? sb[(size_t)i * NN + j] : 0.0f;
    }
    __syncthreads();
    for (int e = tid; e < 4096; e += 256) {
        int r = e >> 6, c = e & 63;
        int i = i0 + r, j = j0 + c;
        scbb[((size_t)(j >> 3) * 512 + i) * 8 + (j & 7)] = f2bf(tile[r][c]);
        float v = 0.0f;
        if (i < NN && j < NN) v = tile[r][c] * dinv[b * NN + i] * dinv[b * NN + j];
        anTb[((size_t)(i >> 3) * 512 + j) * 8 + (i & 7)] = f2bf(v);
    }
}

// ---------------------------------------------------------------------------
__global__ __launch_bounds__(256) void cls_gemm(
    const short* __restrict__ C1, const short* __restrict__ C2,
    const short* __restrict__ Wp, float* __restrict__ partial)
{
    __shared__ short Al[32 * 64 * 8];
    __shared__ short Wl[8 * 128 * 8];
    const int j = blockIdx.x;
    const int tid = threadIdx.x;
    const int w = tid >> 6, lane = tid & 63;
    const int quad = lane >> 4, l15 = lane & 15;

    for (int s = 0; s < 8; ++s) {
        int idx = s * 256 + tid;
        int p = idx >> 6, b = idx & 63;
        size_t ad = ((size_t)p * MR + (size_t)b * NN + j) * 8;
        bf16x8 a = *reinterpret_cast<const bf16x8*>(C1 + ad);
        bf16x8 c = *reinterpret_cast<const bf16x8*>(C2 + ad);
        bf16x8 o;
#pragma unroll
        for (int e = 0; e < 8; ++e) o[e] = f2bf(0.5f * (bf2f(a[e]) + bf2f(c[e])));
        *reinterpret_cast<bf16x8*>(&Al[(p * 64 + b) * 8]) = o;
    }

    f32x4 acc[4][2] = {};
    const size_t wp0 = (size_t)j * 32;
    for (int s = 0; s < 4; ++s) {
#pragma unroll
        for (int pp = 0; pp < 2; ++pp) {
            int p = w + pp * 4;
            gl_lds16(Wp + ((wp0 + s * 8 + p) * 128 + lane) * 8,      &Wl[(p * 128) * 8]);
            gl_lds16(Wp + ((wp0 + s * 8 + p) * 128 + 64 + lane) * 8, &Wl[(p * 128 + 64) * 8]);
        }
        __syncthreads();
#pragma unroll
        for (int kb = 0; kb < 2; ++kb) {
            bf16x8 af[4], bfr[2];
#pragma unroll
            for (int mi = 0; mi < 4; ++mi)
                af[mi] = *reinterpret_cast<const bf16x8*>(
                    &Al[((s * 8 + kb * 4 + quad) * 64 + mi * 16 + l15) * 8]);
#pragma unroll
            for (int ni = 0; ni < 2; ++ni)
                bfr[ni] = *reinterpret_cast<const bf16x8*>(
                    &Wl[((kb * 4 + quad) * 128 + w * 32 + ni * 16 + l15) * 8]);
#pragma unroll
            for (int mi = 0; mi < 4; ++mi)
#pragma unroll
                for (int ni = 0; ni < 2; ++ni)
                    acc[mi][ni] = __builtin_amdgcn_mfma_f32_16x16x32_bf16(af[mi], bfr[ni], acc[mi][ni], 0, 0, 0);
        }
        __syncthreads();
    }
    float* pj = partial + (size_t)j * 8192;
#pragma unroll
    for (int mi = 0; mi < 4; ++mi)
#pragma unroll
        for (int r = 0; r < 4; ++r) {
            int row = mi * 16 + quad * 4 + r;
#pragma unroll
            for (int ni = 0; ni < 2; ++ni)
                pj[row * 128 + w * 32 + ni * 16 + l15] = acc[mi][ni][r];
        }
}

__global__ void cls_reduce(const float* __restrict__ partial, float* __restrict__ clsh)
{
    int o = blockIdx.x * 256 + threadIdx.x;
    float s = 0.0f;
    for (int kb = 0; kb < 400; ++kb) s += partial[(size_t)kb * 8192 + o];
    clsh[o] = s;
}

__global__ void logits_final(
    const float* __restrict__ clsh, const float* __restrict__ b1,
    const float* __restrict__ w2, const float* __restrict__ b2,
    float* __restrict__ out)
{
    __shared__ float t[128];
    int b = blockIdx.x;
    int tid = threadIdx.x;
    t[tid] = fmaxf(clsh[b * 128 + tid] + b1[tid], 0.0f);
    __syncthreads();
    if (tid < 2) {
        float s = b2[tid];
        for (int o = 0; o < 128; ++o) s += t[o] * w2[tid * 128 + o];
        out[b * 2 + tid] = s;
    }
}

// ---------------------------------------------------------------------------
extern "C" void kernel_launch(void* const* d_in, const int* in_sizes, int n_in,
                              void* d_out, int out_size, void* d_ws, size_t ws_size,
                              hipStream_t stream)
{
    const float* fc        = (const float*)d_in[0];
    const float* sc        = (const float*)d_in[1];
    const float* proj_w    = (const float*)d_in[2];
    const float* proj_b    = (const float*)d_in[3];
    const float* enc_qkv_w = (const float*)d_in[4];
    const float* enc_qkv_b = (const float*)d_in[5];
    const float* enc_out_w = (const float*)d_in[6];
    const float* enc_out_b = (const float*)d_in[7];
    const float* enc_l1_w  = (const float*)d_in[8];
    const float* enc_l1_b  = (const float*)d_in[9];
    const float* enc_l2_w  = (const float*)d_in[10];
    const float* enc_l2_b  = (const float*)d_in[11];
    const float* enc_n1_g  = (const float*)d_in[12];
    const float* enc_n1_b  = (const float*)d_in[13];
    const float* enc_n2_g  = (const float*)d_in[14];
    const float* enc_n2_b  = (const float*)d_in[15];
    const float* gcn_w1    = (const float*)d_in[16];
    const float* gcn_b1    = (const float*)d_in[17];
    const float* gcn_w2    = (const float*)d_in[18];
    const float* gcn_b2    = (const float*)d_in[19];
    const float* ca1_qkv_w = (const float*)d_in[20];
    const float* ca1_qkv_b = (const float*)d_in[21];
    const float* ca1_out_w = (const float*)d_in[22];
    const float* ca1_out_b = (const float*)d_in[23];
    const float* ca1_n_g   = (const float*)d_in[24];
    const float* ca1_n_b   = (const float*)d_in[25];
    const float* ca2_qkv_w = (const float*)d_in[26];
    const float* ca2_qkv_b = (const float*)d_in[27];
    const float* ca2_out_w = (const float*)d_in[28];
    const float* ca2_out_b = (const float*)d_in[29];
    const float* ca2_n_g   = (const float*)d_in[30];
    const float* ca2_n_b   = (const float*)d_in[31];
    const float* cls_w1    = (const float*)d_in[32];
    const float* cls_b1    = (const float*)d_in[33];
    const float* cls_w2    = (const float*)d_in[34];
    const float* cls_b2    = (const float*)d_in[35];

    char* wsb = (char*)d_ws;
    size_t off = 0;
    auto alloc = [&](size_t bytes) { char* r = wsb + off; off += (bytes + 255) & ~(size_t)255; return r; };
    short* bufBig = (short*)alloc((size_t)MR * 1024 * 2);
    short* fcb    = (short*)alloc((size_t)56 * MR * 8 * 2);
    short* anT    = (short*)alloc((size_t)NB * 56 * 512 * 8 * 2);
    short* bufH   = (short*)alloc((size_t)32 * MR * 8 * 2);
    short* bufA   = (short*)alloc((size_t)32 * MR * 8 * 2);
    short* bufC   = (short*)alloc((size_t)32 * MR * 8 * 2);
    short* bufZS  = (short*)alloc((size_t)32 * MR * 8 * 2);
    short* vT     = (short*)alloc((size_t)NB * NHH * 56 * 64 * 8 * 2);
    short* w1b    = (short*)alloc((size_t)12800 * 128 * 8 * 2);
    short* projwb = (short*)alloc((size_t)56 * 256 * 8 * 2);
    short* qkvwb  = (short*)alloc((size_t)32 * 1536 * 8 * 2);
    short* outwb  = (short*)alloc((size_t)32 * 512 * 8 * 2);
    short* l1wb   = (short*)alloc((size_t)32 * 2048 * 8 * 2);
    short* l2wb   = (short*)alloc((size_t)128 * 512 * 8 * 2);
    short* gw1b   = (short*)alloc((size_t)56 * 256 * 8 * 2);
    short* gw2b   = (short*)alloc((size_t)32 * 256 * 8 * 2);
    short* c1qb   = (short*)alloc((size_t)32 * 768 * 8 * 2);
    short* c1ob   = (short*)alloc((size_t)32 * 256 * 8 * 2);
    short* c2qb   = (short*)alloc((size_t)32 * 768 * 8 * 2);
    short* c2ob   = (short*)alloc((size_t)32 * 256 * 8 * 2);
    float* dinv   = (float*)alloc((size_t)MR * 4);
    float* clsh   = (float*)alloc((size_t)NB * 128 * 4);
    short* scb = bufBig;
    short* XT1 = bufBig + (size_t)64 * 56 * 512 * 8;
    short* h1  = bufBig;
    short* XT2 = XT1;
    float* partial = (float*)fcb;

    dim3 blk(256), blk512(512);
    auto cgrid = [](long long n) { return dim3((unsigned)((n + 255) / 256)); };

    // ---- conversions to P8 ----
    conv_p8<<<cgrid((long long)MR * 56), blk, 0, stream>>>(fc, fcb, MR, 400, 448, MR);
    {
        ConvPack pk;
        int st = 0;
        auto seg = [&](int i, const float* s, short* d, int R, int K, int Kp) {
            pk.s[i].src = s; pk.s[i].dst = d; pk.s[i].R = R; pk.s[i].K = K;
            pk.s[i].Kp = Kp; pk.s[i].start = st; st += R * (Kp >> 3);
        };
        seg(0,  proj_w,    projwb, 256,  400,  448);
        seg(1,  enc_qkv_w, qkvwb,  1536, 256,  256);
        seg(2,  enc_out_w, outwb,  512,  256,  256);
        seg(3,  enc_l1_w,  l1wb,   2048, 256,  256);
        seg(4,  enc_l2_w,  l2wb,   512,  1024, 1024);
        seg(5,  gcn_w1,    gw1b,   256,  400,  448);
        seg(6,  gcn_w2,    gw2b,   256,  256,  256);
        seg(7,  ca1_qkv_w, c1qb,   768,  256,  256);
        seg(8,  ca1_out_w, c1ob,   256,  256,  256);
        seg(9,  ca2_qkv_w, c2qb,   768,  256,  256);
        seg(10, ca2_out_w, c2ob,   256,  256,  256);
        pk.total = st;
        conv_multi<<<cgrid(st), blk, 0, stream>>>(pk);
    }
    w1_p8<<<800, blk, 0, stream>>>(cls_w1, w1b);

    // ---- FC branch ----
    gemm_p8<<<dim3(100, 2, 1), blk512, 0, stream>>>(
        fcb, MR, 0, projwb, 256, 0, proj_b, bufH, MR, 0, 0, MR, 256, 256, 448, 0);
    for (int l = 0; l < 2; ++l) {
        gemm_p8<<<dim3(100, 6, 1), blk512, 0, stream>>>(
            bufH, MR, 0, qkvwb + (size_t)l * 768 * 8, 1536, 0, enc_qkv_b + l * 768,
            bufBig, MR, 0, 0, MR, 768, 768, 256, 0);
        vtrans<<<dim3(1792), blk, 0, stream>>>(bufBig, vT);
        attn_p8<<<dim3(1792), blk, 0, stream>>>(bufBig, vT, bufA);
        // attn-out GEMM + residual + LN (in-place on bufH)
        gemm_ln<<<400, blk, 0, stream>>>(
            bufA, outwb + (size_t)l * 256 * 8, 512, enc_out_b + l * 256,
            bufH, enc_n1_g + l * DD, enc_n1_b + l * DD, bufH, 256);
        gemm_p8<<<dim3(100, 8, 1), blk512, 0, stream>>>(
            bufH, MR, 0, l1wb + (size_t)l * 1024 * 8, 2048, 0, enc_l1_b + l * 1024,
            bufBig, MR, 0, 0, MR, 1024, 1024, 256, 1);
        // FF2 GEMM + residual + LN (in-place on bufH)
        gemm_ln<<<400, blk, 0, stream>>>(
            bufBig, l2wb + (size_t)l * 256 * 8, 512, enc_l2_b + l * 256,
            bufH, enc_n2_g + l * DD, enc_n2_b + l * DD, bufH, 1024);
    }

    // ---- GCN branch ----
    colsum_dinv<<<dim3(2, NB), blk, 0, stream>>>(sc, dinv);
    sc_prep<<<dim3(7, 7, NB), blk, 0, stream>>>(sc, dinv, scb, anT);
    gemm_p8<<<dim3(1, 4, NB), blk512, 0, stream>>>(
        gw1b, 256, 0, scb, 512, 56LL * 512 * 8, nullptr,
        XT1, 256, 0, 56LL * 256 * 8, 256, 400, 448, 448, 0);
    gemm_p8<<<dim3(2, 2, NB), blk512, 0, stream>>>(
        anT, 512, 56LL * 512 * 8, XT1, 256, 56LL * 256 * 8, gcn_b1,
        h1, 512, 0, 32LL * 512 * 8, 400, 256, 256, 448, 1);
    gemm_p8<<<dim3(1, 4, NB), blk512, 0, stream>>>(
        gw2b, 256, 0, h1, 512, 32LL * 512 * 8, nullptr,
        XT2, 256, 0, 56LL * 256 * 8, 256, 400, 448, 256, 0);
    gemm_p8<<<dim3(2, 2, NB), blk512, 0, stream>>>(
        anT, 512, 56LL * 512 * 8, XT2, 256, 56LL * 256 * 8, gcn_b2,
        bufZS, MR, 400, 0, 400, 256, 256, 448, 0);

    // ---- Cross attention 1: Q = Z_F, KV = Z_S ----
    gemm_p8<<<dim3(100, 2, 1), blk512, 0, stream>>>(
        bufH, MR, 0, c1qb, 768, 0, ca1_qkv_b, bufBig, MR, 0, 0, MR, 256, 256, 256, 0);
    gemm_p8<<<dim3(100, 4, 1), blk512, 0, stream>>>(
        bufZS, MR, 0, c1qb + 256 * 8, 768, 0, ca1_qkv_b + 256,
        bufBig + (size_t)32 * MR * 8, MR, 0, 0, MR, 512, 512, 256, 0);
    vtrans<<<dim3(1792), blk, 0, stream>>>(bufBig, vT);
    attn_p8<<<dim3(1792), blk, 0, stream>>>(bufBig, vT, bufA);
    gemm_ln<<<400, blk, 0, stream>>>(
        bufA, c1ob, 256, ca1_out_b, bufH, ca1_n_g, ca1_n_b, bufC, 256);

    // ---- Cross attention 2: Q = Z_S, KV = Z_F ----
    gemm_p8<<<dim3(100, 2, 1), blk512, 0, stream>>>(
        bufZS, MR, 0, c2qb, 768, 0, ca2_qkv_b, bufBig, MR, 0, 0, MR, 256, 256, 256, 0);
    gemm_p8<<<dim3(100, 4, 1), blk512, 0, stream>>>(
        bufH, MR, 0, c2qb + 256 * 8, 768, 0, ca2_qkv_b + 256,
        bufBig + (size_t)32 * MR * 8, MR, 0, 0, MR, 512, 512, 256, 0);
    vtrans<<<dim3(1792), blk, 0, stream>>>(bufBig, vT);
    attn_p8<<<dim3(1792), blk, 0, stream>>>(bufBig, vT, bufA);
    gemm_ln<<<400, blk, 0, stream>>>(
        bufA, c2ob, 256, ca2_out_b, bufZS, ca2_n_g, ca2_n_b, bufZS, 256);

    // ---- Classifier ----
    cls_gemm<<<400, blk, 0, stream>>>(bufC, bufZS, w1b, partial);
    cls_reduce<<<32, blk, 0, stream>>>(partial, clsh);
    logits_final<<<NB, 128, 0, stream>>>(clsh, cls_b1, cls_w2, cls_b2, (float*)d_out);
}

// Round 10
// 899.719 us; speedup vs baseline: 1.1337x; 1.0454x over previous
//
#include <hip/hip_runtime.h>
#include <math.h>

// Problem constants
#define NB   64
#define NN   400
#define DD   256
#define NHH  4
#define HDD  64
#define MR   25600            // NB*NN

typedef __attribute__((ext_vector_type(8))) short bf16x8;
typedef __attribute__((ext_vector_type(4))) float f32x4;

__device__ __forceinline__ short f2bf(float x) {
    union { float f; unsigned u; } v; v.f = x;
    return (short)((v.u + 0x7FFFu + ((v.u >> 16) & 1u)) >> 16);
}
__device__ __forceinline__ float bf2f(short s) {
    union { unsigned u; float f; } v; v.u = ((unsigned)(unsigned short)s) << 16;
    return v.f;
}
// async global->LDS, 16 B/lane; src = per-lane addr, LDS dest = wave-uniform base
__device__ __forceinline__ void gl_lds16(const void* g, void* l) {
    __builtin_amdgcn_global_load_lds(
        (const __attribute__((address_space(1))) unsigned*)g,
        (__attribute__((address_space(3))) unsigned*)l, 16, 0, 0);
}
// counted vmcnt wait (T4): never drain to 0 in a main loop. "memory" clobber
// orders LDS reads after the wait at IR level.
__device__ __forceinline__ void wait_vmcnt(int n) {
    switch (n) {
    case 0: asm volatile("s_waitcnt vmcnt(0)" ::: "memory"); break;
    case 1: asm volatile("s_waitcnt vmcnt(1)" ::: "memory"); break;
    case 2: asm volatile("s_waitcnt vmcnt(2)" ::: "memory"); break;
    case 3: asm volatile("s_waitcnt vmcnt(3)" ::: "memory"); break;
    case 4: asm volatile("s_waitcnt vmcnt(4)" ::: "memory"); break;
    default: asm volatile("s_waitcnt vmcnt(5)" ::: "memory"); break;
    }
}
__device__ __forceinline__ void barrier_raw() {
    __builtin_amdgcn_sched_barrier(0);
    __builtin_amdgcn_s_barrier();
    __builtin_amdgcn_sched_barrier(0);
}

// ---------------------------------------------------------------------------
// P8 layout: element (row, k) lives at ((k>>3)*rows + row)*8 + (k&7) (bf16).
// = the 16x16x32 MFMA fragment layout; staging is contiguous 1 KiB bursts.
// ---------------------------------------------------------------------------

// bf16 GEMM, 256x128 tile, 512 threads (8 waves: 4m x 2n), BK=32, 3 staging
// buffers, 2-deep counted-vmcnt pipeline. NEW: T1 XCD-chunked block swizzle —
// xcd = lin%8 owns a contiguous m-major g-range, so the 8 n-blocks sharing an
// A-panel co-locate on one XCD (A slice ~1.6 MB << 4 MB L2). Staging loads go
// from L3 (~600cy) to L2 (~200cy) latency; A L3-refetch drops ~2x.
// All call-site grids have nwg % 8 == 0 -> mapping is bijective.
__global__ __launch_bounds__(512, 4) void gemm_p8(
    const short* __restrict__ A, int arows, long long sA,
    const short* __restrict__ B, int brows, long long sB,
    const float* __restrict__ bias,
    short* __restrict__ C, int crows, int crz, long long sCe,
    int M, int N, int Npad, int K, int relu)
{
    __shared__ short lds[36864];   // 3 bufs of 12288 (A 8192 + B 4096); epilogue [256][136] fits
    const int tid = threadIdx.x;

    // XCD-chunked swizzle of the flattened grid (x = m-tile, y = n-tile, z = batch)
    const unsigned gx = gridDim.x, gy = gridDim.y;
    const unsigned nwg = gx * gy * gridDim.z;
    const unsigned lin = (blockIdx.z * gy + blockIdx.y) * gx + blockIdx.x;
    const unsigned g = (lin & 7) * (nwg >> 3) + (lin >> 3);   // xcd-contiguous
    const unsigned zz = g / (gx * gy);
    const unsigned rem2 = g - zz * gx * gy;
    const unsigned mx = rem2 / gy;          // m-major: same-m blocks share an XCD
    const unsigned ny = rem2 - mx * gy;

    const int z = (int)zz;
    const int m0 = (int)mx * 256, n0 = (int)ny * 128;
    const short* Ab = A + (size_t)z * sA;
    const short* Bb = B + (size_t)z * sB;

    const int w = tid >> 6, lane = tid & 63;
    const int quad = lane >> 4, l15 = lane & 15;
    const int wm = w & 3, wn = w >> 2;

    f32x4 acc[4][4] = {};

    const int KT = K >> 5;          // steps of 32 k (4 planes)

    auto STAGE = [&](int buf, int kt) {
        const int gp0 = kt << 2;
        short* Al = lds + buf * 12288;
        short* Bl = Al + 8192;
        // 24 chunks (16 A + 8 B), 3 per wave
#pragma unroll
        for (int i = 0; i < 3; ++i) {
            int c = i * 8 + w;
            if (c < 16) {
                int p = c >> 2, hh = c & 3;
                gl_lds16(Ab + ((size_t)(gp0 + p) * arows + m0 + hh * 64 + lane) * 8,
                         &Al[(p * 256 + hh * 64) * 8]);
            } else {
                int cb = c - 16, p = cb >> 1, hh = cb & 1;
                gl_lds16(Bb + ((size_t)(gp0 + p) * brows + n0 + hh * 64 + lane) * 8,
                         &Bl[(p * 128 + hh * 64) * 8]);
            }
        }
    };

    STAGE(0, 0);
    STAGE(1, 1);
    for (int kt = 0; kt < KT; ++kt) {
        wait_vmcnt(kt + 1 < KT ? 3 : 0);   // chunk kt complete; kt+1 (3 loads) stays in flight
        barrier_raw();
        if (kt + 2 < KT) STAGE((kt + 2) % 3, kt + 2);
        const short* Al = lds + (kt % 3) * 12288;
        const short* Bl = Al + 8192;
        bf16x8 af[4], bfr[4];
#pragma unroll
        for (int mi = 0; mi < 4; ++mi)
            af[mi] = *reinterpret_cast<const bf16x8*>(
                &Al[(quad * 256 + wm * 64 + mi * 16 + l15) * 8]);
#pragma unroll
        for (int ni = 0; ni < 4; ++ni)
            bfr[ni] = *reinterpret_cast<const bf16x8*>(
                &Bl[(quad * 128 + wn * 64 + ni * 16 + l15) * 8]);
#pragma unroll
        for (int mi = 0; mi < 4; ++mi)
#pragma unroll
            for (int ni = 0; ni < 4; ++ni)
                acc[mi][ni] = __builtin_amdgcn_mfma_f32_16x16x32_bf16(af[mi], bfr[ni], acc[mi][ni], 0, 0, 0);
    }
    __syncthreads();   // all waves done reading staging before epilogue overwrite

    // epilogue: acc -> bf16 row-major LDS tile [256][136], then 16B coalesced stores
#pragma unroll
    for (int mi = 0; mi < 4; ++mi) {
#pragma unroll
        for (int r = 0; r < 4; ++r) {
            int row = wm * 64 + mi * 16 + quad * 4 + r;
#pragma unroll
            for (int ni = 0; ni < 4; ++ni) {
                int col = wn * 64 + ni * 16 + l15;
                int gcol = n0 + col;
                float v = 0.0f;
                if (gcol < N) {
                    v = acc[mi][ni][r];
                    if (bias) v += bias[gcol];
                    if (relu) v = fmaxf(v, 0.0f);
                }
                lds[row * 136 + col] = f2bf(v);
            }
        }
    }
    __syncthreads();
    short* Cbz = C + (size_t)z * sCe;
    const long long zr = (long long)z * crz;
#pragma unroll
    for (int t = 0; t < 8; ++t) {
        int c = t * 512 + tid;
        int row = c & 255, p16 = c >> 8;
        int grow = m0 + row;
        int gcol0 = n0 + p16 * 8;
        if (grow < M && gcol0 < Npad) {
            bf16x8 v = *reinterpret_cast<const bf16x8*>(&lds[row * 136 + p16 * 8]);
            *reinterpret_cast<bf16x8*>(
                &Cbz[((size_t)(gcol0 >> 3) * crows + zr + grow) * 8]) = v;
        }
    }
}

// ---------------------------------------------------------------------------
// Fused GEMM (N=256) + residual + LayerNorm. Tile 64m x 256n; BK=32, 3
// staging buffers, 2-deep counted-vmcnt pipeline. Wave w owns COLS
// w*64..w*64+64 (4 m-frags x 4 n-frags) -> 8 ds_read_b128 per step.
// out[row] = LN(resid[row] + bf16(A·B^T + bias)) * g + b.  K % 64 == 0.
// ---------------------------------------------------------------------------
__global__ __launch_bounds__(256) void gemm_ln(
    const short* __restrict__ A,
    const short* __restrict__ B, int brows,
    const float* __restrict__ bias,
    const short* __restrict__ resid,
    const float* __restrict__ g, const float* __restrict__ bb,
    short* __restrict__ out, int K)
{
    __shared__ short lds[30720];        // 3 bufs of 10240: A [0,2048) B [2048,10240); epilogue rowt[64][264]
    __shared__ float gs[256], bs[256], bi_s[256];
    __shared__ float red[2][4][64];
    const int tid = threadIdx.x;
    const int m0 = blockIdx.x * 64;
    const int w = tid >> 6, lane = tid & 63;
    const int quad = lane >> 4, l15 = lane & 15;
    gs[tid] = g[tid]; bs[tid] = bb[tid]; bi_s[tid] = bias[tid];

    f32x4 acc[4][4] = {};
    const int KT = K >> 5;

    auto STAGE = [&](int buf, int kt) {
        const int gp0 = kt << 2;
        short* Al = lds + buf * 10240;
        short* Bl = Al + 2048;
        // 20 chunks (4 A + 16 B), 5 per wave
#pragma unroll
        for (int i = 0; i < 5; ++i) {
            int c = i * 4 + w;
            if (c < 4) {
                gl_lds16(A + ((size_t)(gp0 + c) * MR + m0 + lane) * 8, &Al[(c * 64) * 8]);
            } else {
                int cb = c - 4, p = cb >> 2, cq = cb & 3;
                gl_lds16(B + ((size_t)(gp0 + p) * brows + cq * 64 + lane) * 8,
                         &Bl[(p * 256 + cq * 64) * 8]);
            }
        }
    };

    STAGE(0, 0);
    STAGE(1, 1);
    for (int kt = 0; kt < KT; ++kt) {
        wait_vmcnt(kt + 1 < KT ? 5 : 0);
        barrier_raw();
        if (kt + 2 < KT) STAGE((kt + 2) % 3, kt + 2);
        const short* Al = lds + (kt % 3) * 10240;
        const short* Bl = Al + 2048;
        bf16x8 af[4], bfr[4];
#pragma unroll
        for (int mi = 0; mi < 4; ++mi)
            af[mi] = *reinterpret_cast<const bf16x8*>(
                &Al[(quad * 64 + mi * 16 + l15) * 8]);
#pragma unroll
        for (int ni = 0; ni < 4; ++ni)
            bfr[ni] = *reinterpret_cast<const bf16x8*>(
                &Bl[(quad * 256 + w * 64 + ni * 16 + l15) * 8]);
#pragma unroll
        for (int mi = 0; mi < 4; ++mi)
#pragma unroll
            for (int ni = 0; ni < 4; ++ni)
                acc[mi][ni] = __builtin_amdgcn_mfma_f32_16x16x32_bf16(af[mi], bfr[ni], acc[mi][ni], 0, 0, 0);
    }
    __syncthreads();   // staging reads complete before rowt overwrite

    // epilogue 1: bias add, round to bf16, into row-tile rowt[64][4 groups][66]
    // (66-stride breaks bank alignment). part = w (this wave's col quarter).
    short* rowt = lds;
#pragma unroll
    for (int mi = 0; mi < 4; ++mi)
#pragma unroll
        for (int ni = 0; ni < 4; ++ni) {
            int col = w * 64 + ni * 16 + l15;
#pragma unroll
            for (int r = 0; r < 4; ++r) {
                int row = mi * 16 + quad * 4 + r;
                rowt[row * 264 + w * 66 + ni * 16 + l15] = f2bf(acc[mi][ni][r] + bi_s[col]);
            }
        }
    __syncthreads();

    // epilogue 2: thread = (row, quarter): add residual, reduce, normalize
    const int row = tid >> 2, part = tid & 3;
    const int grow = m0 + row;
    float vv[8][8];
    float sum = 0.0f, sq = 0.0f;
#pragma unroll
    for (int i = 0; i < 8; ++i) {
        int plane = part * 8 + i;
        bf16x8 rv = *reinterpret_cast<const bf16x8*>(resid + ((size_t)plane * MR + grow) * 8);
        bf16x8 tv = *reinterpret_cast<const bf16x8*>(&rowt[row * 264 + part * 66 + i * 8]);
#pragma unroll
        for (int e = 0; e < 8; ++e) {
            float v = bf2f(tv[e]) + bf2f(rv[e]);
            vv[i][e] = v; sum += v; sq += v * v;
        }
    }
    red[0][part][row] = sum; red[1][part][row] = sq;
    __syncthreads();
    sum = red[0][0][row] + red[0][1][row] + red[0][2][row] + red[0][3][row];
    sq  = red[1][0][row] + red[1][1][row] + red[1][2][row] + red[1][3][row];
    float mu = sum * (1.0f / 256.0f);
    float var = sq * (1.0f / 256.0f) - mu * mu;
    float rstd = 1.0f / sqrtf(fmaxf(var, 0.0f) + 1e-5f);
#pragma unroll
    for (int i = 0; i < 8; ++i) {
        int plane = part * 8 + i;
        bf16x8 o;
#pragma unroll
        for (int e = 0; e < 8; ++e)
            o[e] = f2bf((vv[i][e] - mu) * rstd * gs[plane * 8 + e] + bs[plane * 8 + e]);
        *reinterpret_cast<bf16x8*>(out + ((size_t)plane * MR + grow) * 8) = o;
    }
}

// ---------------------------------------------------------------------------
// V transpose: per (b,h), vT[(bh*56 + kp)*64 + d]*8 + (key&7) = V[key][d],
// keys >= 400 zeroed. XCD-swizzled 1D grid (1792 = 8*224): all chunks of a
// (b,h) run on XCD bh%8 -> vT lands in the L2 that attn_p8 will read it from.
// ---------------------------------------------------------------------------
__global__ __launch_bounds__(256) void vtrans(
    const short* __restrict__ qkv, short* __restrict__ vT)
{
    __shared__ short tile[64][66];
    const int id = blockIdx.x;
    const int xcd = id & 7, rem = id >> 3;
    const int bh_hi = rem / 7, c = rem - bh_hi * 7;
    const int bh_i = bh_hi * 8 + xcd;
    const int h = bh_i & 3, b = bh_i >> 2;
    const int tid = threadIdx.x;
    const size_t bh = (size_t)bh_i;
    for (int t = tid; t < 512; t += 256) {
        int pp = t >> 6, l = t & 63;
        int j = c * 64 + l;
        bf16x8 v;
        if (j < NN)
            v = *reinterpret_cast<const bf16x8*>(
                qkv + (((size_t)(64 + 8 * h + pp)) * MR + (size_t)b * NN + j) * 8);
        else { for (int e = 0; e < 8; ++e) v[e] = 0; }
#pragma unroll
        for (int e = 0; e < 8; ++e) tile[l][pp * 8 + e] = v[e];
    }
    __syncthreads();
    for (int t = tid; t < 512; t += 256) {
        int kq = t >> 6, d = t & 63;
        int kp = c * 8 + kq;
        bf16x8 o;
#pragma unroll
        for (int e = 0; e < 8; ++e) o[e] = tile[kq * 8 + e][d];
        *reinterpret_cast<bf16x8*>(vT + ((bh * 56 + kp) * 64 + d) * 8) = o;
    }
}

// ---------------------------------------------------------------------------
// Attention, LDS-minimal: K and V fragments are read STRAIGHT FROM GLOBAL
// (both are L2-resident on this block's XCD thanks to the swizzle, and both
// access patterns are 16 lanes x 16B contiguous per quad = fully coalesced).
// LDS holds only the P tile (and transiently Q) -> 52 KB -> 3 blocks/CU.
// Barriers per block: 3. PV loop is barrier-free.
// ---------------------------------------------------------------------------
__global__ __launch_bounds__(256, 3) void attn_p8(
    const short* __restrict__ qkv, const short* __restrict__ vT,
    short* __restrict__ Out)
{
    __shared__ short PS[26624];   // P: 52 planes x 64 rows x 8 (53248 B); [0..4096) doubles as Q staging
    const int id = blockIdx.x;
    const int xcd = id & 7, rem = id >> 3;
    const int bh_hi = rem / 7, qt = rem - bh_hi * 7;
    const int bh_i = bh_hi * 8 + xcd;
    const int h = bh_i & 3, b = bh_i >> 2;
    const int tid = threadIdx.x;
    const int w = tid >> 6, lane = tid & 63;
    const int quad = lane >> 4, l15 = lane & 15;
    const size_t rowb = (size_t)b * NN;

    // stage Q (8 planes x 64 rows) into PS[0..4096)
    for (int j = w; j < 8; j += 4)
        gl_lds16(qkv + (((size_t)(8 * h + j)) * MR + rowb + qt * 64 + lane) * 8, &PS[j * 512]);
    __syncthreads();

    bf16x8 aq0 = *reinterpret_cast<const bf16x8*>(&PS[(quad * 64 + w * 16 + l15) * 8]);
    bf16x8 aq1 = *reinterpret_cast<const bf16x8*>(&PS[((4 + quad) * 64 + w * 16 + l15) * 8]);

    // QK^T: K fragment for (nt, quad) = 16B at plane (32+8h+quad), key nt*16+l15
    const short* Kb0 = qkv + ((size_t)(32 + 8 * h + quad) * MR + rowb + l15) * 8;
    const short* Kb1 = qkv + ((size_t)(36 + 8 * h + quad) * MR + rowb + l15) * 8;

    f32x4 sacc[25];
#pragma unroll
    for (int nt = 0; nt < 25; ++nt) { sacc[nt][0] = 0; sacc[nt][1] = 0; sacc[nt][2] = 0; sacc[nt][3] = 0; }
#pragma unroll
    for (int nt = 0; nt < 25; ++nt) {
        bf16x8 b0 = *reinterpret_cast<const bf16x8*>(Kb0 + nt * 128);
        bf16x8 b1 = *reinterpret_cast<const bf16x8*>(Kb1 + nt * 128);
        sacc[nt] = __builtin_amdgcn_mfma_f32_16x16x32_bf16(aq0, b0, sacc[nt], 0, 0, 0);
        sacc[nt] = __builtin_amdgcn_mfma_f32_16x16x32_bf16(aq1, b1, sacc[nt], 0, 0, 0);
    }

    float mx[4] = {-3e38f, -3e38f, -3e38f, -3e38f}, sm[4] = {0, 0, 0, 0};
#pragma unroll
    for (int nt = 0; nt < 25; ++nt)
#pragma unroll
        for (int r = 0; r < 4; ++r) mx[r] = fmaxf(mx[r], sacc[nt][r]);
#pragma unroll
    for (int r = 0; r < 4; ++r) {
        mx[r] = fmaxf(mx[r], __shfl_xor(mx[r], 1));
        mx[r] = fmaxf(mx[r], __shfl_xor(mx[r], 2));
        mx[r] = fmaxf(mx[r], __shfl_xor(mx[r], 4));
        mx[r] = fmaxf(mx[r], __shfl_xor(mx[r], 8));
    }
#pragma unroll
    for (int nt = 0; nt < 25; ++nt)
#pragma unroll
        for (int r = 0; r < 4; ++r) {
            float e = __expf((sacc[nt][r] - mx[r]) * 0.125f);
            sacc[nt][r] = e;
            sm[r] += e;
        }
#pragma unroll
    for (int r = 0; r < 4; ++r) {
        sm[r] += __shfl_xor(sm[r], 1);
        sm[r] += __shfl_xor(sm[r], 2);
        sm[r] += __shfl_xor(sm[r], 4);
        sm[r] += __shfl_xor(sm[r], 8);
    }
    __syncthreads();   // Q LDS reads complete -> P may overwrite PS

    // P transpose into PS (C-layout -> A-fragment layout), keys>=400 zeroed
#pragma unroll
    for (int nt = 0; nt < 25; ++nt)
#pragma unroll
        for (int r = 0; r < 4; ++r) {
            int colk = nt * 16 + l15;
            PS[((colk >> 3) * 64 + w * 16 + quad * 4 + r) * 8 + (colk & 7)] = f2bf(sacc[nt][r]);
        }
    for (int idx = tid; idx < 1024; idx += 256) PS[25600 + idx] = 0;

    f32x4 oacc[4];
#pragma unroll
    for (int dt = 0; dt < 4; ++dt) { oacc[dt][0] = 0; oacc[dt][1] = 0; oacc[dt][2] = 0; oacc[dt][3] = 0; }
    __syncthreads();   // P visible to all waves

    // PV, barrier-free: V fragment for (kt, quad, dt) = 16B at vT plane
    // bh*56 + kt*4 + quad, d = dt*16 + l15 (L2-resident, coalesced).
    const short* Vb = vT + (((size_t)bh_i * 56 + quad) * 64 + l15) * 8;
#pragma unroll
    for (int kt = 0; kt < 13; ++kt) {
        bf16x8 pa = *reinterpret_cast<const bf16x8*>(
            &PS[((kt * 4 + quad) * 64 + w * 16 + l15) * 8]);
#pragma unroll
        for (int dt = 0; dt < 4; ++dt) {
            bf16x8 vb = *reinterpret_cast<const bf16x8*>(Vb + kt * 2048 + dt * 128);
            oacc[dt] = __builtin_amdgcn_mfma_f32_16x16x32_bf16(pa, vb, oacc[dt], 0, 0, 0);
        }
    }
#pragma unroll
    for (int r = 0; r < 4; ++r) {
        int row = qt * 64 + w * 16 + quad * 4 + r;
        if (row >= NN) continue;
        float inv = 1.0f / sm[r];
#pragma unroll
        for (int dt = 0; dt < 4; ++dt) {
            int col = dt * 16 + l15;
            Out[(((size_t)(8 * h + (col >> 3))) * MR + rowb + row) * 8 + (col & 7)] =
                f2bf(oacc[dt][r] * inv);
        }
    }
}

// ---------------------------------------------------------------------------
// vectorized f32 -> P8 conversion: one thread per (row, 8-col group);
// float4 x2 reads, one bf16x8 store.
// ---------------------------------------------------------------------------
__global__ void conv_p8(const float* __restrict__ src, short* __restrict__ dst,
                        int R, int K, int Kp, int PR)
{
    const int G = Kp >> 3;
    int idx = blockIdx.x * 256 + threadIdx.x;
    if (idx >= R * G) return;
    int r = idx / G, g = idx - r * G;
    int k0 = g << 3;
    bf16x8 o;
    if (k0 + 8 <= K) {
        const float4 v0 = *reinterpret_cast<const float4*>(src + (size_t)r * K + k0);
        const float4 v1 = *reinterpret_cast<const float4*>(src + (size_t)r * K + k0 + 4);
        o[0] = f2bf(v0.x); o[1] = f2bf(v0.y); o[2] = f2bf(v0.z); o[3] = f2bf(v0.w);
        o[4] = f2bf(v1.x); o[5] = f2bf(v1.y); o[6] = f2bf(v1.z); o[7] = f2bf(v1.w);
    } else {
#pragma unroll
        for (int e = 0; e < 8; ++e) {
            int k = k0 + e;
            o[e] = (k < K) ? f2bf(src[(size_t)r * K + k]) : (short)0;
        }
    }
    *reinterpret_cast<bf16x8*>(dst + ((size_t)g * PR + r) * 8) = o;
}

// ---------------------------------------------------------------------------
// batched f32 -> P8 conversion for the 11 small weight matrices: one launch
// instead of 11 (saves ~10 launch slots). Segment table passed by value.
// ---------------------------------------------------------------------------
struct ConvSeg { const float* src; short* dst; int R, K, Kp, start; };
struct ConvPack { ConvSeg s[11]; int total; };

__global__ void conv_multi(ConvPack p)
{
    int idx = blockIdx.x * 256 + threadIdx.x;
    if (idx >= p.total) return;
    int si = 0;
#pragma unroll
    for (int t = 1; t < 11; ++t) if (idx >= p.s[t].start) si = t;
    const ConvSeg sg = p.s[si];
    int local = idx - sg.start;
    const int G = sg.Kp >> 3;
    int r = local / G, g = local - r * G;
    int k0 = g << 3;
    bf16x8 o;
    if (k0 + 8 <= sg.K) {
        const float4 v0 = *reinterpret_cast<const float4*>(sg.src + (size_t)r * sg.K + k0);
        const float4 v1 = *reinterpret_cast<const float4*>(sg.src + (size_t)r * sg.K + k0 + 4);
        o[0] = f2bf(v0.x); o[1] = f2bf(v0.y); o[2] = f2bf(v0.z); o[3] = f2bf(v0.w);
        o[4] = f2bf(v1.x); o[5] = f2bf(v1.y); o[6] = f2bf(v1.z); o[7] = f2bf(v1.w);
    } else {
#pragma unroll
        for (int e = 0; e < 8; ++e) {
            int k = k0 + e;
            o[e] = (k < sg.K) ? f2bf(sg.src[(size_t)r * sg.K + k]) : (short)0;
        }
    }
    *reinterpret_cast<bf16x8*>(sg.dst + ((size_t)g * sg.R + r) * 8) = o;
}

// ---------------------------------------------------------------------------
__global__ __launch_bounds__(256) void w1_p8(
    const float* __restrict__ W1, short* __restrict__ Wp)
{
    __shared__ float tile[128][129];
    const int k0 = blockIdx.x * 128;
    const int tid = threadIdx.x;
    for (int t = 0; t < 16; ++t) {
        int idx = t * 256 + tid;
        int r = idx >> 5, k4 = idx & 31;
        float4 v = *(const float4*)(W1 + (size_t)r * 102400 + k0 + k4 * 4);
        tile[r][k4 * 4 + 0] = v.x; tile[r][k4 * 4 + 1] = v.y;
        tile[r][k4 * 4 + 2] = v.z; tile[r][k4 * 4 + 3] = v.w;
    }
    __syncthreads();
    for (int t = 0; t < 8; ++t) {
        int idx = t * 256 + tid;
        int pidx = idx >> 7, r = idx & 127;
        bf16x8 o;
#pragma unroll
        for (int e = 0; e < 8; ++e) o[e] = f2bf(tile[r][pidx * 8 + e]);
        *reinterpret_cast<bf16x8*>(Wp + (((size_t)(k0 >> 3) + pidx) * 128 + r) * 8) = o;
    }
}

// ---------------------------------------------------------------------------
__global__ void colsum_dinv(const float* __restrict__ sc, float* __restrict__ dinv)
{
    int b = blockIdx.y;
    int j = blockIdx.x * 256 + threadIdx.x;
    if (j >= NN) return;
    const float* p = sc + (size_t)b * NN * NN + j;
    float s = 0.0f;
    for (int i = 0; i < NN; ++i) s += p[(size_t)i * NN];
    dinv[b * NN + j] = (s > 0.0f) ? 1.0f / sqrtf(s) : 0.0f;
}

// ---------------------------------------------------------------------------
__global__ __launch_bounds__(256) void sc_prep(
    const float* __restrict__ sc, const float* __restrict__ dinv,
    short* __restrict__ scb, short* __restrict__ anT)
{
    __shared__ float tile[64][65];
    const int b = blockIdx.z;
    const int i0 = blockIdx.y * 64, j0 = blockIdx.x * 64;
    const int tid = threadIdx.x;
    const float* sb = sc + (size_t)b * NN * NN;
    short* scbb = scb + (size_t)b * 56 * 512 * 8;
    short* anTb = anT + (size_t)b * 56 * 512 * 8;
    for (int e = tid; e < 4096; e += 256) {
        int r = e >> 6, c = e & 63;
        int i = i0 + r, j = j0 + c;
        tile[r][c] = (i < NN && j < NN) ? sb[(size_t)i * NN + j] : 0.0f;
    }
    __syncthreads();
    for (int e = tid; e < 4096; e += 256) {
        int r = e >> 6, c = e & 63;
        int i = i0 + r, j = j0 + c;
        scbb[((size_t)(j >> 3) * 512 + i) * 8 + (j & 7)] = f2bf(tile[r][c]);
        float v = 0.0f;
        if (i < NN && j < NN) v = tile[r][c] * dinv[b * NN + i] * dinv[b * NN + j];
        anTb[((size_t)(i >> 3) * 512 + j) * 8 + (i & 7)] = f2bf(v);
    }
}

// ---------------------------------------------------------------------------
__global__ __launch_bounds__(256) void cls_gemm(
    const short* __restrict__ C1, const short* __restrict__ C2,
    const short* __restrict__ Wp, float* __restrict__ partial)
{
    __shared__ short Al[32 * 64 * 8];
    __shared__ short Wl[8 * 128 * 8];
    const int j = blockIdx.x;
    const int tid = threadIdx.x;
    const int w = tid >> 6, lane = tid & 63;
    const int quad = lane >> 4, l15 = lane & 15;

    for (int s = 0; s < 8; ++s) {
        int idx = s * 256 + tid;
        int p = idx >> 6, b = idx & 63;
        size_t ad = ((size_t)p * MR + (size_t)b * NN + j) * 8;
        bf16x8 a = *reinterpret_cast<const bf16x8*>(C1 + ad);
        bf16x8 c = *reinterpret_cast<const bf16x8*>(C2 + ad);
        bf16x8 o;
#pragma unroll
        for (int e = 0; e < 8; ++e) o[e] = f2bf(0.5f * (bf2f(a[e]) + bf2f(c[e])));
        *reinterpret_cast<bf16x8*>(&Al[(p * 64 + b) * 8]) = o;
    }

    f32x4 acc[4][2] = {};
    const size_t wp0 = (size_t)j * 32;
    for (int s = 0; s < 4; ++s) {
#pragma unroll
        for (int pp = 0; pp < 2; ++pp) {
            int p = w + pp * 4;
            gl_lds16(Wp + ((wp0 + s * 8 + p) * 128 + lane) * 8,      &Wl[(p * 128) * 8]);
            gl_lds16(Wp + ((wp0 + s * 8 + p) * 128 + 64 + lane) * 8, &Wl[(p * 128 + 64) * 8]);
        }
        __syncthreads();
#pragma unroll
        for (int kb = 0; kb < 2; ++kb) {
            bf16x8 af[4], bfr[2];
#pragma unroll
            for (int mi = 0; mi < 4; ++mi)
                af[mi] = *reinterpret_cast<const bf16x8*>(
                    &Al[((s * 8 + kb * 4 + quad) * 64 + mi * 16 + l15) * 8]);
#pragma unroll
            for (int ni = 0; ni < 2; ++ni)
                bfr[ni] = *reinterpret_cast<const bf16x8*>(
                    &Wl[((kb * 4 + quad) * 128 + w * 32 + ni * 16 + l15) * 8]);
#pragma unroll
            for (int mi = 0; mi < 4; ++mi)
#pragma unroll
                for (int ni = 0; ni < 2; ++ni)
                    acc[mi][ni] = __builtin_amdgcn_mfma_f32_16x16x32_bf16(af[mi], bfr[ni], acc[mi][ni], 0, 0, 0);
        }
        __syncthreads();
    }
    float* pj = partial + (size_t)j * 8192;
#pragma unroll
    for (int mi = 0; mi < 4; ++mi)
#pragma unroll
        for (int r = 0; r < 4; ++r) {
            int row = mi * 16 + quad * 4 + r;
#pragma unroll
            for (int ni = 0; ni < 2; ++ni)
                pj[row * 128 + w * 32 + ni * 16 + l15] = acc[mi][ni][r];
        }
}

__global__ void cls_reduce(const float* __restrict__ partial, float* __restrict__ clsh)
{
    int o = blockIdx.x * 256 + threadIdx.x;
    float s = 0.0f;
    for (int kb = 0; kb < 400; ++kb) s += partial[(size_t)kb * 8192 + o];
    clsh[o] = s;
}

__global__ void logits_final(
    const float* __restrict__ clsh, const float* __restrict__ b1,
    const float* __restrict__ w2, const float* __restrict__ b2,
    float* __restrict__ out)
{
    __shared__ float t[128];
    int b = blockIdx.x;
    int tid = threadIdx.x;
    t[tid] = fmaxf(clsh[b * 128 + tid] + b1[tid], 0.0f);
    __syncthreads();
    if (tid < 2) {
        float s = b2[tid];
        for (int o = 0; o < 128; ++o) s += t[o] * w2[tid * 128 + o];
        out[b * 2 + tid] = s;
    }
}

// ---------------------------------------------------------------------------
extern "C" void kernel_launch(void* const* d_in, const int* in_sizes, int n_in,
                              void* d_out, int out_size, void* d_ws, size_t ws_size,
                              hipStream_t stream)
{
    const float* fc        = (const float*)d_in[0];
    const float* sc        = (const float*)d_in[1];
    const float* proj_w    = (const float*)d_in[2];
    const float* proj_b    = (const float*)d_in[3];
    const float* enc_qkv_w = (const float*)d_in[4];
    const float* enc_qkv_b = (const float*)d_in[5];
    const float* enc_out_w = (const float*)d_in[6];
    const float* enc_out_b = (const float*)d_in[7];
    const float* enc_l1_w  = (const float*)d_in[8];
    const float* enc_l1_b  = (const float*)d_in[9];
    const float* enc_l2_w  = (const float*)d_in[10];
    const float* enc_l2_b  = (const float*)d_in[11];
    const float* enc_n1_g  = (const float*)d_in[12];
    const float* enc_n1_b  = (const float*)d_in[13];
    const float* enc_n2_g  = (const float*)d_in[14];
    const float* enc_n2_b  = (const float*)d_in[15];
    const float* gcn_w1    = (const float*)d_in[16];
    const float* gcn_b1    = (const float*)d_in[17];
    const float* gcn_w2    = (const float*)d_in[18];
    const float* gcn_b2    = (const float*)d_in[19];
    const float* ca1_qkv_w = (const float*)d_in[20];
    const float* ca1_qkv_b = (const float*)d_in[21];
    const float* ca1_out_w = (const float*)d_in[22];
    const float* ca1_out_b = (const float*)d_in[23];
    const float* ca1_n_g   = (const float*)d_in[24];
    const float* ca1_n_b   = (const float*)d_in[25];
    const float* ca2_qkv_w = (const float*)d_in[26];
    const float* ca2_qkv_b = (const float*)d_in[27];
    const float* ca2_out_w = (const float*)d_in[28];
    const float* ca2_out_b = (const float*)d_in[29];
    const float* ca2_n_g   = (const float*)d_in[30];
    const float* ca2_n_b   = (const float*)d_in[31];
    const float* cls_w1    = (const float*)d_in[32];
    const float* cls_b1    = (const float*)d_in[33];
    const float* cls_w2    = (const float*)d_in[34];
    const float* cls_b2    = (const float*)d_in[35];

    char* wsb = (char*)d_ws;
    size_t off = 0;
    auto alloc = [&](size_t bytes) { char* r = wsb + off; off += (bytes + 255) & ~(size_t)255; return r; };
    short* bufBig = (short*)alloc((size_t)MR * 1024 * 2);
    short* fcb    = (short*)alloc((size_t)56 * MR * 8 * 2);
    short* anT    = (short*)alloc((size_t)NB * 56 * 512 * 8 * 2);
    short* bufH   = (short*)alloc((size_t)32 * MR * 8 * 2);
    short* bufA   = (short*)alloc((size_t)32 * MR * 8 * 2);
    short* bufC   = (short*)alloc((size_t)32 * MR * 8 * 2);
    short* bufZS  = (short*)alloc((size_t)32 * MR * 8 * 2);
    short* vT     = (short*)alloc((size_t)NB * NHH * 56 * 64 * 8 * 2);
    short* w1b    = (short*)alloc((size_t)12800 * 128 * 8 * 2);
    short* projwb = (short*)alloc((size_t)56 * 256 * 8 * 2);
    short* qkvwb  = (short*)alloc((size_t)32 * 1536 * 8 * 2);
    short* outwb  = (short*)alloc((size_t)32 * 512 * 8 * 2);
    short* l1wb   = (short*)alloc((size_t)32 * 2048 * 8 * 2);
    short* l2wb   = (short*)alloc((size_t)128 * 512 * 8 * 2);
    short* gw1b   = (short*)alloc((size_t)56 * 256 * 8 * 2);
    short* gw2b   = (short*)alloc((size_t)32 * 256 * 8 * 2);
    short* c1qb   = (short*)alloc((size_t)32 * 768 * 8 * 2);
    short* c1ob   = (short*)alloc((size_t)32 * 256 * 8 * 2);
    short* c2qb   = (short*)alloc((size_t)32 * 768 * 8 * 2);
    short* c2ob   = (short*)alloc((size_t)32 * 256 * 8 * 2);
    float* dinv   = (float*)alloc((size_t)MR * 4);
    float* clsh   = (float*)alloc((size_t)NB * 128 * 4);
    short* scb = bufBig;
    short* XT1 = bufBig + (size_t)64 * 56 * 512 * 8;
    short* h1  = bufBig;
    short* XT2 = XT1;
    float* partial = (float*)fcb;

    dim3 blk(256), blk512(512);
    auto cgrid = [](long long n) { return dim3((unsigned)((n + 255) / 256)); };

    // ---- conversions to P8 ----
    conv_p8<<<cgrid((long long)MR * 56), blk, 0, stream>>>(fc, fcb, MR, 400, 448, MR);
    {
        ConvPack pk;
        int st = 0;
        auto seg = [&](int i, const float* s, short* d, int R, int K, int Kp) {
            pk.s[i].src = s; pk.s[i].dst = d; pk.s[i].R = R; pk.s[i].K = K;
            pk.s[i].Kp = Kp; pk.s[i].start = st; st += R * (Kp >> 3);
        };
        seg(0,  proj_w,    projwb, 256,  400,  448);
        seg(1,  enc_qkv_w, qkvwb,  1536, 256,  256);
        seg(2,  enc_out_w, outwb,  512,  256,  256);
        seg(3,  enc_l1_w,  l1wb,   2048, 256,  256);
        seg(4,  enc_l2_w,  l2wb,   512,  1024, 1024);
        seg(5,  gcn_w1,    gw1b,   256,  400,  448);
        seg(6,  gcn_w2,    gw2b,   256,  256,  256);
        seg(7,  ca1_qkv_w, c1qb,   768,  256,  256);
        seg(8,  ca1_out_w, c1ob,   256,  256,  256);
        seg(9,  ca2_qkv_w, c2qb,   768,  256,  256);
        seg(10, ca2_out_w, c2ob,   256,  256,  256);
        pk.total = st;
        conv_multi<<<cgrid(st), blk, 0, stream>>>(pk);
    }
    w1_p8<<<800, blk, 0, stream>>>(cls_w1, w1b);

    // ---- FC branch ----
    gemm_p8<<<dim3(100, 2, 1), blk512, 0, stream>>>(
        fcb, MR, 0, projwb, 256, 0, proj_b, bufH, MR, 0, 0, MR, 256, 256, 448, 0);
    for (int l = 0; l < 2; ++l) {
        gemm_p8<<<dim3(100, 6, 1), blk512, 0, stream>>>(
            bufH, MR, 0, qkvwb + (size_t)l * 768 * 8, 1536, 0, enc_qkv_b + l * 768,
            bufBig, MR, 0, 0, MR, 768, 768, 256, 0);
        vtrans<<<dim3(1792), blk, 0, stream>>>(bufBig, vT);
        attn_p8<<<dim3(1792), blk, 0, stream>>>(bufBig, vT, bufA);
        // attn-out GEMM + residual + LN (in-place on bufH)
        gemm_ln<<<400, blk, 0, stream>>>(
            bufA, outwb + (size_t)l * 256 * 8, 512, enc_out_b + l * 256,
            bufH, enc_n1_g + l * DD, enc_n1_b + l * DD, bufH, 256);
        gemm_p8<<<dim3(100, 8, 1), blk512, 0, stream>>>(
            bufH, MR, 0, l1wb + (size_t)l * 1024 * 8, 2048, 0, enc_l1_b + l * 1024,
            bufBig, MR, 0, 0, MR, 1024, 1024, 256, 1);
        // FF2 GEMM + residual + LN (in-place on bufH)
        gemm_ln<<<400, blk, 0, stream>>>(
            bufBig, l2wb + (size_t)l * 256 * 8, 512, enc_l2_b + l * 256,
            bufH, enc_n2_g + l * DD, enc_n2_b + l * DD, bufH, 1024);
    }

    // ---- GCN branch ----
    colsum_dinv<<<dim3(2, NB), blk, 0, stream>>>(sc, dinv);
    sc_prep<<<dim3(7, 7, NB), blk, 0, stream>>>(sc, dinv, scb, anT);
    gemm_p8<<<dim3(1, 4, NB), blk512, 0, stream>>>(
        gw1b, 256, 0, scb, 512, 56LL * 512 * 8, nullptr,
        XT1, 256, 0, 56LL * 256 * 8, 256, 400, 448, 448, 0);
    gemm_p8<<<dim3(2, 2, NB), blk512, 0, stream>>>(
        anT, 512, 56LL * 512 * 8, XT1, 256, 56LL * 256 * 8, gcn_b1,
        h1, 512, 0, 32LL * 512 * 8, 400, 256, 256, 448, 1);
    gemm_p8<<<dim3(1, 4, NB), blk512, 0, stream>>>(
        gw2b, 256, 0, h1, 512, 32LL * 512 * 8, nullptr,
        XT2, 256, 0, 56LL * 256 * 8, 256, 400, 448, 256, 0);
    gemm_p8<<<dim3(2, 2, NB), blk512, 0, stream>>>(
        anT, 512, 56LL * 512 * 8, XT2, 256, 56LL * 256 * 8, gcn_b2,
        bufZS, MR, 400, 0, 400, 256, 256, 448, 0);

    // ---- Cross attention 1: Q = Z_F, KV = Z_S ----
    gemm_p8<<<dim3(100, 2, 1), blk512, 0, stream>>>(
        bufH, MR, 0, c1qb, 768, 0, ca1_qkv_b, bufBig, MR, 0, 0, MR, 256, 256, 256, 0);
    gemm_p8<<<dim3(100, 4, 1), blk512, 0, stream>>>(
        bufZS, MR, 0, c1qb + 256 * 8, 768, 0, ca1_qkv_b + 256,
        bufBig + (size_t)32 * MR * 8, MR, 0, 0, MR, 512, 512, 256, 0);
    vtrans<<<dim3(1792), blk, 0, stream>>>(bufBig, vT);
    attn_p8<<<dim3(1792), blk, 0, stream>>>(bufBig, vT, bufA);
    gemm_ln<<<400, blk, 0, stream>>>(
        bufA, c1ob, 256, ca1_out_b, bufH, ca1_n_g, ca1_n_b, bufC, 256);

    // ---- Cross attention 2: Q = Z_S, KV = Z_F ----
    gemm_p8<<<dim3(100, 2, 1), blk512, 0, stream>>>(
        bufZS, MR, 0, c2qb, 768, 0, ca2_qkv_b, bufBig, MR, 0, 0, MR, 256, 256, 256, 0);
    gemm_p8<<<dim3(100, 4, 1), blk512, 0, stream>>>(
        bufH, MR, 0, c2qb + 256 * 8, 768, 0, ca2_qkv_b + 256,
        bufBig + (size_t)32 * MR * 8, MR, 0, 0, MR, 512, 512, 256, 0);
    vtrans<<<dim3(1792), blk, 0, stream>>>(bufBig, vT);
    attn_p8<<<dim3(1792), blk, 0, stream>>>(bufBig, vT, bufA);
    gemm_ln<<<400, blk, 0, stream>>>(
        bufA, c2ob, 256, ca2_out_b, bufZS, ca2_n_g, ca2_n_b, bufZS, 256);

    // ---- Classifier ----
    cls_gemm<<<400, blk, 0, stream>>>(bufC, bufZS, w1b, partial);
    cls_reduce<<<32, blk, 0, stream>>>(partial, clsh);
    logits_final<<<NB, 128, 0, stream>>>(clsh, cls_b1, cls_w2, cls_b2, (float*)d_out);
}

// Round 14
// 894.141 us; speedup vs baseline: 1.1407x; 1.0062x over previous
//
#include <hip/hip_runtime.h>
#include <math.h>

// Problem constants
#define NB   64
#define NN   400
#define DD   256
#define NHH  4
#define HDD  64
#define MR   25600            // NB*NN

typedef __attribute__((ext_vector_type(8))) short bf16x8;
typedef __attribute__((ext_vector_type(4))) float f32x4;

__device__ __forceinline__ short f2bf(float x) {
    union { float f; unsigned u; } v; v.f = x;
    return (short)((v.u + 0x7FFFu + ((v.u >> 16) & 1u)) >> 16);
}
__device__ __forceinline__ float bf2f(short s) {
    union { unsigned u; float f; } v; v.u = ((unsigned)(unsigned short)s) << 16;
    return v.f;
}
// async global->LDS, 16 B/lane; src = per-lane addr, LDS dest = wave-uniform base
__device__ __forceinline__ void gl_lds16(const void* g, void* l) {
    __builtin_amdgcn_global_load_lds(
        (const __attribute__((address_space(1))) unsigned*)g,
        (__attribute__((address_space(3))) unsigned*)l, 16, 0, 0);
}
// counted vmcnt wait (T4): never drain to 0 in a main loop. "memory" clobber
// orders LDS reads after the wait at IR level. vmcnt is per-wave.
__device__ __forceinline__ void wait_vmcnt(int n) {
    switch (n) {
    case 0: asm volatile("s_waitcnt vmcnt(0)" ::: "memory"); break;
    case 1: asm volatile("s_waitcnt vmcnt(1)" ::: "memory"); break;
    case 2: asm volatile("s_waitcnt vmcnt(2)" ::: "memory"); break;
    case 3: asm volatile("s_waitcnt vmcnt(3)" ::: "memory"); break;
    case 4: asm volatile("s_waitcnt vmcnt(4)" ::: "memory"); break;
    default: asm volatile("s_waitcnt vmcnt(5)" ::: "memory"); break;
    }
}
__device__ __forceinline__ void barrier_raw() {
    __builtin_amdgcn_sched_barrier(0);
    __builtin_amdgcn_s_barrier();
    __builtin_amdgcn_sched_barrier(0);
}

// ---------------------------------------------------------------------------
// P8 layout: element (row, k) lives at ((k>>3)*rows + row)*8 + (k&7) (bf16).
// = the 16x16x32 MFMA fragment layout; staging is contiguous 1 KiB bursts.
// ---------------------------------------------------------------------------

// bf16 GEMM, 256x128 tile, 512 threads (8 waves: 4m x 2n), BK=32, 3 staging
// buffers, 2-deep counted-vmcnt pipeline, T1 XCD-chunked block swizzle
// (measured: total 940->900, gemm_p8 out of top-5). FROZEN.
__global__ __launch_bounds__(512, 4) void gemm_p8(
    const short* __restrict__ A, int arows, long long sA,
    const short* __restrict__ B, int brows, long long sB,
    const float* __restrict__ bias,
    short* __restrict__ C, int crows, int crz, long long sCe,
    int M, int N, int Npad, int K, int relu)
{
    __shared__ short lds[36864];   // 3 bufs of 12288 (A 8192 + B 4096); epilogue [256][136] fits
    const int tid = threadIdx.x;

    // XCD-chunked swizzle of the flattened grid (x = m-tile, y = n-tile, z = batch)
    const unsigned gx = gridDim.x, gy = gridDim.y;
    const unsigned nwg = gx * gy * gridDim.z;
    const unsigned lin = (blockIdx.z * gy + blockIdx.y) * gx + blockIdx.x;
    const unsigned g = (lin & 7) * (nwg >> 3) + (lin >> 3);   // xcd-contiguous
    const unsigned zz = g / (gx * gy);
    const unsigned rem2 = g - zz * gx * gy;
    const unsigned mx = rem2 / gy;          // m-major: same-m blocks share an XCD
    const unsigned ny = rem2 - mx * gy;

    const int z = (int)zz;
    const int m0 = (int)mx * 256, n0 = (int)ny * 128;
    const short* Ab = A + (size_t)z * sA;
    const short* Bb = B + (size_t)z * sB;

    const int w = tid >> 6, lane = tid & 63;
    const int quad = lane >> 4, l15 = lane & 15;
    const int wm = w & 3, wn = w >> 2;

    f32x4 acc[4][4] = {};

    const int KT = K >> 5;          // steps of 32 k (4 planes)

    auto STAGE = [&](int buf, int kt) {
        const int gp0 = kt << 2;
        short* Al = lds + buf * 12288;
        short* Bl = Al + 8192;
        // 24 chunks (16 A + 8 B), 3 per wave
#pragma unroll
        for (int i = 0; i < 3; ++i) {
            int c = i * 8 + w;
            if (c < 16) {
                int p = c >> 2, hh = c & 3;
                gl_lds16(Ab + ((size_t)(gp0 + p) * arows + m0 + hh * 64 + lane) * 8,
                         &Al[(p * 256 + hh * 64) * 8]);
            } else {
                int cb = c - 16, p = cb >> 1, hh = cb & 1;
                gl_lds16(Bb + ((size_t)(gp0 + p) * brows + n0 + hh * 64 + lane) * 8,
                         &Bl[(p * 128 + hh * 64) * 8]);
            }
        }
    };

    STAGE(0, 0);
    STAGE(1, 1);
    for (int kt = 0; kt < KT; ++kt) {
        wait_vmcnt(kt + 1 < KT ? 3 : 0);   // chunk kt complete; kt+1 (3 loads) stays in flight
        barrier_raw();
        if (kt + 2 < KT) STAGE((kt + 2) % 3, kt + 2);
        const short* Al = lds + (kt % 3) * 12288;
        const short* Bl = Al + 8192;
        bf16x8 af[4], bfr[4];
#pragma unroll
        for (int mi = 0; mi < 4; ++mi)
            af[mi] = *reinterpret_cast<const bf16x8*>(
                &Al[(quad * 256 + wm * 64 + mi * 16 + l15) * 8]);
#pragma unroll
        for (int ni = 0; ni < 4; ++ni)
            bfr[ni] = *reinterpret_cast<const bf16x8*>(
                &Bl[(quad * 128 + wn * 64 + ni * 16 + l15) * 8]);
#pragma unroll
        for (int mi = 0; mi < 4; ++mi)
#pragma unroll
            for (int ni = 0; ni < 4; ++ni)
                acc[mi][ni] = __builtin_amdgcn_mfma_f32_16x16x32_bf16(af[mi], bfr[ni], acc[mi][ni], 0, 0, 0);
    }
    __syncthreads();   // all waves done reading staging before epilogue overwrite

    // epilogue: acc -> bf16 row-major LDS tile [256][136], then 16B coalesced stores
#pragma unroll
    for (int mi = 0; mi < 4; ++mi) {
#pragma unroll
        for (int r = 0; r < 4; ++r) {
            int row = wm * 64 + mi * 16 + quad * 4 + r;
#pragma unroll
            for (int ni = 0; ni < 4; ++ni) {
                int col = wn * 64 + ni * 16 + l15;
                int gcol = n0 + col;
                float v = 0.0f;
                if (gcol < N) {
                    v = acc[mi][ni][r];
                    if (bias) v += bias[gcol];
                    if (relu) v = fmaxf(v, 0.0f);
                }
                lds[row * 136 + col] = f2bf(v);
            }
        }
    }
    __syncthreads();
    short* Cbz = C + (size_t)z * sCe;
    const long long zr = (long long)z * crz;
#pragma unroll
    for (int t = 0; t < 8; ++t) {
        int c = t * 512 + tid;
        int row = c & 255, p16 = c >> 8;
        int grow = m0 + row;
        int gcol0 = n0 + p16 * 8;
        if (grow < M && gcol0 < Npad) {
            bf16x8 v = *reinterpret_cast<const bf16x8*>(&lds[row * 136 + p16 * 8]);
            *reinterpret_cast<bf16x8*>(
                &Cbz[((size_t)(gcol0 >> 3) * crows + zr + grow) * 8]) = v;
        }
    }
}

// ---------------------------------------------------------------------------
// Fused GEMM (N=256) + residual + LayerNorm. Tile 64m x 256n; 512 threads
// (8 waves), wave w owns a 32-col EIGHTH (4 m-frags x 2 n-frags, 8 MFMA +
// 6 ds_read/step). LDS ~68KB -> 2 blocks/CU x 8 waves = 16 waves/CU (2x) —
// the occupancy lever that gave gemm_p8 +27% in R8. BK=32, 3 staging
// buffers, 2-deep counted-vmcnt (waves 0-3: 3 loads/chunk, waves 4-7: 2).
// out[row] = LN(resid[row] + bf16(A·B^T + bias)) * g + b.  K % 64 == 0.
// ---------------------------------------------------------------------------
__global__ __launch_bounds__(512, 4) void gemm_ln(
    const short* __restrict__ A,
    const short* __restrict__ B, int brows,
    const float* __restrict__ bias,
    const short* __restrict__ resid,
    const float* __restrict__ g, const float* __restrict__ bb,
    short* __restrict__ out, int K)
{
    __shared__ short lds[30720];        // 3 bufs of 10240: A [0,2048) B [2048,10240); epilogue rowt[64][264]
    __shared__ float gs[256], bs[256], bi_s[256];
    __shared__ float red[2][8][64];
    const int tid = threadIdx.x;
    const int m0 = blockIdx.x * 64;
    const int w = tid >> 6, lane = tid & 63;
    const int quad = lane >> 4, l15 = lane & 15;
    if (tid < 256) { gs[tid] = g[tid]; bs[tid] = bb[tid]; bi_s[tid] = bias[tid]; }

    f32x4 acc[4][2] = {};
    const int KT = K >> 5;
    const int myloads = (w < 4) ? 3 : 2;   // per-wave loads per STAGE (vmcnt is per-wave)

    auto STAGE = [&](int buf, int kt) {
        const int gp0 = kt << 2;
        short* Al = lds + buf * 10240;
        short* Bl = Al + 2048;
        // 20 chunks (4 A + 16 B), 8 waves: waves 0-3 take 3, waves 4-7 take 2
#pragma unroll
        for (int i = 0; i < 3; ++i) {
            int c = i * 8 + w;
            if (c < 4) {
                gl_lds16(A + ((size_t)(gp0 + c) * MR + m0 + lane) * 8, &Al[(c * 64) * 8]);
            } else if (c < 20) {
                int cb = c - 4, p = cb >> 2, cq = cb & 3;
                gl_lds16(B + ((size_t)(gp0 + p) * brows + cq * 64 + lane) * 8,
                         &Bl[(p * 256 + cq * 64) * 8]);
            }
        }
    };

    STAGE(0, 0);
    STAGE(1, 1);
    for (int kt = 0; kt < KT; ++kt) {
        wait_vmcnt(kt + 1 < KT ? myloads : 0);
        barrier_raw();
        if (kt + 2 < KT) STAGE((kt + 2) % 3, kt + 2);
        const short* Al = lds + (kt % 3) * 10240;
        const short* Bl = Al + 2048;
        bf16x8 af[4], bfr[2];
#pragma unroll
        for (int mi = 0; mi < 4; ++mi)
            af[mi] = *reinterpret_cast<const bf16x8*>(
                &Al[(quad * 64 + mi * 16 + l15) * 8]);
#pragma unroll
        for (int ni = 0; ni < 2; ++ni)
            bfr[ni] = *reinterpret_cast<const bf16x8*>(
                &Bl[(quad * 256 + w * 32 + ni * 16 + l15) * 8]);
#pragma unroll
        for (int mi = 0; mi < 4; ++mi)
#pragma unroll
            for (int ni = 0; ni < 2; ++ni)
                acc[mi][ni] = __builtin_amdgcn_mfma_f32_16x16x32_bf16(af[mi], bfr[ni], acc[mi][ni], 0, 0, 0);
    }
    __syncthreads();   // staging reads complete before rowt overwrite

    // epilogue 1: bias add, round to bf16, into row-tile rowt[64][4 groups][66]
    // (66-stride breaks bank alignment). Wave w owns cols w*32..w*32+32.
    short* rowt = lds;
#pragma unroll
    for (int mi = 0; mi < 4; ++mi)
#pragma unroll
        for (int ni = 0; ni < 2; ++ni) {
            int col = w * 32 + ni * 16 + l15;
            int part = col >> 6, idx = col & 63;
#pragma unroll
            for (int r = 0; r < 4; ++r) {
                int row = mi * 16 + quad * 4 + r;
                rowt[row * 264 + part * 66 + idx] = f2bf(acc[mi][ni][r] + bi_s[col]);
            }
        }
    __syncthreads();

    // epilogue 2: thread = (row, eighth): 64 rows x 8 parts, 32 cols each
    const int row = tid >> 3, part = tid & 7;
    const int grow = m0 + row;
    float vv[4][8];
    float sum = 0.0f, sq = 0.0f;
#pragma unroll
    for (int i = 0; i < 4; ++i) {
        int plane = part * 4 + i;            // 8-col group index (0..31)
        bf16x8 rv = *reinterpret_cast<const bf16x8*>(resid + ((size_t)plane * MR + grow) * 8);
        bf16x8 tv = *reinterpret_cast<const bf16x8*>(
            &rowt[row * 264 + (plane >> 3) * 66 + (plane & 7) * 8]);
#pragma unroll
        for (int e = 0; e < 8; ++e) {
            float v = bf2f(tv[e]) + bf2f(rv[e]);
            vv[i][e] = v; sum += v; sq += v * v;
        }
    }
    red[0][part][row] = sum; red[1][part][row] = sq;
    __syncthreads();
    sum = 0.0f; sq = 0.0f;
#pragma unroll
    for (int p = 0; p < 8; ++p) { sum += red[0][p][row]; sq += red[1][p][row]; }
    float mu = sum * (1.0f / 256.0f);
    float var = sq * (1.0f / 256.0f) - mu * mu;
    float rstd = 1.0f / sqrtf(fmaxf(var, 0.0f) + 1e-5f);
#pragma unroll
    for (int i = 0; i < 4; ++i) {
        int plane = part * 4 + i;
        bf16x8 o;
#pragma unroll
        for (int e = 0; e < 8; ++e)
            o[e] = f2bf((vv[i][e] - mu) * rstd * gs[plane * 8 + e] + bs[plane * 8 + e]);
        *reinterpret_cast<bf16x8*>(out + ((size_t)plane * MR + grow) * 8) = o;
    }
}

// ---------------------------------------------------------------------------
// V transpose: per (b,h), vT[(bh*56 + kp)*64 + d]*8 + (key&7) = V[key][d],
// keys >= 400 zeroed. XCD-swizzled 1D grid (1792 = 8*224).
// ---------------------------------------------------------------------------
__global__ __launch_bounds__(256) void vtrans(
    const short* __restrict__ qkv, short* __restrict__ vT)
{
    __shared__ short tile[64][66];
    const int id = blockIdx.x;
    const int xcd = id & 7, rem = id >> 3;
    const int bh_hi = rem / 7, c = rem - bh_hi * 7;
    const int bh_i = bh_hi * 8 + xcd;
    const int h = bh_i & 3, b = bh_i >> 2;
    const int tid = threadIdx.x;
    const size_t bh = (size_t)bh_i;
    for (int t = tid; t < 512; t += 256) {
        int pp = t >> 6, l = t & 63;
        int j = c * 64 + l;
        bf16x8 v;
        if (j < NN)
            v = *reinterpret_cast<const bf16x8*>(
                qkv + (((size_t)(64 + 8 * h + pp)) * MR + (size_t)b * NN + j) * 8);
        else { for (int e = 0; e < 8; ++e) v[e] = 0; }
#pragma unroll
        for (int e = 0; e < 8; ++e) tile[l][pp * 8 + e] = v[e];
    }
    __syncthreads();
    for (int t = tid; t < 512; t += 256) {
        int kq = t >> 6, d = t & 63;
        int kp = c * 8 + kq;
        bf16x8 o;
#pragma unroll
        for (int e = 0; e < 8; ++e) o[e] = tile[kq * 8 + e][d];
        *reinterpret_cast<bf16x8*>(vT + ((bh * 56 + kp) * 64 + d) * 8) = o;
    }
}

// ---------------------------------------------------------------------------
// Attention, LDS-minimal: K and V fragments read straight from global
// (L2-resident via XCD swizzle, coalesced). LDS holds only P (+Q transiently)
// -> 52 KB -> 3 blocks/CU. Barriers per block: 3. PV loop barrier-free.
// ---------------------------------------------------------------------------
__global__ __launch_bounds__(256, 3) void attn_p8(
    const short* __restrict__ qkv, const short* __restrict__ vT,
    short* __restrict__ Out)
{
    __shared__ short PS[26624];   // P: 52 planes x 64 rows x 8 (53248 B); [0..4096) doubles as Q staging
    const int id = blockIdx.x;
    const int xcd = id & 7, rem = id >> 3;
    const int bh_hi = rem / 7, qt = rem - bh_hi * 7;
    const int bh_i = bh_hi * 8 + xcd;
    const int h = bh_i & 3, b = bh_i >> 2;
    const int tid = threadIdx.x;
    const int w = tid >> 6, lane = tid & 63;
    const int quad = lane >> 4, l15 = lane & 15;
    const size_t rowb = (size_t)b * NN;

    // stage Q (8 planes x 64 rows) into PS[0..4096)
    for (int j = w; j < 8; j += 4)
        gl_lds16(qkv + (((size_t)(8 * h + j)) * MR + rowb + qt * 64 + lane) * 8, &PS[j * 512]);
    __syncthreads();

    bf16x8 aq0 = *reinterpret_cast<const bf16x8*>(&PS[(quad * 64 + w * 16 + l15) * 8]);
    bf16x8 aq1 = *reinterpret_cast<const bf16x8*>(&PS[((4 + quad) * 64 + w * 16 + l15) * 8]);

    // QK^T: K fragment for (nt, quad) = 16B at plane (32+8h+quad), key nt*16+l15
    const short* Kb0 = qkv + ((size_t)(32 + 8 * h + quad) * MR + rowb + l15) * 8;
    const short* Kb1 = qkv + ((size_t)(36 + 8 * h + quad) * MR + rowb + l15) * 8;

    f32x4 sacc[25];
#pragma unroll
    for (int nt = 0; nt < 25; ++nt) { sacc[nt][0] = 0; sacc[nt][1] = 0; sacc[nt][2] = 0; sacc[nt][3] = 0; }
#pragma unroll
    for (int nt = 0; nt < 25; ++nt) {
        bf16x8 b0 = *reinterpret_cast<const bf16x8*>(Kb0 + nt * 128);
        bf16x8 b1 = *reinterpret_cast<const bf16x8*>(Kb1 + nt * 128);
        sacc[nt] = __builtin_amdgcn_mfma_f32_16x16x32_bf16(aq0, b0, sacc[nt], 0, 0, 0);
        sacc[nt] = __builtin_amdgcn_mfma_f32_16x16x32_bf16(aq1, b1, sacc[nt], 0, 0, 0);
    }

    float mx[4] = {-3e38f, -3e38f, -3e38f, -3e38f}, sm[4] = {0, 0, 0, 0};
#pragma unroll
    for (int nt = 0; nt < 25; ++nt)
#pragma unroll
        for (int r = 0; r < 4; ++r) mx[r] = fmaxf(mx[r], sacc[nt][r]);
#pragma unroll
    for (int r = 0; r < 4; ++r) {
        mx[r] = fmaxf(mx[r], __shfl_xor(mx[r], 1));
        mx[r] = fmaxf(mx[r], __shfl_xor(mx[r], 2));
        mx[r] = fmaxf(mx[r], __shfl_xor(mx[r], 4));
        mx[r] = fmaxf(mx[r], __shfl_xor(mx[r], 8));
    }
#pragma unroll
    for (int nt = 0; nt < 25; ++nt)
#pragma unroll
        for (int r = 0; r < 4; ++r) {
            float e = __expf((sacc[nt][r] - mx[r]) * 0.125f);
            sacc[nt][r] = e;
            sm[r] += e;
        }
#pragma unroll
    for (int r = 0; r < 4; ++r) {
        sm[r] += __shfl_xor(sm[r], 1);
        sm[r] += __shfl_xor(sm[r], 2);
        sm[r] += __shfl_xor(sm[r], 4);
        sm[r] += __shfl_xor(sm[r], 8);
    }
    __syncthreads();   // Q LDS reads complete -> P may overwrite PS

    // P transpose into PS (C-layout -> A-fragment layout), keys>=400 zeroed
#pragma unroll
    for (int nt = 0; nt < 25; ++nt)
#pragma unroll
        for (int r = 0; r < 4; ++r) {
            int colk = nt * 16 + l15;
            PS[((colk >> 3) * 64 + w * 16 + quad * 4 + r) * 8 + (colk & 7)] = f2bf(sacc[nt][r]);
        }
    for (int idx = tid; idx < 1024; idx += 256) PS[25600 + idx] = 0;

    f32x4 oacc[4];
#pragma unroll
    for (int dt = 0; dt < 4; ++dt) { oacc[dt][0] = 0; oacc[dt][1] = 0; oacc[dt][2] = 0; oacc[dt][3] = 0; }
    __syncthreads();   // P visible to all waves

    // PV, barrier-free: V fragment for (kt, quad, dt) = 16B at vT plane
    // bh*56 + kt*4 + quad, d = dt*16 + l15 (L2-resident, coalesced).
    const short* Vb = vT + (((size_t)bh_i * 56 + quad) * 64 + l15) * 8;
#pragma unroll
    for (int kt = 0; kt < 13; ++kt) {
        bf16x8 pa = *reinterpret_cast<const bf16x8*>(
            &PS[((kt * 4 + quad) * 64 + w * 16 + l15) * 8]);
#pragma unroll
        for (int dt = 0; dt < 4; ++dt) {
            bf16x8 vb = *reinterpret_cast<const bf16x8*>(Vb + kt * 2048 + dt * 128);
            oacc[dt] = __builtin_amdgcn_mfma_f32_16x16x32_bf16(pa, vb, oacc[dt], 0, 0, 0);
        }
    }
#pragma unroll
    for (int r = 0; r < 4; ++r) {
        int row = qt * 64 + w * 16 + quad * 4 + r;
        if (row >= NN) continue;
        float inv = 1.0f / sm[r];
#pragma unroll
        for (int dt = 0; dt < 4; ++dt) {
            int col = dt * 16 + l15;
            Out[(((size_t)(8 * h + (col >> 3))) * MR + rowb + row) * 8 + (col & 7)] =
                f2bf(oacc[dt][r] * inv);
        }
    }
}

// ---------------------------------------------------------------------------
// vectorized f32 -> P8 conversion: one thread per (row, 8-col group).
// ---------------------------------------------------------------------------
__global__ void conv_p8(const float* __restrict__ src, short* __restrict__ dst,
                        int R, int K, int Kp, int PR)
{
    const int G = Kp >> 3;
    int idx = blockIdx.x * 256 + threadIdx.x;
    if (idx >= R * G) return;
    int r = idx / G, g = idx - r * G;
    int k0 = g << 3;
    bf16x8 o;
    if (k0 + 8 <= K) {
        const float4 v0 = *reinterpret_cast<const float4*>(src + (size_t)r * K + k0);
        const float4 v1 = *reinterpret_cast<const float4*>(src + (size_t)r * K + k0 + 4);
        o[0] = f2bf(v0.x); o[1] = f2bf(v0.y); o[2] = f2bf(v0.z); o[3] = f2bf(v0.w);
        o[4] = f2bf(v1.x); o[5] = f2bf(v1.y); o[6] = f2bf(v1.z); o[7] = f2bf(v1.w);
    } else {
#pragma unroll
        for (int e = 0; e < 8; ++e) {
            int k = k0 + e;
            o[e] = (k < K) ? f2bf(src[(size_t)r * K + k]) : (short)0;
        }
    }
    *reinterpret_cast<bf16x8*>(dst + ((size_t)g * PR + r) * 8) = o;
}

// ---------------------------------------------------------------------------
// batched f32 -> P8 conversion for the 11 small weight matrices.
// ---------------------------------------------------------------------------
struct ConvSeg { const float* src; short* dst; int R, K, Kp, start; };
struct ConvPack { ConvSeg s[11]; int total; };

__global__ void conv_multi(ConvPack p)
{
    int idx = blockIdx.x * 256 + threadIdx.x;
    if (idx >= p.total) return;
    int si = 0;
#pragma unroll
    for (int t = 1; t < 11; ++t) if (idx >= p.s[t].start) si = t;
    const ConvSeg sg = p.s[si];
    int local = idx - sg.start;
    const int G = sg.Kp >> 3;
    int r = local / G, g = local - r * G;
    int k0 = g << 3;
    bf16x8 o;
    if (k0 + 8 <= sg.K) {
        const float4 v0 = *reinterpret_cast<const float4*>(sg.src + (size_t)r * sg.K + k0);
        const float4 v1 = *reinterpret_cast<const float4*>(sg.src + (size_t)r * sg.K + k0 + 4);
        o[0] = f2bf(v0.x); o[1] = f2bf(v0.y); o[2] = f2bf(v0.z); o[3] = f2bf(v0.w);
        o[4] = f2bf(v1.x); o[5] = f2bf(v1.y); o[6] = f2bf(v1.z); o[7] = f2bf(v1.w);
    } else {
#pragma unroll
        for (int e = 0; e < 8; ++e) {
            int k = k0 + e;
            o[e] = (k < sg.K) ? f2bf(sg.src[(size_t)r * sg.K + k]) : (short)0;
        }
    }
    *reinterpret_cast<bf16x8*>(sg.dst + ((size_t)g * sg.R + r) * 8) = o;
}

// ---------------------------------------------------------------------------
__global__ __launch_bounds__(256) void w1_p8(
    const float* __restrict__ W1, short* __restrict__ Wp)
{
    __shared__ float tile[128][129];
    const int k0 = blockIdx.x * 128;
    const int tid = threadIdx.x;
    for (int t = 0; t < 16; ++t) {
        int idx = t * 256 + tid;
        int r = idx >> 5, k4 = idx & 31;
        float4 v = *(const float4*)(W1 + (size_t)r * 102400 + k0 + k4 * 4);
        tile[r][k4 * 4 + 0] = v.x; tile[r][k4 * 4 + 1] = v.y;
        tile[r][k4 * 4 + 2] = v.z; tile[r][k4 * 4 + 3] = v.w;
    }
    __syncthreads();
    for (int t = 0; t < 8; ++t) {
        int idx = t * 256 + tid;
        int pidx = idx >> 7, r = idx & 127;
        bf16x8 o;
#pragma unroll
        for (int e = 0; e < 8; ++e) o[e] = f2bf(tile[r][pidx * 8 + e]);
        *reinterpret_cast<bf16x8*>(Wp + (((size_t)(k0 >> 3) + pidx) * 128 + r) * 8) = o;
    }
}

// ---------------------------------------------------------------------------
__global__ void colsum_dinv(const float* __restrict__ sc, float* __restrict__ dinv)
{
    int b = blockIdx.y;
    int j = blockIdx.x * 256 + threadIdx.x;
    if (j >= NN) return;
    const float* p = sc + (size_t)b * NN * NN + j;
    float s = 0.0f;
    for (int i = 0; i < NN; ++i) s += p[(size_t)i * NN];
    dinv[b * NN + j] = (s > 0.0f) ? 1.0f / sqrtf(s) : 0.0f;
}

// ---------------------------------------------------------------------------
__global__ __launch_bounds__(256) void sc_prep(
    const float* __restrict__ sc, const float* __restrict__ dinv,
    short* __restrict__ scb, short* __restrict__ anT)
{
    __shared__ float tile[64][65];
    const int b = blockIdx.z;
    const int i0 = blockIdx.y * 64, j0 = blockIdx.x * 64;
    const int tid = threadIdx.x;
    const float* sb = sc + (size_t)b * NN * NN;
    short* scbb = scb + (size_t)b * 56 * 512 * 8;
    short* anTb = anT + (size_t)b * 56 * 512 * 8;
    for (int e = tid; e < 4096; e += 256) {
        int r = e >> 6, c = e & 63;
        int i = i0 + r, j = j0 + c;
        tile[r][c] = (i < NN && j < NN) ? sb[(size_t)i * NN + j] : 0.0f;
    }
    __syncthreads();
    for (int e = tid; e < 4096; e += 256) {
        int r = e >> 6, c = e & 63;
        int i = i0 + r, j = j0 + c;
        scbb[((size_t)(j >> 3) * 512 + i) * 8 + (j & 7)] = f2bf(tile[r][c]);
        float v = 0.0f;
        if (i < NN && j < NN) v = tile[r][c] * dinv[b * NN + i] * dinv[b * NN + j];
        anTb[((size_t)(i >> 3) * 512 + j) * 8 + (i & 7)] = f2bf(v);
    }
}

// ---------------------------------------------------------------------------
__global__ __launch_bounds__(256) void cls_gemm(
    const short* __restrict__ C1, const short* __restrict__ C2,
    const short* __restrict__ Wp, float* __restrict__ partial)
{
    __shared__ short Al[32 * 64 * 8];
    __shared__ short Wl[8 * 128 * 8];
    const int j = blockIdx.x;
    const int tid = threadIdx.x;
    const int w = tid >> 6, lane = tid & 63;
    const int quad = lane >> 4, l15 = lane & 15;

    for (int s = 0; s < 8; ++s) {
        int idx = s * 256 + tid;
        int p = idx >> 6, b = idx & 63;
        size_t ad = ((size_t)p * MR + (size_t)b * NN + j) * 8;
        bf16x8 a = *reinterpret_cast<const bf16x8*>(C1 + ad);
        bf16x8 c = *reinterpret_cast<const bf16x8*>(C2 + ad);
        bf16x8 o;
#pragma unroll
        for (int e = 0; e < 8; ++e) o[e] = f2bf(0.5f * (bf2f(a[e]) + bf2f(c[e])));
        *reinterpret_cast<bf16x8*>(&Al[(p * 64 + b) * 8]) = o;
    }

    f32x4 acc[4][2] = {};
    const size_t wp0 = (size_t)j * 32;
    for (int s = 0; s < 4; ++s) {
#pragma unroll
        for (int pp = 0; pp < 2; ++pp) {
            int p = w + pp * 4;
            gl_lds16(Wp + ((wp0 + s * 8 + p) * 128 + lane) * 8,      &Wl[(p * 128) * 8]);
            gl_lds16(Wp + ((wp0 + s * 8 + p) * 128 + 64 + lane) * 8, &Wl[(p * 128 + 64) * 8]);
        }
        __syncthreads();
#pragma unroll
        for (int kb = 0; kb < 2; ++kb) {
            bf16x8 af[4], bfr[2];
#pragma unroll
            for (int mi = 0; mi < 4; ++mi)
                af[mi] = *reinterpret_cast<const bf16x8*>(
                    &Al[((s * 8 + kb * 4 + quad) * 64 + mi * 16 + l15) * 8]);
#pragma unroll
            for (int ni = 0; ni < 2; ++ni)
                bfr[ni] = *reinterpret_cast<const bf16x8*>(
                    &Wl[((kb * 4 + quad) * 128 + w * 32 + ni * 16 + l15) * 8]);
#pragma unroll
            for (int mi = 0; mi < 4; ++mi)
#pragma unroll
                for (int ni = 0; ni < 2; ++ni)
                    acc[mi][ni] = __builtin_amdgcn_mfma_f32_16x16x32_bf16(af[mi], bfr[ni], acc[mi][ni], 0, 0, 0);
        }
        __syncthreads();
    }
    float* pj = partial + (size_t)j * 8192;
#pragma unroll
    for (int mi = 0; mi < 4; ++mi)
#pragma unroll
        for (int r = 0; r < 4; ++r) {
            int row = mi * 16 + quad * 4 + r;
#pragma unroll
            for (int ni = 0; ni < 2; ++ni)
                pj[row * 128 + w * 32 + ni * 16 + l15] = acc[mi][ni][r];
        }
}

__global__ void cls_reduce(const float* __restrict__ partial, float* __restrict__ clsh)
{
    int o = blockIdx.x * 256 + threadIdx.x;
    float s = 0.0f;
    for (int kb = 0; kb < 400; ++kb) s += partial[(size_t)kb * 8192 + o];
    clsh[o] = s;
}

__global__ void logits_final(
    const float* __restrict__ clsh, const float* __restrict__ b1,
    const float* __restrict__ w2, const float* __restrict__ b2,
    float* __restrict__ out)
{
    __shared__ float t[128];
    int b = blockIdx.x;
    int tid = threadIdx.x;
    t[tid] = fmaxf(clsh[b * 128 + tid] + b1[tid], 0.0f);
    __syncthreads();
    if (tid < 2) {
        float s = b2[tid];
        for (int o = 0; o < 128; ++o) s += t[o] * w2[tid * 128 + o];
        out[b * 2 + tid] = s;
    }
}

// ---------------------------------------------------------------------------
extern "C" void kernel_launch(void* const* d_in, const int* in_sizes, int n_in,
                              void* d_out, int out_size, void* d_ws, size_t ws_size,
                              hipStream_t stream)
{
    const float* fc        = (const float*)d_in[0];
    const float* sc        = (const float*)d_in[1];
    const float* proj_w    = (const float*)d_in[2];
    const float* proj_b    = (const float*)d_in[3];
    const float* enc_qkv_w = (const float*)d_in[4];
    const float* enc_qkv_b = (const float*)d_in[5];
    const float* enc_out_w = (const float*)d_in[6];
    const float* enc_out_b = (const float*)d_in[7];
    const float* enc_l1_w  = (const float*)d_in[8];
    const float* enc_l1_b  = (const float*)d_in[9];
    const float* enc_l2_w  = (const float*)d_in[10];
    const float* enc_l2_b  = (const float*)d_in[11];
    const float* enc_n1_g  = (const float*)d_in[12];
    const float* enc_n1_b  = (const float*)d_in[13];
    const float* enc_n2_g  = (const float*)d_in[14];
    const float* enc_n2_b  = (const float*)d_in[15];
    const float* gcn_w1    = (const float*)d_in[16];
    const float* gcn_b1    = (const float*)d_in[17];
    const float* gcn_w2    = (const float*)d_in[18];
    const float* gcn_b2    = (const float*)d_in[19];
    const float* ca1_qkv_w = (const float*)d_in[20];
    const float* ca1_qkv_b = (const float*)d_in[21];
    const float* ca1_out_w = (const float*)d_in[22];
    const float* ca1_out_b = (const float*)d_in[23];
    const float* ca1_n_g   = (const float*)d_in[24];
    const float* ca1_n_b   = (const float*)d_in[25];
    const float* ca2_qkv_w = (const float*)d_in[26];
    const float* ca2_qkv_b = (const float*)d_in[27];
    const float* ca2_out_w = (const float*)d_in[28];
    const float* ca2_out_b = (const float*)d_in[29];
    const float* ca2_n_g   = (const float*)d_in[30];
    const float* ca2_n_b   = (const float*)d_in[31];
    const float* cls_w1    = (const float*)d_in[32];
    const float* cls_b1    = (const float*)d_in[33];
    const float* cls_w2    = (const float*)d_in[34];
    const float* cls_b2    = (const float*)d_in[35];

    char* wsb = (char*)d_ws;
    size_t off = 0;
    auto alloc = [&](size_t bytes) { char* r = wsb + off; off += (bytes + 255) & ~(size_t)255; return r; };
    short* bufBig = (short*)alloc((size_t)MR * 1024 * 2);
    short* fcb    = (short*)alloc((size_t)56 * MR * 8 * 2);
    short* anT    = (short*)alloc((size_t)NB * 56 * 512 * 8 * 2);
    short* bufH   = (short*)alloc((size_t)32 * MR * 8 * 2);
    short* bufA   = (short*)alloc((size_t)32 * MR * 8 * 2);
    short* bufC   = (short*)alloc((size_t)32 * MR * 8 * 2);
    short* bufZS  = (short*)alloc((size_t)32 * MR * 8 * 2);
    short* vT     = (short*)alloc((size_t)NB * NHH * 56 * 64 * 8 * 2);
    short* w1b    = (short*)alloc((size_t)12800 * 128 * 8 * 2);
    short* projwb = (short*)alloc((size_t)56 * 256 * 8 * 2);
    short* qkvwb  = (short*)alloc((size_t)32 * 1536 * 8 * 2);
    short* outwb  = (short*)alloc((size_t)32 * 512 * 8 * 2);
    short* l1wb   = (short*)alloc((size_t)32 * 2048 * 8 * 2);
    short* l2wb   = (short*)alloc((size_t)128 * 512 * 8 * 2);
    short* gw1b   = (short*)alloc((size_t)56 * 256 * 8 * 2);
    short* gw2b   = (short*)alloc((size_t)32 * 256 * 8 * 2);
    short* c1qb   = (short*)alloc((size_t)32 * 768 * 8 * 2);
    short* c1ob   = (short*)alloc((size_t)32 * 256 * 8 * 2);
    short* c2qb   = (short*)alloc((size_t)32 * 768 * 8 * 2);
    short* c2ob   = (short*)alloc((size_t)32 * 256 * 8 * 2);
    float* dinv   = (float*)alloc((size_t)MR * 4);
    float* clsh   = (float*)alloc((size_t)NB * 128 * 4);
    short* scb = bufBig;
    short* XT1 = bufBig + (size_t)64 * 56 * 512 * 8;
    short* h1  = bufBig;
    short* XT2 = XT1;
    float* partial = (float*)fcb;

    dim3 blk(256), blk512(512);
    auto cgrid = [](long long n) { return dim3((unsigned)((n + 255) / 256)); };

    // ---- conversions to P8 ----
    conv_p8<<<cgrid((long long)MR * 56), blk, 0, stream>>>(fc, fcb, MR, 400, 448, MR);
    {
        ConvPack pk;
        int st = 0;
        auto seg = [&](int i, const float* s, short* d, int R, int K, int Kp) {
            pk.s[i].src = s; pk.s[i].dst = d; pk.s[i].R = R; pk.s[i].K = K;
            pk.s[i].Kp = Kp; pk.s[i].start = st; st += R * (Kp >> 3);
        };
        seg(0,  proj_w,    projwb, 256,  400,  448);
        seg(1,  enc_qkv_w, qkvwb,  1536, 256,  256);
        seg(2,  enc_out_w, outwb,  512,  256,  256);
        seg(3,  enc_l1_w,  l1wb,   2048, 256,  256);
        seg(4,  enc_l2_w,  l2wb,   512,  1024, 1024);
        seg(5,  gcn_w1,    gw1b,   256,  400,  448);
        seg(6,  gcn_w2,    gw2b,   256,  256,  256);
        seg(7,  ca1_qkv_w, c1qb,   768,  256,  256);
        seg(8,  ca1_out_w, c1ob,   256,  256,  256);
        seg(9,  ca2_qkv_w, c2qb,   768,  256,  256);
        seg(10, ca2_out_w, c2ob,   256,  256,  256);
        pk.total = st;
        conv_multi<<<cgrid(st), blk, 0, stream>>>(pk);
    }
    w1_p8<<<800, blk, 0, stream>>>(cls_w1, w1b);

    // ---- FC branch ----
    gemm_p8<<<dim3(100, 2, 1), blk512, 0, stream>>>(
        fcb, MR, 0, projwb, 256, 0, proj_b, bufH, MR, 0, 0, MR, 256, 256, 448, 0);
    for (int l = 0; l < 2; ++l) {
        gemm_p8<<<dim3(100, 6, 1), blk512, 0, stream>>>(
            bufH, MR, 0, qkvwb + (size_t)l * 768 * 8, 1536, 0, enc_qkv_b + l * 768,
            bufBig, MR, 0, 0, MR, 768, 768, 256, 0);
        vtrans<<<dim3(1792), blk, 0, stream>>>(bufBig, vT);
        attn_p8<<<dim3(1792), blk, 0, stream>>>(bufBig, vT, bufA);
        // attn-out GEMM + residual + LN (in-place on bufH)
        gemm_ln<<<400, blk512, 0, stream>>>(
            bufA, outwb + (size_t)l * 256 * 8, 512, enc_out_b + l * 256,
            bufH, enc_n1_g + l * DD, enc_n1_b + l * DD, bufH, 256);
        gemm_p8<<<dim3(100, 8, 1), blk512, 0, stream>>>(
            bufH, MR, 0, l1wb + (size_t)l * 1024 * 8, 2048, 0, enc_l1_b + l * 1024,
            bufBig, MR, 0, 0, MR, 1024, 1024, 256, 1);
        // FF2 GEMM + residual + LN (in-place on bufH)
        gemm_ln<<<400, blk512, 0, stream>>>(
            bufBig, l2wb + (size_t)l * 256 * 8, 512, enc_l2_b + l * 256,
            bufH, enc_n2_g + l * DD, enc_n2_b + l * DD, bufH, 1024);
    }

    // ---- GCN branch ----
    colsum_dinv<<<dim3(2, NB), blk, 0, stream>>>(sc, dinv);
    sc_prep<<<dim3(7, 7, NB), blk, 0, stream>>>(sc, dinv, scb, anT);
    gemm_p8<<<dim3(1, 4, NB), blk512, 0, stream>>>(
        gw1b, 256, 0, scb, 512, 56LL * 512 * 8, nullptr,
        XT1, 256, 0, 56LL * 256 * 8, 256, 400, 448, 448, 0);
    gemm_p8<<<dim3(2, 2, NB), blk512, 0, stream>>>(
        anT, 512, 56LL * 512 * 8, XT1, 256, 56LL * 256 * 8, gcn_b1,
        h1, 512, 0, 32LL * 512 * 8, 400, 256, 256, 448, 1);
    gemm_p8<<<dim3(1, 4, NB), blk512, 0, stream>>>(
        gw2b, 256, 0, h1, 512, 32LL * 512 * 8, nullptr,
        XT2, 256, 0, 56LL * 256 * 8, 256, 400, 448, 256, 0);
    gemm_p8<<<dim3(2, 2, NB), blk512, 0, stream>>>(
        anT, 512, 56LL * 512 * 8, XT2, 256, 56LL * 256 * 8, gcn_b2,
        bufZS, MR, 400, 0, 400, 256, 256, 448, 0);

    // ---- Cross attention 1: Q = Z_F, KV = Z_S ----
    gemm_p8<<<dim3(100, 2, 1), blk512, 0, stream>>>(
        bufH, MR, 0, c1qb, 768, 0, ca1_qkv_b, bufBig, MR, 0, 0, MR, 256, 256, 256, 0);
    gemm_p8<<<dim3(100, 4, 1), blk512, 0, stream>>>(
        bufZS, MR, 0, c1qb + 256 * 8, 768, 0, ca1_qkv_b + 256,
        bufBig + (size_t)32 * MR * 8, MR, 0, 0, MR, 512, 512, 256, 0);
    vtrans<<<dim3(1792), blk, 0, stream>>>(bufBig, vT);
    attn_p8<<<dim3(1792), blk, 0, stream>>>(bufBig, vT, bufA);
    gemm_ln<<<400, blk512, 0, stream>>>(
        bufA, c1ob, 256, ca1_out_b, bufH, ca1_n_g, ca1_n_b, bufC, 256);

    // ---- Cross attention 2: Q = Z_S, KV = Z_F ----
    gemm_p8<<<dim3(100, 2, 1), blk512, 0, stream>>>(
        bufZS, MR, 0, c2qb, 768, 0, ca2_qkv_b, bufBig, MR, 0, 0, MR, 256, 256, 256, 0);
    gemm_p8<<<dim3(100, 4, 1), blk512, 0, stream>>>(
        bufH, MR, 0, c2qb + 256 * 8, 768, 0, ca2_qkv_b + 256,
        bufBig + (size_t)32 * MR * 8, MR, 0, 0, MR, 512, 512, 256, 0);
    vtrans<<<dim3(1792), blk, 0, stream>>>(bufBig, vT);
    attn_p8<<<dim3(1792), blk, 0, stream>>>(bufBig, vT, bufA);
    gemm_ln<<<400, blk512, 0, stream>>>(
        bufA, c2ob, 256, ca2_out_b, bufZS, ca2_n_g, ca2_n_b, bufZS, 256);

    // ---- Classifier ----
    cls_gemm<<<400, blk, 0, stream>>>(bufC, bufZS, w1b, partial);
    cls_reduce<<<32, blk, 0, stream>>>(partial, clsh);
    logits_final<<<NB, 128, 0, stream>>>(clsh, cls_b1, cls_w2, cls_b2, (float*)d_out);
}

// Round 15
// 878.109 us; speedup vs baseline: 1.1616x; 1.0183x over previous
//
#include <hip/hip_runtime.h>
#include <math.h>

// Problem constants
#define NB   64
#define NN   400
#define DD   256
#define NHH  4
#define HDD  64
#define MR   25600            // NB*NN

typedef __attribute__((ext_vector_type(8))) short bf16x8;
typedef __attribute__((ext_vector_type(4))) float f32x4;

__device__ __forceinline__ short f2bf(float x) {
    union { float f; unsigned u; } v; v.f = x;
    return (short)((v.u + 0x7FFFu + ((v.u >> 16) & 1u)) >> 16);
}
__device__ __forceinline__ float bf2f(short s) {
    union { unsigned u; float f; } v; v.u = ((unsigned)(unsigned short)s) << 16;
    return v.f;
}
// async global->LDS, 16 B/lane; src = per-lane addr, LDS dest = wave-uniform base
__device__ __forceinline__ void gl_lds16(const void* g, void* l) {
    __builtin_amdgcn_global_load_lds(
        (const __attribute__((address_space(1))) unsigned*)g,
        (__attribute__((address_space(3))) unsigned*)l, 16, 0, 0);
}
// counted vmcnt wait (T4): never drain to 0 in a main loop. "memory" clobber
// orders LDS reads after the wait at IR level. vmcnt is per-wave.
__device__ __forceinline__ void wait_vmcnt(int n) {
    switch (n) {
    case 0: asm volatile("s_waitcnt vmcnt(0)" ::: "memory"); break;
    case 1: asm volatile("s_waitcnt vmcnt(1)" ::: "memory"); break;
    case 2: asm volatile("s_waitcnt vmcnt(2)" ::: "memory"); break;
    case 3: asm volatile("s_waitcnt vmcnt(3)" ::: "memory"); break;
    case 4: asm volatile("s_waitcnt vmcnt(4)" ::: "memory"); break;
    default: asm volatile("s_waitcnt vmcnt(5)" ::: "memory"); break;
    }
}
__device__ __forceinline__ void barrier_raw() {
    __builtin_amdgcn_sched_barrier(0);
    __builtin_amdgcn_s_barrier();
    __builtin_amdgcn_sched_barrier(0);
}

// ---------------------------------------------------------------------------
// P8 layout: element (row, k) lives at ((k>>3)*rows + row)*8 + (k&7) (bf16).
// = the 16x16x32 MFMA fragment layout; staging is contiguous 1 KiB bursts.
// ---------------------------------------------------------------------------

// bf16 GEMM, 256x128 tile, 512 threads (8 waves: 4m x 2n), BK=32, 3 staging
// buffers, 2-deep counted-vmcnt pipeline, T1 XCD-chunked block swizzle
// (measured: total 940->900, gemm_p8 out of top-5). FROZEN.
__global__ __launch_bounds__(512, 4) void gemm_p8(
    const short* __restrict__ A, int arows, long long sA,
    const short* __restrict__ B, int brows, long long sB,
    const float* __restrict__ bias,
    short* __restrict__ C, int crows, int crz, long long sCe,
    int M, int N, int Npad, int K, int relu)
{
    __shared__ short lds[36864];   // 3 bufs of 12288 (A 8192 + B 4096); epilogue [256][136] fits
    const int tid = threadIdx.x;

    // XCD-chunked swizzle of the flattened grid (x = m-tile, y = n-tile, z = batch)
    const unsigned gx = gridDim.x, gy = gridDim.y;
    const unsigned nwg = gx * gy * gridDim.z;
    const unsigned lin = (blockIdx.z * gy + blockIdx.y) * gx + blockIdx.x;
    const unsigned g = (lin & 7) * (nwg >> 3) + (lin >> 3);   // xcd-contiguous
    const unsigned zz = g / (gx * gy);
    const unsigned rem2 = g - zz * gx * gy;
    const unsigned mx = rem2 / gy;          // m-major: same-m blocks share an XCD
    const unsigned ny = rem2 - mx * gy;

    const int z = (int)zz;
    const int m0 = (int)mx * 256, n0 = (int)ny * 128;
    const short* Ab = A + (size_t)z * sA;
    const short* Bb = B + (size_t)z * sB;

    const int w = tid >> 6, lane = tid & 63;
    const int quad = lane >> 4, l15 = lane & 15;
    const int wm = w & 3, wn = w >> 2;

    f32x4 acc[4][4] = {};

    const int KT = K >> 5;          // steps of 32 k (4 planes)

    auto STAGE = [&](int buf, int kt) {
        const int gp0 = kt << 2;
        short* Al = lds + buf * 12288;
        short* Bl = Al + 8192;
        // 24 chunks (16 A + 8 B), 3 per wave
#pragma unroll
        for (int i = 0; i < 3; ++i) {
            int c = i * 8 + w;
            if (c < 16) {
                int p = c >> 2, hh = c & 3;
                gl_lds16(Ab + ((size_t)(gp0 + p) * arows + m0 + hh * 64 + lane) * 8,
                         &Al[(p * 256 + hh * 64) * 8]);
            } else {
                int cb = c - 16, p = cb >> 1, hh = cb & 1;
                gl_lds16(Bb + ((size_t)(gp0 + p) * brows + n0 + hh * 64 + lane) * 8,
                         &Bl[(p * 128 + hh * 64) * 8]);
            }
        }
    };

    STAGE(0, 0);
    STAGE(1, 1);
    for (int kt = 0; kt < KT; ++kt) {
        wait_vmcnt(kt + 1 < KT ? 3 : 0);   // chunk kt complete; kt+1 (3 loads) stays in flight
        barrier_raw();
        if (kt + 2 < KT) STAGE((kt + 2) % 3, kt + 2);
        const short* Al = lds + (kt % 3) * 12288;
        const short* Bl = Al + 8192;
        bf16x8 af[4], bfr[4];
#pragma unroll
        for (int mi = 0; mi < 4; ++mi)
            af[mi] = *reinterpret_cast<const bf16x8*>(
                &Al[(quad * 256 + wm * 64 + mi * 16 + l15) * 8]);
#pragma unroll
        for (int ni = 0; ni < 4; ++ni)
            bfr[ni] = *reinterpret_cast<const bf16x8*>(
                &Bl[(quad * 128 + wn * 64 + ni * 16 + l15) * 8]);
#pragma unroll
        for (int mi = 0; mi < 4; ++mi)
#pragma unroll
            for (int ni = 0; ni < 4; ++ni)
                acc[mi][ni] = __builtin_amdgcn_mfma_f32_16x16x32_bf16(af[mi], bfr[ni], acc[mi][ni], 0, 0, 0);
    }
    __syncthreads();   // all waves done reading staging before epilogue overwrite

    // epilogue: acc -> bf16 row-major LDS tile [256][136], then 16B coalesced stores
#pragma unroll
    for (int mi = 0; mi < 4; ++mi) {
#pragma unroll
        for (int r = 0; r < 4; ++r) {
            int row = wm * 64 + mi * 16 + quad * 4 + r;
#pragma unroll
            for (int ni = 0; ni < 4; ++ni) {
                int col = wn * 64 + ni * 16 + l15;
                int gcol = n0 + col;
                float v = 0.0f;
                if (gcol < N) {
                    v = acc[mi][ni][r];
                    if (bias) v += bias[gcol];
                    if (relu) v = fmaxf(v, 0.0f);
                }
                lds[row * 136 + col] = f2bf(v);
            }
        }
    }
    __syncthreads();
    short* Cbz = C + (size_t)z * sCe;
    const long long zr = (long long)z * crz;
#pragma unroll
    for (int t = 0; t < 8; ++t) {
        int c = t * 512 + tid;
        int row = c & 255, p16 = c >> 8;
        int grow = m0 + row;
        int gcol0 = n0 + p16 * 8;
        if (grow < M && gcol0 < Npad) {
            bf16x8 v = *reinterpret_cast<const bf16x8*>(&lds[row * 136 + p16 * 8]);
            *reinterpret_cast<bf16x8*>(
                &Cbz[((size_t)(gcol0 >> 3) * crows + zr + grow) * 8]) = v;
        }
    }
}

// ---------------------------------------------------------------------------
// Fused GEMM (N=256) + residual + LayerNorm. 512 threads, wave owns a
// 32-col eighth. Measured 899.7 -> 894.1 with this form. FROZEN.
// ---------------------------------------------------------------------------
__global__ __launch_bounds__(512, 4) void gemm_ln(
    const short* __restrict__ A,
    const short* __restrict__ B, int brows,
    const float* __restrict__ bias,
    const short* __restrict__ resid,
    const float* __restrict__ g, const float* __restrict__ bb,
    short* __restrict__ out, int K)
{
    __shared__ short lds[30720];        // 3 bufs of 10240: A [0,2048) B [2048,10240); epilogue rowt[64][264]
    __shared__ float gs[256], bs[256], bi_s[256];
    __shared__ float red[2][8][64];
    const int tid = threadIdx.x;
    const int m0 = blockIdx.x * 64;
    const int w = tid >> 6, lane = tid & 63;
    const int quad = lane >> 4, l15 = lane & 15;
    if (tid < 256) { gs[tid] = g[tid]; bs[tid] = bb[tid]; bi_s[tid] = bias[tid]; }

    f32x4 acc[4][2] = {};
    const int KT = K >> 5;
    const int myloads = (w < 4) ? 3 : 2;   // per-wave loads per STAGE (vmcnt is per-wave)

    auto STAGE = [&](int buf, int kt) {
        const int gp0 = kt << 2;
        short* Al = lds + buf * 10240;
        short* Bl = Al + 2048;
        // 20 chunks (4 A + 16 B), 8 waves: waves 0-3 take 3, waves 4-7 take 2
#pragma unroll
        for (int i = 0; i < 3; ++i) {
            int c = i * 8 + w;
            if (c < 4) {
                gl_lds16(A + ((size_t)(gp0 + c) * MR + m0 + lane) * 8, &Al[(c * 64) * 8]);
            } else if (c < 20) {
                int cb = c - 4, p = cb >> 2, cq = cb & 3;
                gl_lds16(B + ((size_t)(gp0 + p) * brows + cq * 64 + lane) * 8,
                         &Bl[(p * 256 + cq * 64) * 8]);
            }
        }
    };

    STAGE(0, 0);
    STAGE(1, 1);
    for (int kt = 0; kt < KT; ++kt) {
        wait_vmcnt(kt + 1 < KT ? myloads : 0);
        barrier_raw();
        if (kt + 2 < KT) STAGE((kt + 2) % 3, kt + 2);
        const short* Al = lds + (kt % 3) * 10240;
        const short* Bl = Al + 2048;
        bf16x8 af[4], bfr[2];
#pragma unroll
        for (int mi = 0; mi < 4; ++mi)
            af[mi] = *reinterpret_cast<const bf16x8*>(
                &Al[(quad * 64 + mi * 16 + l15) * 8]);
#pragma unroll
        for (int ni = 0; ni < 2; ++ni)
            bfr[ni] = *reinterpret_cast<const bf16x8*>(
                &Bl[(quad * 256 + w * 32 + ni * 16 + l15) * 8]);
#pragma unroll
        for (int mi = 0; mi < 4; ++mi)
#pragma unroll
            for (int ni = 0; ni < 2; ++ni)
                acc[mi][ni] = __builtin_amdgcn_mfma_f32_16x16x32_bf16(af[mi], bfr[ni], acc[mi][ni], 0, 0, 0);
    }
    __syncthreads();   // staging reads complete before rowt overwrite

    // epilogue 1: bias add, round to bf16, into row-tile rowt[64][4 groups][66]
    short* rowt = lds;
#pragma unroll
    for (int mi = 0; mi < 4; ++mi)
#pragma unroll
        for (int ni = 0; ni < 2; ++ni) {
            int col = w * 32 + ni * 16 + l15;
            int part = col >> 6, idx = col & 63;
#pragma unroll
            for (int r = 0; r < 4; ++r) {
                int row = mi * 16 + quad * 4 + r;
                rowt[row * 264 + part * 66 + idx] = f2bf(acc[mi][ni][r] + bi_s[col]);
            }
        }
    __syncthreads();

    // epilogue 2: thread = (row, eighth): 64 rows x 8 parts, 32 cols each
    const int row = tid >> 3, part = tid & 7;
    const int grow = m0 + row;
    float vv[4][8];
    float sum = 0.0f, sq = 0.0f;
#pragma unroll
    for (int i = 0; i < 4; ++i) {
        int plane = part * 4 + i;            // 8-col group index (0..31)
        bf16x8 rv = *reinterpret_cast<const bf16x8*>(resid + ((size_t)plane * MR + grow) * 8);
        bf16x8 tv = *reinterpret_cast<const bf16x8*>(
            &rowt[row * 264 + (plane >> 3) * 66 + (plane & 7) * 8]);
#pragma unroll
        for (int e = 0; e < 8; ++e) {
            float v = bf2f(tv[e]) + bf2f(rv[e]);
            vv[i][e] = v; sum += v; sq += v * v;
        }
    }
    red[0][part][row] = sum; red[1][part][row] = sq;
    __syncthreads();
    sum = 0.0f; sq = 0.0f;
#pragma unroll
    for (int p = 0; p < 8; ++p) { sum += red[0][p][row]; sq += red[1][p][row]; }
    float mu = sum * (1.0f / 256.0f);
    float var = sq * (1.0f / 256.0f) - mu * mu;
    float rstd = 1.0f / sqrtf(fmaxf(var, 0.0f) + 1e-5f);
#pragma unroll
    for (int i = 0; i < 4; ++i) {
        int plane = part * 4 + i;
        bf16x8 o;
#pragma unroll
        for (int e = 0; e < 8; ++e)
            o[e] = f2bf((vv[i][e] - mu) * rstd * gs[plane * 8 + e] + bs[plane * 8 + e]);
        *reinterpret_cast<bf16x8*>(out + ((size_t)plane * MR + grow) * 8) = o;
    }
}

// ---------------------------------------------------------------------------
// V transpose: per (b,h), vT[(bh*56 + kp)*64 + d]*8 + (key&7) = V[key][d],
// keys >= 400 zeroed. XCD-swizzled 1D grid (1792 = 8*224).
// ---------------------------------------------------------------------------
__global__ __launch_bounds__(256) void vtrans(
    const short* __restrict__ qkv, short* __restrict__ vT)
{
    __shared__ short tile[64][66];
    const int id = blockIdx.x;
    const int xcd = id & 7, rem = id >> 3;
    const int bh_hi = rem / 7, c = rem - bh_hi * 7;
    const int bh_i = bh_hi * 8 + xcd;
    const int h = bh_i & 3, b = bh_i >> 2;
    const int tid = threadIdx.x;
    const size_t bh = (size_t)bh_i;
    for (int t = tid; t < 512; t += 256) {
        int pp = t >> 6, l = t & 63;
        int j = c * 64 + l;
        bf16x8 v;
        if (j < NN)
            v = *reinterpret_cast<const bf16x8*>(
                qkv + (((size_t)(64 + 8 * h + pp)) * MR + (size_t)b * NN + j) * 8);
        else { for (int e = 0; e < 8; ++e) v[e] = 0; }
#pragma unroll
        for (int e = 0; e < 8; ++e) tile[l][pp * 8 + e] = v[e];
    }
    __syncthreads();
    for (int t = tid; t < 512; t += 256) {
        int kq = t >> 6, d = t & 63;
        int kp = c * 8 + kq;
        bf16x8 o;
#pragma unroll
        for (int e = 0; e < 8; ++e) o[e] = tile[kq * 8 + e][d];
        *reinterpret_cast<bf16x8*>(vT + ((bh * 56 + kp) * 64 + d) * 8) = o;
    }
}

// ---------------------------------------------------------------------------
// Attention, 1-WAVE blocks (64 threads, QBLK=16): each wave owns 16 q-rows
// end-to-end. Q fragments load DIRECTLY global->register (16B/lane, L2);
// K/V fragments from global as before. P tile is wave-private LDS
// [52][16][8] = 13.3 KB -> ~12 blocks/CU (vs 3), and ZERO barriers (P
// write->read is same-wave, lgkmcnt-ordered). Grid 6400 = 64*4*25,
// XCD-swizzled; 25*16 = 400 so no output row bound check.
// ---------------------------------------------------------------------------
__global__ __launch_bounds__(64) void attn_p8(
    const short* __restrict__ qkv, const short* __restrict__ vT,
    short* __restrict__ Out)
{
    __shared__ short PS[6656];   // P: 52 planes x 16 rows x 8 (13312 B)
    const int id = blockIdx.x;
    const int xcd = id & 7, rem = id >> 3;       // 6400 = 8 * 800
    const int bh_hi = rem / 25, qt = rem - bh_hi * 25;
    const int bh_i = bh_hi * 8 + xcd;
    const int h = bh_i & 3, b = bh_i >> 2;
    const int lane = threadIdx.x & 63;
    const int quad = lane >> 4, l15 = lane & 15;
    const size_t rowb = (size_t)b * NN;
    const int q0 = qt * 16;

    // Q fragments straight from global (plane quad / 4+quad, row q0+l15)
    bf16x8 aq0 = *reinterpret_cast<const bf16x8*>(
        qkv + (((size_t)(8 * h + quad)) * MR + rowb + q0 + l15) * 8);
    bf16x8 aq1 = *reinterpret_cast<const bf16x8*>(
        qkv + (((size_t)(8 * h + 4 + quad)) * MR + rowb + q0 + l15) * 8);

    // QK^T: K fragment for (nt, quad) = 16B at plane (32+8h+quad), key nt*16+l15
    const short* Kb0 = qkv + ((size_t)(32 + 8 * h + quad) * MR + rowb + l15) * 8;
    const short* Kb1 = qkv + ((size_t)(36 + 8 * h + quad) * MR + rowb + l15) * 8;

    f32x4 sacc[25];
#pragma unroll
    for (int nt = 0; nt < 25; ++nt) { sacc[nt][0] = 0; sacc[nt][1] = 0; sacc[nt][2] = 0; sacc[nt][3] = 0; }
#pragma unroll
    for (int nt = 0; nt < 25; ++nt) {
        bf16x8 b0 = *reinterpret_cast<const bf16x8*>(Kb0 + nt * 128);
        bf16x8 b1 = *reinterpret_cast<const bf16x8*>(Kb1 + nt * 128);
        sacc[nt] = __builtin_amdgcn_mfma_f32_16x16x32_bf16(aq0, b0, sacc[nt], 0, 0, 0);
        sacc[nt] = __builtin_amdgcn_mfma_f32_16x16x32_bf16(aq1, b1, sacc[nt], 0, 0, 0);
    }

    float mx[4] = {-3e38f, -3e38f, -3e38f, -3e38f}, sm[4] = {0, 0, 0, 0};
#pragma unroll
    for (int nt = 0; nt < 25; ++nt)
#pragma unroll
        for (int r = 0; r < 4; ++r) mx[r] = fmaxf(mx[r], sacc[nt][r]);
#pragma unroll
    for (int r = 0; r < 4; ++r) {
        mx[r] = fmaxf(mx[r], __shfl_xor(mx[r], 1));
        mx[r] = fmaxf(mx[r], __shfl_xor(mx[r], 2));
        mx[r] = fmaxf(mx[r], __shfl_xor(mx[r], 4));
        mx[r] = fmaxf(mx[r], __shfl_xor(mx[r], 8));
    }
#pragma unroll
    for (int nt = 0; nt < 25; ++nt)
#pragma unroll
        for (int r = 0; r < 4; ++r) {
            float e = __expf((sacc[nt][r] - mx[r]) * 0.125f);
            sacc[nt][r] = e;
            sm[r] += e;
        }
#pragma unroll
    for (int r = 0; r < 4; ++r) {
        sm[r] += __shfl_xor(sm[r], 1);
        sm[r] += __shfl_xor(sm[r], 2);
        sm[r] += __shfl_xor(sm[r], 4);
        sm[r] += __shfl_xor(sm[r], 8);
    }

    // P transpose into wave-private PS (C-layout -> A-fragment layout);
    // key-planes 50,51 zeroed (keys 400..415 for the kt=12 tail).
#pragma unroll
    for (int nt = 0; nt < 25; ++nt)
#pragma unroll
        for (int r = 0; r < 4; ++r) {
            int colk = nt * 16 + l15;
            PS[((colk >> 3) * 16 + quad * 4 + r) * 8 + (colk & 7)] = f2bf(sacc[nt][r]);
        }
    for (int idx = lane; idx < 256; idx += 64) PS[6400 + idx] = 0;
    // no barrier: same-wave LDS write->read is lgkmcnt-ordered

    f32x4 oacc[4];
#pragma unroll
    for (int dt = 0; dt < 4; ++dt) { oacc[dt][0] = 0; oacc[dt][1] = 0; oacc[dt][2] = 0; oacc[dt][3] = 0; }

    // PV: V fragment for (kt, quad, dt) = 16B at vT plane bh*56 + kt*4 + quad,
    // d = dt*16 + l15 (L2-resident, coalesced). pa from wave-private PS.
    const short* Vb = vT + (((size_t)bh_i * 56 + quad) * 64 + l15) * 8;
#pragma unroll
    for (int kt = 0; kt < 13; ++kt) {
        bf16x8 pa = *reinterpret_cast<const bf16x8*>(
            &PS[((kt * 4 + quad) * 16 + l15) * 8]);
#pragma unroll
        for (int dt = 0; dt < 4; ++dt) {
            bf16x8 vb = *reinterpret_cast<const bf16x8*>(Vb + kt * 2048 + dt * 128);
            oacc[dt] = __builtin_amdgcn_mfma_f32_16x16x32_bf16(pa, vb, oacc[dt], 0, 0, 0);
        }
    }
#pragma unroll
    for (int r = 0; r < 4; ++r) {
        int row = q0 + quad * 4 + r;           // always < 400 (25*16 = 400)
        float inv = 1.0f / sm[r];
#pragma unroll
        for (int dt = 0; dt < 4; ++dt) {
            int col = dt * 16 + l15;
            Out[(((size_t)(8 * h + (col >> 3))) * MR + rowb + row) * 8 + (col & 7)] =
                f2bf(oacc[dt][r] * inv);
        }
    }
}

// ---------------------------------------------------------------------------
// vectorized f32 -> P8 conversion: one thread per (row, 8-col group).
// ---------------------------------------------------------------------------
__global__ void conv_p8(const float* __restrict__ src, short* __restrict__ dst,
                        int R, int K, int Kp, int PR)
{
    const int G = Kp >> 3;
    int idx = blockIdx.x * 256 + threadIdx.x;
    if (idx >= R * G) return;
    int r = idx / G, g = idx - r * G;
    int k0 = g << 3;
    bf16x8 o;
    if (k0 + 8 <= K) {
        const float4 v0 = *reinterpret_cast<const float4*>(src + (size_t)r * K + k0);
        const float4 v1 = *reinterpret_cast<const float4*>(src + (size_t)r * K + k0 + 4);
        o[0] = f2bf(v0.x); o[1] = f2bf(v0.y); o[2] = f2bf(v0.z); o[3] = f2bf(v0.w);
        o[4] = f2bf(v1.x); o[5] = f2bf(v1.y); o[6] = f2bf(v1.z); o[7] = f2bf(v1.w);
    } else {
#pragma unroll
        for (int e = 0; e < 8; ++e) {
            int k = k0 + e;
            o[e] = (k < K) ? f2bf(src[(size_t)r * K + k]) : (short)0;
        }
    }
    *reinterpret_cast<bf16x8*>(dst + ((size_t)g * PR + r) * 8) = o;
}

// ---------------------------------------------------------------------------
// batched f32 -> P8 conversion for the 11 small weight matrices.
// ---------------------------------------------------------------------------
struct ConvSeg { const float* src; short* dst; int R, K, Kp, start; };
struct ConvPack { ConvSeg s[11]; int total; };

__global__ void conv_multi(ConvPack p)
{
    int idx = blockIdx.x * 256 + threadIdx.x;
    if (idx >= p.total) return;
    int si = 0;
#pragma unroll
    for (int t = 1; t < 11; ++t) if (idx >= p.s[t].start) si = t;
    const ConvSeg sg = p.s[si];
    int local = idx - sg.start;
    const int G = sg.Kp >> 3;
    int r = local / G, g = local - r * G;
    int k0 = g << 3;
    bf16x8 o;
    if (k0 + 8 <= sg.K) {
        const float4 v0 = *reinterpret_cast<const float4*>(sg.src + (size_t)r * sg.K + k0);
        const float4 v1 = *reinterpret_cast<const float4*>(sg.src + (size_t)r * sg.K + k0 + 4);
        o[0] = f2bf(v0.x); o[1] = f2bf(v0.y); o[2] = f2bf(v0.z); o[3] = f2bf(v0.w);
        o[4] = f2bf(v1.x); o[5] = f2bf(v1.y); o[6] = f2bf(v1.z); o[7] = f2bf(v1.w);
    } else {
#pragma unroll
        for (int e = 0; e < 8; ++e) {
            int k = k0 + e;
            o[e] = (k < sg.K) ? f2bf(sg.src[(size_t)r * sg.K + k]) : (short)0;
        }
    }
    *reinterpret_cast<bf16x8*>(sg.dst + ((size_t)g * sg.R + r) * 8) = o;
}

// ---------------------------------------------------------------------------
__global__ __launch_bounds__(256) void w1_p8(
    const float* __restrict__ W1, short* __restrict__ Wp)
{
    __shared__ float tile[128][129];
    const int k0 = blockIdx.x * 128;
    const int tid = threadIdx.x;
    for (int t = 0; t < 16; ++t) {
        int idx = t * 256 + tid;
        int r = idx >> 5, k4 = idx & 31;
        float4 v = *(const float4*)(W1 + (size_t)r * 102400 + k0 + k4 * 4);
        tile[r][k4 * 4 + 0] = v.x; tile[r][k4 * 4 + 1] = v.y;
        tile[r][k4 * 4 + 2] = v.z; tile[r][k4 * 4 + 3] = v.w;
    }
    __syncthreads();
    for (int t = 0; t < 8; ++t) {
        int idx = t * 256 + tid;
        int pidx = idx >> 7, r = idx & 127;
        bf16x8 o;
#pragma unroll
        for (int e = 0; e < 8; ++e) o[e] = f2bf(tile[r][pidx * 8 + e]);
        *reinterpret_cast<bf16x8*>(Wp + (((size_t)(k0 >> 3) + pidx) * 128 + r) * 8) = o;
    }
}

// ---------------------------------------------------------------------------
__global__ void colsum_dinv(const float* __restrict__ sc, float* __restrict__ dinv)
{
    int b = blockIdx.y;
    int j = blockIdx.x * 256 + threadIdx.x;
    if (j >= NN) return;
    const float* p = sc + (size_t)b * NN * NN + j;
    float s = 0.0f;
    for (int i = 0; i < NN; ++i) s += p[(size_t)i * NN];
    dinv[b * NN + j] = (s > 0.0f) ? 1.0f / sqrtf(s) : 0.0f;
}

// ---------------------------------------------------------------------------
__global__ __launch_bounds__(256) void sc_prep(
    const float* __restrict__ sc, const float* __restrict__ dinv,
    short* __restrict__ scb, short* __restrict__ anT)
{
    __shared__ float tile[64][65];
    const int b = blockIdx.z;
    const int i0 = blockIdx.y * 64, j0 = blockIdx.x * 64;
    const int tid = threadIdx.x;
    const float* sb = sc + (size_t)b * NN * NN;
    short* scbb = scb + (size_t)b * 56 * 512 * 8;
    short* anTb = anT + (size_t)b * 56 * 512 * 8;
    for (int e = tid; e < 4096; e += 256) {
        int r = e >> 6, c = e & 63;
        int i = i0 + r, j = j0 + c;
        tile[r][c] = (i < NN && j < NN) ? sb[(size_t)i * NN + j] : 0.0f;
    }
    __syncthreads();
    for (int e = tid; e < 4096; e += 256) {
        int r = e >> 6, c = e & 63;
        int i = i0 + r, j = j0 + c;
        scbb[((size_t)(j >> 3) * 512 + i) * 8 + (j & 7)] = f2bf(tile[r][c]);
        float v = 0.0f;
        if (i < NN && j < NN) v = tile[r][c] * dinv[b * NN + i] * dinv[b * NN + j];
        anTb[((size_t)(i >> 3) * 512 + j) * 8 + (i & 7)] = f2bf(v);
    }
}

// ---------------------------------------------------------------------------
__global__ __launch_bounds__(256) void cls_gemm(
    const short* __restrict__ C1, const short* __restrict__ C2,
    const short* __restrict__ Wp, float* __restrict__ partial)
{
    __shared__ short Al[32 * 64 * 8];
    __shared__ short Wl[8 * 128 * 8];
    const int j = blockIdx.x;
    const int tid = threadIdx.x;
    const int w = tid >> 6, lane = tid & 63;
    const int quad = lane >> 4, l15 = lane & 15;

    for (int s = 0; s < 8; ++s) {
        int idx = s * 256 + tid;
        int p = idx >> 6, b = idx & 63;
        size_t ad = ((size_t)p * MR + (size_t)b * NN + j) * 8;
        bf16x8 a = *reinterpret_cast<const bf16x8*>(C1 + ad);
        bf16x8 c = *reinterpret_cast<const bf16x8*>(C2 + ad);
        bf16x8 o;
#pragma unroll
        for (int e = 0; e < 8; ++e) o[e] = f2bf(0.5f * (bf2f(a[e]) + bf2f(c[e])));
        *reinterpret_cast<bf16x8*>(&Al[(p * 64 + b) * 8]) = o;
    }

    f32x4 acc[4][2] = {};
    const size_t wp0 = (size_t)j * 32;
    for (int s = 0; s < 4; ++s) {
#pragma unroll
        for (int pp = 0; pp < 2; ++pp) {
            int p = w + pp * 4;
            gl_lds16(Wp + ((wp0 + s * 8 + p) * 128 + lane) * 8,      &Wl[(p * 128) * 8]);
            gl_lds16(Wp + ((wp0 + s * 8 + p) * 128 + 64 + lane) * 8, &Wl[(p * 128 + 64) * 8]);
        }
        __syncthreads();
#pragma unroll
        for (int kb = 0; kb < 2; ++kb) {
            bf16x8 af[4], bfr[2];
#pragma unroll
            for (int mi = 0; mi < 4; ++mi)
                af[mi] = *reinterpret_cast<const bf16x8*>(
                    &Al[((s * 8 + kb * 4 + quad) * 64 + mi * 16 + l15) * 8]);
#pragma unroll
            for (int ni = 0; ni < 2; ++ni)
                bfr[ni] = *reinterpret_cast<const bf16x8*>(
                    &Wl[((kb * 4 + quad) * 128 + w * 32 + ni * 16 + l15) * 8]);
#pragma unroll
            for (int mi = 0; mi < 4; ++mi)
#pragma unroll
                for (int ni = 0; ni < 2; ++ni)
                    acc[mi][ni] = __builtin_amdgcn_mfma_f32_16x16x32_bf16(af[mi], bfr[ni], acc[mi][ni], 0, 0, 0);
        }
        __syncthreads();
    }
    float* pj = partial + (size_t)j * 8192;
#pragma unroll
    for (int mi = 0; mi < 4; ++mi)
#pragma unroll
        for (int r = 0; r < 4; ++r) {
            int row = mi * 16 + quad * 4 + r;
#pragma unroll
            for (int ni = 0; ni < 2; ++ni)
                pj[row * 128 + w * 32 + ni * 16 + l15] = acc[mi][ni][r];
        }
}

__global__ void cls_reduce(const float* __restrict__ partial, float* __restrict__ clsh)
{
    int o = blockIdx.x * 256 + threadIdx.x;
    float s = 0.0f;
    for (int kb = 0; kb < 400; ++kb) s += partial[(size_t)kb * 8192 + o];
    clsh[o] = s;
}

__global__ void logits_final(
    const float* __restrict__ clsh, const float* __restrict__ b1,
    const float* __restrict__ w2, const float* __restrict__ b2,
    float* __restrict__ out)
{
    __shared__ float t[128];
    int b = blockIdx.x;
    int tid = threadIdx.x;
    t[tid] = fmaxf(clsh[b * 128 + tid] + b1[tid], 0.0f);
    __syncthreads();
    if (tid < 2) {
        float s = b2[tid];
        for (int o = 0; o < 128; ++o) s += t[o] * w2[tid * 128 + o];
        out[b * 2 + tid] = s;
    }
}

// ---------------------------------------------------------------------------
extern "C" void kernel_launch(void* const* d_in, const int* in_sizes, int n_in,
                              void* d_out, int out_size, void* d_ws, size_t ws_size,
                              hipStream_t stream)
{
    const float* fc        = (const float*)d_in[0];
    const float* sc        = (const float*)d_in[1];
    const float* proj_w    = (const float*)d_in[2];
    const float* proj_b    = (const float*)d_in[3];
    const float* enc_qkv_w = (const float*)d_in[4];
    const float* enc_qkv_b = (const float*)d_in[5];
    const float* enc_out_w = (const float*)d_in[6];
    const float* enc_out_b = (const float*)d_in[7];
    const float* enc_l1_w  = (const float*)d_in[8];
    const float* enc_l1_b  = (const float*)d_in[9];
    const float* enc_l2_w  = (const float*)d_in[10];
    const float* enc_l2_b  = (const float*)d_in[11];
    const float* enc_n1_g  = (const float*)d_in[12];
    const float* enc_n1_b  = (const float*)d_in[13];
    const float* enc_n2_g  = (const float*)d_in[14];
    const float* enc_n2_b  = (const float*)d_in[15];
    const float* gcn_w1    = (const float*)d_in[16];
    const float* gcn_b1    = (const float*)d_in[17];
    const float* gcn_w2    = (const float*)d_in[18];
    const float* gcn_b2    = (const float*)d_in[19];
    const float* ca1_qkv_w = (const float*)d_in[20];
    const float* ca1_qkv_b = (const float*)d_in[21];
    const float* ca1_out_w = (const float*)d_in[22];
    const float* ca1_out_b = (const float*)d_in[23];
    const float* ca1_n_g   = (const float*)d_in[24];
    const float* ca1_n_b   = (const float*)d_in[25];
    const float* ca2_qkv_w = (const float*)d_in[26];
    const float* ca2_qkv_b = (const float*)d_in[27];
    const float* ca2_out_w = (const float*)d_in[28];
    const float* ca2_out_b = (const float*)d_in[29];
    const float* ca2_n_g   = (const float*)d_in[30];
    const float* ca2_n_b   = (const float*)d_in[31];
    const float* cls_w1    = (const float*)d_in[32];
    const float* cls_b1    = (const float*)d_in[33];
    const float* cls_w2    = (const float*)d_in[34];
    const float* cls_b2    = (const float*)d_in[35];

    char* wsb = (char*)d_ws;
    size_t off = 0;
    auto alloc = [&](size_t bytes) { char* r = wsb + off; off += (bytes + 255) & ~(size_t)255; return r; };
    short* bufBig = (short*)alloc((size_t)MR * 1024 * 2);
    short* fcb    = (short*)alloc((size_t)56 * MR * 8 * 2);
    short* anT    = (short*)alloc((size_t)NB * 56 * 512 * 8 * 2);
    short* bufH   = (short*)alloc((size_t)32 * MR * 8 * 2);
    short* bufA   = (short*)alloc((size_t)32 * MR * 8 * 2);
    short* bufC   = (short*)alloc((size_t)32 * MR * 8 * 2);
    short* bufZS  = (short*)alloc((size_t)32 * MR * 8 * 2);
    short* vT     = (short*)alloc((size_t)NB * NHH * 56 * 64 * 8 * 2);
    short* w1b    = (short*)alloc((size_t)12800 * 128 * 8 * 2);
    short* projwb = (short*)alloc((size_t)56 * 256 * 8 * 2);
    short* qkvwb  = (short*)alloc((size_t)32 * 1536 * 8 * 2);
    short* outwb  = (short*)alloc((size_t)32 * 512 * 8 * 2);
    short* l1wb   = (short*)alloc((size_t)32 * 2048 * 8 * 2);
    short* l2wb   = (short*)alloc((size_t)128 * 512 * 8 * 2);
    short* gw1b   = (short*)alloc((size_t)56 * 256 * 8 * 2);
    short* gw2b   = (short*)alloc((size_t)32 * 256 * 8 * 2);
    short* c1qb   = (short*)alloc((size_t)32 * 768 * 8 * 2);
    short* c1ob   = (short*)alloc((size_t)32 * 256 * 8 * 2);
    short* c2qb   = (short*)alloc((size_t)32 * 768 * 8 * 2);
    short* c2ob   = (short*)alloc((size_t)32 * 256 * 8 * 2);
    float* dinv   = (float*)alloc((size_t)MR * 4);
    float* clsh   = (float*)alloc((size_t)NB * 128 * 4);
    short* scb = bufBig;
    short* XT1 = bufBig + (size_t)64 * 56 * 512 * 8;
    short* h1  = bufBig;
    short* XT2 = XT1;
    float* partial = (float*)fcb;

    dim3 blk(256), blk512(512), blk64(64);
    auto cgrid = [](long long n) { return dim3((unsigned)((n + 255) / 256)); };

    // ---- conversions to P8 ----
    conv_p8<<<cgrid((long long)MR * 56), blk, 0, stream>>>(fc, fcb, MR, 400, 448, MR);
    {
        ConvPack pk;
        int st = 0;
        auto seg = [&](int i, const float* s, short* d, int R, int K, int Kp) {
            pk.s[i].src = s; pk.s[i].dst = d; pk.s[i].R = R; pk.s[i].K = K;
            pk.s[i].Kp = Kp; pk.s[i].start = st; st += R * (Kp >> 3);
        };
        seg(0,  proj_w,    projwb, 256,  400,  448);
        seg(1,  enc_qkv_w, qkvwb,  1536, 256,  256);
        seg(2,  enc_out_w, outwb,  512,  256,  256);
        seg(3,  enc_l1_w,  l1wb,   2048, 256,  256);
        seg(4,  enc_l2_w,  l2wb,   512,  1024, 1024);
        seg(5,  gcn_w1,    gw1b,   256,  400,  448);
        seg(6,  gcn_w2,    gw2b,   256,  256,  256);
        seg(7,  ca1_qkv_w, c1qb,   768,  256,  256);
        seg(8,  ca1_out_w, c1ob,   256,  256,  256);
        seg(9,  ca2_qkv_w, c2qb,   768,  256,  256);
        seg(10, ca2_out_w, c2ob,   256,  256,  256);
        pk.total = st;
        conv_multi<<<cgrid(st), blk, 0, stream>>>(pk);
    }
    w1_p8<<<800, blk, 0, stream>>>(cls_w1, w1b);

    // ---- FC branch ----
    gemm_p8<<<dim3(100, 2, 1), blk512, 0, stream>>>(
        fcb, MR, 0, projwb, 256, 0, proj_b, bufH, MR, 0, 0, MR, 256, 256, 448, 0);
    for (int l = 0; l < 2; ++l) {
        gemm_p8<<<dim3(100, 6, 1), blk512, 0, stream>>>(
            bufH, MR, 0, qkvwb + (size_t)l * 768 * 8, 1536, 0, enc_qkv_b + l * 768,
            bufBig, MR, 0, 0, MR, 768, 768, 256, 0);
        vtrans<<<dim3(1792), blk, 0, stream>>>(bufBig, vT);
        attn_p8<<<dim3(6400), blk64, 0, stream>>>(bufBig, vT, bufA);
        // attn-out GEMM + residual + LN (in-place on bufH)
        gemm_ln<<<400, blk512, 0, stream>>>(
            bufA, outwb + (size_t)l * 256 * 8, 512, enc_out_b + l * 256,
            bufH, enc_n1_g + l * DD, enc_n1_b + l * DD, bufH, 256);
        gemm_p8<<<dim3(100, 8, 1), blk512, 0, stream>>>(
            bufH, MR, 0, l1wb + (size_t)l * 1024 * 8, 2048, 0, enc_l1_b + l * 1024,
            bufBig, MR, 0, 0, MR, 1024, 1024, 256, 1);
        // FF2 GEMM + residual + LN (in-place on bufH)
        gemm_ln<<<400, blk512, 0, stream>>>(
            bufBig, l2wb + (size_t)l * 256 * 8, 512, enc_l2_b + l * 256,
            bufH, enc_n2_g + l * DD, enc_n2_b + l * DD, bufH, 1024);
    }

    // ---- GCN branch ----
    colsum_dinv<<<dim3(2, NB), blk, 0, stream>>>(sc, dinv);
    sc_prep<<<dim3(7, 7, NB), blk, 0, stream>>>(sc, dinv, scb, anT);
    gemm_p8<<<dim3(1, 4, NB), blk512, 0, stream>>>(
        gw1b, 256, 0, scb, 512, 56LL * 512 * 8, nullptr,
        XT1, 256, 0, 56LL * 256 * 8, 256, 400, 448, 448, 0);
    gemm_p8<<<dim3(2, 2, NB), blk512, 0, stream>>>(
        anT, 512, 56LL * 512 * 8, XT1, 256, 56LL * 256 * 8, gcn_b1,
        h1, 512, 0, 32LL * 512 * 8, 400, 256, 256, 448, 1);
    gemm_p8<<<dim3(1, 4, NB), blk512, 0, stream>>>(
        gw2b, 256, 0, h1, 512, 32LL * 512 * 8, nullptr,
        XT2, 256, 0, 56LL * 256 * 8, 256, 400, 448, 256, 0);
    gemm_p8<<<dim3(2, 2, NB), blk512, 0, stream>>>(
        anT, 512, 56LL * 512 * 8, XT2, 256, 56LL * 256 * 8, gcn_b2,
        bufZS, MR, 400, 0, 400, 256, 256, 448, 0);

    // ---- Cross attention 1: Q = Z_F, KV = Z_S ----
    gemm_p8<<<dim3(100, 2, 1), blk512, 0, stream>>>(
        bufH, MR, 0, c1qb, 768, 0, ca1_qkv_b, bufBig, MR, 0, 0, MR, 256, 256, 256, 0);
    gemm_p8<<<dim3(100, 4, 1), blk512, 0, stream>>>(
        bufZS, MR, 0, c1qb + 256 * 8, 768, 0, ca1_qkv_b + 256,
        bufBig + (size_t)32 * MR * 8, MR, 0, 0, MR, 512, 512, 256, 0);
    vtrans<<<dim3(1792), blk, 0, stream>>>(bufBig, vT);
    attn_p8<<<dim3(6400), blk64, 0, stream>>>(bufBig, vT, bufA);
    gemm_ln<<<400, blk512, 0, stream>>>(
        bufA, c1ob, 256, ca1_out_b, bufH, ca1_n_g, ca1_n_b, bufC, 256);

    // ---- Cross attention 2: Q = Z_S, KV = Z_F ----
    gemm_p8<<<dim3(100, 2, 1), blk512, 0, stream>>>(
        bufZS, MR, 0, c2qb, 768, 0, ca2_qkv_b, bufBig, MR, 0, 0, MR, 256, 256, 256, 0);
    gemm_p8<<<dim3(100, 4, 1), blk512, 0, stream>>>(
        bufH, MR, 0, c2qb + 256 * 8, 768, 0, ca2_qkv_b + 256,
        bufBig + (size_t)32 * MR * 8, MR, 0, 0, MR, 512, 512, 256, 0);
    vtrans<<<dim3(1792), blk, 0, stream>>>(bufBig, vT);
    attn_p8<<<dim3(6400), blk64, 0, stream>>>(bufBig, vT, bufA);
    gemm_ln<<<400, blk512, 0, stream>>>(
        bufA, c2ob, 256, ca2_out_b, bufZS, ca2_n_g, ca2_n_b, bufZS, 256);

    // ---- Classifier ----
    cls_gemm<<<400, blk, 0, stream>>>(bufC, bufZS, w1b, partial);
    cls_reduce<<<32, blk, 0, stream>>>(partial, clsh);
    logits_final<<<NB, 128, 0, stream>>>(clsh, cls_b1, cls_w2, cls_b2, (float*)d_out);
}